// Round 2
// baseline (1485.817 us; speedup 1.0000x reference)
//
#include <hip/hip_runtime.h>

#define B_ 8
#define N_ 4096
#define K_ 16
#define C_ 64
#define NK_ (N_*K_)            // 65536
#define M_ (B_*N_*K_)          // 524288
#define BN_EPS_ 0.001f

static __device__ __forceinline__ float rdlane_f(float v, int l) {
  return __int_as_float(__builtin_amdgcn_readlane(__float_as_int(v), l));
}

// bf16 round-to-nearest-even (no NaN inputs in this pipeline)
static __device__ __forceinline__ unsigned short f2bf(float x) {
  unsigned u = __float_as_uint(x);
  unsigned r = (u + 0x7FFFu + ((u >> 16) & 1u)) >> 16;
  return (unsigned short)r;
}

// ---------------- pack points (B,3,N) -> float4 (B*N) ----------------
__global__ __launch_bounds__(256) void pack_pts(const float* __restrict__ p,
                                                float4* __restrict__ pf4) {
  int i = blockIdx.x * 256 + threadIdx.x;   // over B*N
  int b = i >> 12;
  int n = i & (N_ - 1);
  const float* base = p + (size_t)b * 3 * N_;
  pf4[i] = make_float4(base[n], base[N_ + n], base[2 * N_ + n], 0.f);
}

// ---------------- 128x128 transpose: dst[c][o] = src[o][c] ----------------
__global__ __launch_bounds__(256) void transpose_w(const float* __restrict__ src,
                                                   float* __restrict__ dst) {
  __shared__ float t[32][33];
  int r0 = blockIdx.x * 32, c0 = blockIdx.y * 32;
  int tx = threadIdx.x, ty = threadIdx.y;
  for (int i = ty; i < 32; i += 8) t[i][tx] = src[(r0 + i) * 128 + c0 + tx];
  __syncthreads();
  for (int i = ty; i < 32; i += 8) dst[(c0 + i) * 128 + r0 + tx] = t[tx][i];
}

// ---------------- w0at[d][o] = W0[o][d], d<3 ----------------
__global__ void make_w0at(const float* __restrict__ W0, float* __restrict__ w0at) {
  int o = threadIdx.x;  // 128
  for (int d = 0; d < 3; ++d) w0at[d * 128 + o] = W0[o * 131 + d];
}

// ---------------- exact KNN: one lane per query point ----------------
__global__ __launch_bounds__(64) void knn_kernel(const float4* __restrict__ p1f4,
                                                 const float4* __restrict__ p2f4,
                                                 int* __restrict__ idxout) {
  int lane = threadIdx.x;         // 64
  int blk = blockIdx.x;           // 512 = B * N/64
  int b = blk >> 6;
  int n1 = ((blk & 63) << 6) + lane;
  float4 q = p1f4[(b << 12) + n1];
  float ax = q.x, ay = q.y, az = q.z;
  const float4* pb = p2f4 + ((size_t)b << 12);

  float s[16];
  #pragma unroll
  for (int i = 0; i < 16; ++i) s[i] = 3.0e38f;   // s[0] = current 16th-smallest

  // phase 1: exact 16 smallest distance VALUES (sorted descending)
  for (int t = 0; t < N_; t += 64) {
    float4 pt = pb[t + lane];
    #pragma unroll 8
    for (int qq = 0; qq < 64; ++qq) {
      float px = rdlane_f(pt.x, qq), py = rdlane_f(pt.y, qq), pz = rdlane_f(pt.z, qq);
      float dx = ax - px, dy = ay - py, dz = az - pz;
      float d = __fadd_rn(__fadd_rn(__fmul_rn(dx, dx), __fmul_rn(dy, dy)), __fmul_rn(dz, dz));
      if (d < s[0]) {
        #pragma unroll
        for (int i = 0; i < 15; ++i) s[i] = fmaxf(s[i + 1], fminf(s[i], d));
        s[15] = fminf(s[15], d);
      }
    }
  }
  float T = s[0];
  // phase 2: recover indices (ascending n2 scan, cap 16)
  int cnt = 0;
  int obase = ((b << 12) + n1) * K_;
  for (int t = 0; t < N_; t += 64) {
    float4 pt = pb[t + lane];
    #pragma unroll 8
    for (int qq = 0; qq < 64; ++qq) {
      float px = rdlane_f(pt.x, qq), py = rdlane_f(pt.y, qq), pz = rdlane_f(pt.z, qq);
      float dx = ax - px, dy = ay - py, dz = az - pz;
      float d = __fadd_rn(__fadd_rn(__fmul_rn(dx, dx), __fmul_rn(dy, dy)), __fmul_rn(dz, dz));
      if (d <= T && cnt < 16) { idxout[obase + cnt] = t + qq; ++cnt; }
    }
  }
}

// ---------------- P[bn][o] = sum_c W0[o][coff+c] * f[b][c][n] (+bias) ----------------
// f is native (B,64,N) layout
__global__ __launch_bounds__(256) void pkern(const float* __restrict__ f,
                                             const float* __restrict__ W0,
                                             const float* __restrict__ bias,
                                             float* __restrict__ P, int coff) {
  __shared__ float fx[32 * 65];                  // [n][c], pad 65
  __shared__ __align__(16) float Wl[64 * 132];   // [c][o], pad 132
  int tid = threadIdx.x;
  int bn0 = blockIdx.x * 32;
  int b = bn0 >> 12, nb0 = bn0 & (N_ - 1);

  for (int u = tid; u < 32 * 64; u += 256) {
    int c = u >> 5, nl = u & 31;                 // coalesced along n
    fx[nl * 65 + c] = f[((size_t)b * C_ + c) * N_ + nb0 + nl];
  }
  for (int u = tid; u < 128 * 64; u += 256) {
    int o = u >> 6, c = u & 63;
    Wl[c * 132 + o] = W0[o * 131 + coff + c];
  }
  __syncthreads();

  int og = tid & 15, np_ = tid >> 4;
  int o0 = og * 8;
  int na = np_ * 2, nb = na + 1;
  float acc0[8], acc1[8];
  #pragma unroll
  for (int j = 0; j < 8; ++j) {
    float bv = bias ? bias[o0 + j] : 0.f;
    acc0[j] = bv; acc1[j] = bv;
  }
  for (int c = 0; c < 64; ++c) {
    float x0 = fx[na * 65 + c], x1 = fx[nb * 65 + c];
    float4 wa = *(const float4*)&Wl[c * 132 + o0];
    float4 wb = *(const float4*)&Wl[c * 132 + o0 + 4];
    float w[8] = {wa.x, wa.y, wa.z, wa.w, wb.x, wb.y, wb.z, wb.w};
    #pragma unroll
    for (int j = 0; j < 8; ++j) {
      acc0[j] = fmaf(x0, w[j], acc0[j]);
      acc1[j] = fmaf(x1, w[j], acc1[j]);
    }
  }
  float* Pa = P + (size_t)(bn0 + na) * 128 + o0;
  float* Pb = P + (size_t)(bn0 + nb) * 128 + o0;
  *(float4*)Pa = make_float4(acc0[0], acc0[1], acc0[2], acc0[3]);
  *(float4*)(Pa + 4) = make_float4(acc0[4], acc0[5], acc0[6], acc0[7]);
  *(float4*)Pb = make_float4(acc1[0], acc1[1], acc1[2], acc1[3]);
  *(float4*)(Pb + 4) = make_float4(acc1[4], acc1[5], acc1[6], acc1[7]);
}

// ---------------- BN0 stats over x0 = P1 + P2[idx] + W0a*rel_xyz ----------------
__global__ __launch_bounds__(256) void stats0_kernel(
    const float* __restrict__ P1, const float* __restrict__ P2,
    const int* __restrict__ idx, const float4* __restrict__ p1f4,
    const float4* __restrict__ p2f4, const float* __restrict__ w0at,
    float* __restrict__ stats) {
  int tid = threadIdx.x;
  int c = tid & 127, h = tid >> 7;
  float w0 = w0at[c], w1 = w0at[128 + c], w2 = w0at[256 + c];
  float sum = 0.f, sq = 0.f;
  int rbase = blockIdx.x * 256 + h * 128;
  for (int i = 0; i < 128; ++i) {
    int r = rbase + i;
    int b = r >> 16;
    int nk = r & (NK_ - 1);
    int n = nk >> 4;
    int j = idx[r];
    float4 pq = p1f4[(b << 12) + n];
    float4 pj = p2f4[(b << 12) + j];
    float rx = pj.x - pq.x, ry = pj.y - pq.y, rz = pj.z - pq.z;
    float a0 = w0 * rx + w1 * ry + w2 * rz;
    float x = P1[(size_t)((b << 12) + n) * 128 + c] +
              P2[(size_t)((b << 12) + j) * 128 + c] + a0;
    sum += x;
    sq = fmaf(x, x, sq);
  }
  __shared__ float red[256 * 2];
  red[tid * 2] = sum;
  red[tid * 2 + 1] = sq;
  __syncthreads();
  if (h == 0) {
    atomicAdd(stats + c, sum + red[(tid + 128) * 2]);
    atomicAdd(stats + 128 + c, sq + red[(tid + 128) * 2 + 1]);
  }
}

// ---------------- BN finalize: s = gamma*rsqrt(var+eps), t = beta - mean*s ----------------
__global__ void bnfin_kernel(const float* __restrict__ stats, const float* __restrict__ gamma,
                             const float* __restrict__ beta, float* __restrict__ bnp) {
  int o = threadIdx.x;  // 128
  const float invM = 1.0f / (float)M_;
  float mean = stats[o] * invM;
  float var = stats[128 + o] * invM - mean * mean;
  float s = gamma[o] * rsqrtf(var + BN_EPS_);
  bnp[o] = s;
  bnp[128 + o] = beta[o] - mean * s;
}

// ---------------- layer1: assemble x0 -> BN0+relu -> GEMM W1 -> x1(bf16) + stats1 ----------------
__global__ __launch_bounds__(256) void layer1_kernel(
    const float* __restrict__ P1, const float* __restrict__ P2,
    const int* __restrict__ idx, const float4* __restrict__ p1f4,
    const float4* __restrict__ p2f4, const float* __restrict__ w0at,
    const float* __restrict__ bnp0, const float* __restrict__ W1t,
    const float* __restrict__ b1, unsigned short* __restrict__ x1out,
    float* __restrict__ stats1) {
  __shared__ __align__(16) float Xs[64 * 128];   // [c_local][row]
  __shared__ __align__(16) float Ws[16 * 128];   // [cc][o]
  __shared__ float sred[4 * 128 * 2];
  int tid = threadIdx.x;
  int R0 = blockIdx.x * 128;
  int b = R0 >> 16;
  int n0 = (R0 & (NK_ - 1)) >> 4;

  int rl = tid & 127;
  int r = R0 + rl;
  int n = n0 + (rl >> 4);
  int j = idx[r];
  float4 pq = p1f4[(b << 12) + n], pj = p2f4[(b << 12) + j];
  float rx = pj.x - pq.x, ry = pj.y - pq.y, rz = pj.z - pq.z;
  const float* P1r = P1 + (size_t)((b << 12) + n) * 128;
  const float* P2r = P2 + (size_t)((b << 12) + j) * 128;

  int tc = tid & 15, tr = tid >> 4;
  float acc[8][8];
  #pragma unroll
  for (int i = 0; i < 8; ++i)
    #pragma unroll
    for (int jj = 0; jj < 8; ++jj) acc[i][jj] = 0.f;

  for (int ch = 0; ch < 2; ++ch) {
    __syncthreads();  // previous half's Xs readers done
    int cbase = ch * 64 + (tid >> 7) * 32;
    #pragma unroll
    for (int u = 0; u < 32; u += 4) {
      int c = cbase + u;
      float4 p1v = *(const float4*)(P1r + c);
      float4 p2v = *(const float4*)(P2r + c);
      float4 wx = *(const float4*)(w0at + c);
      float4 wy = *(const float4*)(w0at + 128 + c);
      float4 wz = *(const float4*)(w0at + 256 + c);
      float4 sv = *(const float4*)(bnp0 + c);
      float4 tv = *(const float4*)(bnp0 + 128 + c);
      float x0 = p1v.x + p2v.x + wx.x * rx + wy.x * ry + wz.x * rz;
      float x1_ = p1v.y + p2v.y + wx.y * rx + wy.y * ry + wz.y * rz;
      float x2_ = p1v.z + p2v.z + wx.z * rx + wy.z * ry + wz.z * rz;
      float x3_ = p1v.w + p2v.w + wx.w * rx + wy.w * ry + wz.w * rz;
      int cl = c - ch * 64;
      Xs[(cl + 0) * 128 + rl] = fmaxf(fmaf(sv.x, x0, tv.x), 0.f);
      Xs[(cl + 1) * 128 + rl] = fmaxf(fmaf(sv.y, x1_, tv.y), 0.f);
      Xs[(cl + 2) * 128 + rl] = fmaxf(fmaf(sv.z, x2_, tv.z), 0.f);
      Xs[(cl + 3) * 128 + rl] = fmaxf(fmaf(sv.w, x3_, tv.w), 0.f);
    }
    for (int kc = 0; kc < 4; ++kc) {
      int f = tid * 8;
      int cc = f >> 7, oo = f & 127;
      int cglob = ch * 64 + kc * 16 + cc;
      float4 wv0 = *(const float4*)(W1t + cglob * 128 + oo);
      float4 wv1 = *(const float4*)(W1t + cglob * 128 + oo + 4);
      __syncthreads();
      *(float4*)(Ws + cc * 128 + oo) = wv0;
      *(float4*)(Ws + cc * 128 + oo + 4) = wv1;
      __syncthreads();
      #pragma unroll
      for (int cc2 = 0; cc2 < 16; ++cc2) {
        int cl = kc * 16 + cc2;
        float4 xa = *(const float4*)(Xs + cl * 128 + tr * 8);
        float4 xb = *(const float4*)(Xs + cl * 128 + tr * 8 + 4);
        float4 wa = *(const float4*)(Ws + cc2 * 128 + tc * 8);
        float4 wb = *(const float4*)(Ws + cc2 * 128 + tc * 8 + 4);
        float xv[8] = {xa.x, xa.y, xa.z, xa.w, xb.x, xb.y, xb.z, xb.w};
        float wv[8] = {wa.x, wa.y, wa.z, wa.w, wb.x, wb.y, wb.z, wb.w};
        #pragma unroll
        for (int i = 0; i < 8; ++i)
          #pragma unroll
          for (int jj = 0; jj < 8; ++jj) acc[i][jj] = fmaf(xv[i], wv[jj], acc[i][jj]);
      }
    }
  }
  // epilogue: y = acc + b1 ; store bf16 ; stats (fp32)
  float bv[8];
  *(float4*)&bv[0] = *(const float4*)(b1 + tc * 8);
  *(float4*)&bv[4] = *(const float4*)(b1 + tc * 8 + 4);
  float ssum[8], ssq[8];
  #pragma unroll
  for (int jj = 0; jj < 8; ++jj) { ssum[jj] = 0.f; ssq[jj] = 0.f; }
  #pragma unroll
  for (int i = 0; i < 8; ++i) {
    int g = R0 + tr * 8 + i;
    float y[8];
    #pragma unroll
    for (int jj = 0; jj < 8; ++jj) {
      y[jj] = acc[i][jj] + bv[jj];
      ssum[jj] += y[jj];
      ssq[jj] = fmaf(y[jj], y[jj], ssq[jj]);
    }
    uint4 pk;
    pk.x = (unsigned)f2bf(y[0]) | ((unsigned)f2bf(y[1]) << 16);
    pk.y = (unsigned)f2bf(y[2]) | ((unsigned)f2bf(y[3]) << 16);
    pk.z = (unsigned)f2bf(y[4]) | ((unsigned)f2bf(y[5]) << 16);
    pk.w = (unsigned)f2bf(y[6]) | ((unsigned)f2bf(y[7]) << 16);
    *(uint4*)(x1out + (size_t)g * 128 + tc * 8) = pk;
  }
  #pragma unroll
  for (int jj = 0; jj < 8; ++jj) {
    ssum[jj] += __shfl_xor(ssum[jj], 16);
    ssum[jj] += __shfl_xor(ssum[jj], 32);
    ssq[jj] += __shfl_xor(ssq[jj], 16);
    ssq[jj] += __shfl_xor(ssq[jj], 32);
  }
  int wv_ = tid >> 6;
  if ((tid & 63) < 16) {
    #pragma unroll
    for (int jj = 0; jj < 8; ++jj) {
      sred[(wv_ * 128 + tc * 8 + jj) * 2] = ssum[jj];
      sred[(wv_ * 128 + tc * 8 + jj) * 2 + 1] = ssq[jj];
    }
  }
  __syncthreads();
  if (tid < 128) {
    float a = 0.f, q2 = 0.f;
    #pragma unroll
    for (int w = 0; w < 4; ++w) {
      a += sred[(w * 128 + tid) * 2];
      q2 += sred[(w * 128 + tid) * 2 + 1];
    }
    atomicAdd(stats1 + tid, a);
    atomicAdd(stats1 + 128 + tid, q2);
  }
}

// ---------------- layer2: BN1+relu -> GEMM W2 -> max/min over k + stats2 ----------------
__global__ __launch_bounds__(256) void layer2_kernel(
    const unsigned short* __restrict__ x1, const float* __restrict__ bnp1,
    const float* __restrict__ W2t, const float* __restrict__ b2,
    float* __restrict__ ymaxo, float* __restrict__ ymino,
    float* __restrict__ stats2) {
  __shared__ __align__(16) float Xs[64 * 128];
  __shared__ __align__(16) float Ws[16 * 128];
  __shared__ float sred[4 * 128 * 2];
  int tid = threadIdx.x;
  int R0 = blockIdx.x * 128;
  int b = R0 >> 16;
  int n0 = (R0 & (NK_ - 1)) >> 4;

  int rl = tid & 127;
  int r = R0 + rl;
  const unsigned short* xr = x1 + (size_t)r * 128;

  int tc = tid & 15, tr = tid >> 4;
  float acc[8][8];
  #pragma unroll
  for (int i = 0; i < 8; ++i)
    #pragma unroll
    for (int jj = 0; jj < 8; ++jj) acc[i][jj] = 0.f;

  for (int ch = 0; ch < 2; ++ch) {
    __syncthreads();
    int cbase = ch * 64 + (tid >> 7) * 32;
    #pragma unroll
    for (int u = 0; u < 32; u += 4) {
      int c = cbase + u;
      uint2 pv = *(const uint2*)(xr + c);          // 4 bf16
      float xv0 = __uint_as_float(pv.x << 16);
      float xv1 = __uint_as_float(pv.x & 0xFFFF0000u);
      float xv2 = __uint_as_float(pv.y << 16);
      float xv3 = __uint_as_float(pv.y & 0xFFFF0000u);
      float4 sv = *(const float4*)(bnp1 + c);
      float4 tv = *(const float4*)(bnp1 + 128 + c);
      int cl = c - ch * 64;
      Xs[(cl + 0) * 128 + rl] = fmaxf(fmaf(sv.x, xv0, tv.x), 0.f);
      Xs[(cl + 1) * 128 + rl] = fmaxf(fmaf(sv.y, xv1, tv.y), 0.f);
      Xs[(cl + 2) * 128 + rl] = fmaxf(fmaf(sv.z, xv2, tv.z), 0.f);
      Xs[(cl + 3) * 128 + rl] = fmaxf(fmaf(sv.w, xv3, tv.w), 0.f);
    }
    for (int kc = 0; kc < 4; ++kc) {
      int f = tid * 8;
      int cc = f >> 7, oo = f & 127;
      int cglob = ch * 64 + kc * 16 + cc;
      float4 wv0 = *(const float4*)(W2t + cglob * 128 + oo);
      float4 wv1 = *(const float4*)(W2t + cglob * 128 + oo + 4);
      __syncthreads();
      *(float4*)(Ws + cc * 128 + oo) = wv0;
      *(float4*)(Ws + cc * 128 + oo + 4) = wv1;
      __syncthreads();
      #pragma unroll
      for (int cc2 = 0; cc2 < 16; ++cc2) {
        int cl = kc * 16 + cc2;
        float4 xa = *(const float4*)(Xs + cl * 128 + tr * 8);
        float4 xb = *(const float4*)(Xs + cl * 128 + tr * 8 + 4);
        float4 wa = *(const float4*)(Ws + cc2 * 128 + tc * 8);
        float4 wb = *(const float4*)(Ws + cc2 * 128 + tc * 8 + 4);
        float xv[8] = {xa.x, xa.y, xa.z, xa.w, xb.x, xb.y, xb.z, xb.w};
        float wv[8] = {wa.x, wa.y, wa.z, wa.w, wb.x, wb.y, wb.z, wb.w};
        #pragma unroll
        for (int i = 0; i < 8; ++i)
          #pragma unroll
          for (int jj = 0; jj < 8; ++jj) acc[i][jj] = fmaf(xv[i], wv[jj], acc[i][jj]);
      }
    }
  }
  // epilogue: y = acc + b2 ; stats2 ; per-(n,o) max/min over k=16
  float bv[8];
  *(float4*)&bv[0] = *(const float4*)(b2 + tc * 8);
  *(float4*)&bv[4] = *(const float4*)(b2 + tc * 8 + 4);
  #pragma unroll
  for (int i = 0; i < 8; ++i)
    #pragma unroll
    for (int jj = 0; jj < 8; ++jj) acc[i][jj] += bv[jj];

  float ssum[8], ssq[8], mx[8], mn[8];
  #pragma unroll
  for (int jj = 0; jj < 8; ++jj) {
    ssum[jj] = 0.f; ssq[jj] = 0.f;
    mx[jj] = acc[0][jj]; mn[jj] = acc[0][jj];
  }
  #pragma unroll
  for (int i = 0; i < 8; ++i)
    #pragma unroll
    for (int jj = 0; jj < 8; ++jj) {
      float y = acc[i][jj];
      ssum[jj] += y;
      ssq[jj] = fmaf(y, y, ssq[jj]);
      mx[jj] = fmaxf(mx[jj], y);
      mn[jj] = fminf(mn[jj], y);
    }
  #pragma unroll
  for (int jj = 0; jj < 8; ++jj) {
    mx[jj] = fmaxf(mx[jj], __shfl_xor(mx[jj], 16));
    mn[jj] = fminf(mn[jj], __shfl_xor(mn[jj], 16));
  }
  if ((tr & 1) == 0) {
    int n = n0 + (tr >> 1);
    size_t base = ((size_t)(b << 12) + n) * 128 + tc * 8;
    *(float4*)(ymaxo + base) = make_float4(mx[0], mx[1], mx[2], mx[3]);
    *(float4*)(ymaxo + base + 4) = make_float4(mx[4], mx[5], mx[6], mx[7]);
    *(float4*)(ymino + base) = make_float4(mn[0], mn[1], mn[2], mn[3]);
    *(float4*)(ymino + base + 4) = make_float4(mn[4], mn[5], mn[6], mn[7]);
  }
  #pragma unroll
  for (int jj = 0; jj < 8; ++jj) {
    ssum[jj] += __shfl_xor(ssum[jj], 16);
    ssum[jj] += __shfl_xor(ssum[jj], 32);
    ssq[jj] += __shfl_xor(ssq[jj], 16);
    ssq[jj] += __shfl_xor(ssq[jj], 32);
  }
  int wv_ = tid >> 6;
  if ((tid & 63) < 16) {
    #pragma unroll
    for (int jj = 0; jj < 8; ++jj) {
      sred[(wv_ * 128 + tc * 8 + jj) * 2] = ssum[jj];
      sred[(wv_ * 128 + tc * 8 + jj) * 2 + 1] = ssq[jj];
    }
  }
  __syncthreads();
  if (tid < 128) {
    float a = 0.f, q2 = 0.f;
    #pragma unroll
    for (int w = 0; w < 4; ++w) {
      a += sred[(w * 128 + tid) * 2];
      q2 += sred[(w * 128 + tid) * 2 + 1];
    }
    atomicAdd(stats2 + tid, a);
    atomicAdd(stats2 + 128 + tid, q2);
  }
}

// ---------------- final: BN2+relu on max/min, transpose to (B,128,N) ----------------
__global__ __launch_bounds__(256) void final_kernel(const float* __restrict__ ymaxo,
                                                    const float* __restrict__ ymino,
                                                    const float* __restrict__ bnp2,
                                                    float* __restrict__ out) {
  __shared__ float T[64 * 129];
  int tid = threadIdx.x;
  int b = blockIdx.x >> 6;
  int n0 = (blockIdx.x & 63) * 64;
  for (int u = tid; u < 64 * 128; u += 256) {
    int nl = u >> 7, o = u & 127;
    size_t base = ((size_t)(b << 12) + n0 + nl) * 128 + o;
    float s = bnp2[o], t = bnp2[128 + o];
    float v = fmaf(s, (s >= 0.f ? ymaxo[base] : ymino[base]), t);
    T[nl * 129 + o] = fmaxf(v, 0.f);
  }
  __syncthreads();
  for (int u = tid; u < 64 * 128; u += 256) {
    int o = u >> 6, nl = u & 63;
    out[((size_t)b * 128 + o) * N_ + n0 + nl] = T[nl * 129 + o];
  }
}

extern "C" void kernel_launch(void* const* d_in, const int* in_sizes, int n_in,
                              void* d_out, int out_size, void* d_ws, size_t ws_size,
                              hipStream_t stream) {
  (void)in_sizes; (void)n_in; (void)out_size; (void)ws_size;
  const float* points1 = (const float*)d_in[0];
  const float* points2 = (const float*)d_in[1];
  const float* features1 = (const float*)d_in[2];
  const float* features2 = (const float*)d_in[3];
  const float* W0 = (const float*)d_in[4];
  const float* b0 = (const float*)d_in[5];
  const float* g0 = (const float*)d_in[6];
  const float* be0 = (const float*)d_in[7];
  const float* W1 = (const float*)d_in[8];
  const float* b1 = (const float*)d_in[9];
  const float* g1 = (const float*)d_in[10];
  const float* be1 = (const float*)d_in[11];
  const float* W2 = (const float*)d_in[12];
  const float* b2 = (const float*)d_in[13];
  const float* g2 = (const float*)d_in[14];
  const float* be2 = (const float*)d_in[15];
  float* out = (float*)d_out;

  char* ws = (char*)d_ws;
  size_t off = 0;
  auto alloc = [&](size_t bytes) -> void* {
    void* p = ws + off;
    off += (bytes + 255) & ~(size_t)255;
    return p;
  };
  // total workspace: ~195 MB
  int* idx = (int*)alloc((size_t)M_ * 4);                          // 2 MB
  float4* p1f4 = (float4*)alloc((size_t)B_ * N_ * 16);             // 0.5 MB
  float4* p2f4 = (float4*)alloc((size_t)B_ * N_ * 16);             // 0.5 MB
  float* P1 = (float*)alloc((size_t)B_ * N_ * 128 * 4);            // 16 MB
  float* P2 = (float*)alloc((size_t)B_ * N_ * 128 * 4);            // 16 MB
  float* W1t = (float*)alloc(128 * 128 * 4);
  float* W2t = (float*)alloc(128 * 128 * 4);
  float* w0at = (float*)alloc(3 * 128 * 4);
  float* stats = (float*)alloc(3 * 256 * 4);
  float* bnp = (float*)alloc(3 * 256 * 4);
  unsigned short* x1 = (unsigned short*)alloc((size_t)M_ * 128 * 2);  // 128 MB (bf16)
  float* ymaxo = (float*)alloc((size_t)B_ * N_ * 128 * 4);         // 16 MB
  float* ymino = (float*)alloc((size_t)B_ * N_ * 128 * 4);         // 16 MB

  hipMemsetAsync(stats, 0, 3 * 256 * 4, stream);

  pack_pts<<<B_ * N_ / 256, 256, 0, stream>>>(points1, p1f4);
  pack_pts<<<B_ * N_ / 256, 256, 0, stream>>>(points2, p2f4);
  transpose_w<<<dim3(4, 4), dim3(32, 8), 0, stream>>>(W1, W1t);
  transpose_w<<<dim3(4, 4), dim3(32, 8), 0, stream>>>(W2, W2t);
  make_w0at<<<1, 128, 0, stream>>>(W0, w0at);

  knn_kernel<<<B_ * N_ / 64, 64, 0, stream>>>(p1f4, p2f4, idx);

  pkern<<<B_ * N_ / 32, 256, 0, stream>>>(features1, W0, b0, P1, 67);
  pkern<<<B_ * N_ / 32, 256, 0, stream>>>(features2, W0, nullptr, P2, 3);

  stats0_kernel<<<M_ / 256, 256, 0, stream>>>(P1, P2, idx, p1f4, p2f4, w0at, stats);
  bnfin_kernel<<<1, 128, 0, stream>>>(stats, g0, be0, bnp);

  layer1_kernel<<<M_ / 128, 256, 0, stream>>>(P1, P2, idx, p1f4, p2f4, w0at, bnp,
                                              W1t, b1, x1, stats + 256);
  bnfin_kernel<<<1, 128, 0, stream>>>(stats + 256, g1, be1, bnp + 256);

  layer2_kernel<<<M_ / 128, 256, 0, stream>>>(x1, bnp + 256, W2t, b2, ymaxo, ymino,
                                              stats + 512);
  bnfin_kernel<<<1, 128, 0, stream>>>(stats + 512, g2, be2, bnp + 512);

  final_kernel<<<B_ * N_ / 64, 256, 0, stream>>>(ymaxo, ymino, bnp + 512, out);
}

// Round 3
// 1116.418 us; speedup vs baseline: 1.3309x; 1.3309x over previous
//
#include <hip/hip_runtime.h>

#define B_ 8
#define N_ 4096
#define K_ 16
#define C_ 64
#define NK_ (N_*K_)            // 65536
#define M_ (B_*N_*K_)          // 524288
#define BN_EPS_ 0.001f

// bf16 round-to-nearest-even (no NaN inputs in this pipeline)
static __device__ __forceinline__ unsigned short f2bf(float x) {
  unsigned u = __float_as_uint(x);
  unsigned r = (u + 0x7FFFu + ((u >> 16) & 1u)) >> 16;
  return (unsigned short)r;
}

// ---------------- pack points (B,3,N) -> float4 (B*N) ----------------
__global__ __launch_bounds__(256) void pack_pts(const float* __restrict__ p,
                                                float4* __restrict__ pf4) {
  int i = blockIdx.x * 256 + threadIdx.x;   // over B*N
  int b = i >> 12;
  int n = i & (N_ - 1);
  const float* base = p + (size_t)b * 3 * N_;
  pf4[i] = make_float4(base[n], base[N_ + n], base[2 * N_ + n], 0.f);
}

// ---------------- 128x128 transpose: dst[c][o] = src[o][c] ----------------
__global__ __launch_bounds__(256) void transpose_w(const float* __restrict__ src,
                                                   float* __restrict__ dst) {
  __shared__ float t[32][33];
  int r0 = blockIdx.x * 32, c0 = blockIdx.y * 32;
  int tx = threadIdx.x, ty = threadIdx.y;
  for (int i = ty; i < 32; i += 8) t[i][tx] = src[(r0 + i) * 128 + c0 + tx];
  __syncthreads();
  for (int i = ty; i < 32; i += 8) dst[(c0 + i) * 128 + r0 + tx] = t[tx][i];
}

// ---------------- w0at[d][o] = W0[o][d], d<3 ----------------
__global__ void make_w0at(const float* __restrict__ W0, float* __restrict__ w0at) {
  int o = threadIdx.x;  // 128
  for (int d = 0; d < 3; ++d) w0at[d * 128 + o] = W0[o * 131 + d];
}

// ================= KNN, candidate-split 8 ways =================
// knn_part: 1 wave per (b, 64-query group, 512-candidate chunk).
// Branchless sorted-16 insertion; candidate point is wave-uniform (scalar load).
__global__ __launch_bounds__(64) void knn_part(const float4* __restrict__ p1f4,
                                               const float4* __restrict__ p2f4,
                                               float* __restrict__ pvals) {
  int lane = threadIdx.x;
  int blk = blockIdx.x;            // chunk fastest: b(8) x grp(64) x chunk(8)
  int chunk = blk & 7;
  int grp = (blk >> 3) & 63;
  int b = blk >> 9;
  int n1 = (grp << 6) + lane;
  float4 q = p1f4[(b << 12) + n1];
  float ax = q.x, ay = q.y, az = q.z;
  const float4* pb = p2f4 + ((size_t)b << 12) + (chunk << 9);

  float s[16];
  #pragma unroll
  for (int i = 0; i < 16; ++i) s[i] = 3.0e38f;  // sorted desc; s[0]=16th smallest

  #pragma unroll 4
  for (int t = 0; t < 512; ++t) {
    float4 c = pb[t];              // wave-uniform -> scalar load
    float dx = ax - c.x, dy = ay - c.y, dz = az - c.z;
    float d = __fadd_rn(__fadd_rn(__fmul_rn(dx, dx), __fmul_rn(dy, dy)), __fmul_rn(dz, dz));
    #pragma unroll
    for (int i = 0; i < 15; ++i) s[i] = fmaxf(s[i + 1], fminf(s[i], d));
    s[15] = fminf(s[15], d);
  }
  float* dst = pvals + ((size_t)((b << 12) + n1) * 8 + chunk) * 16;
  *(float4*)(dst + 0)  = make_float4(s[0], s[1], s[2], s[3]);
  *(float4*)(dst + 4)  = make_float4(s[4], s[5], s[6], s[7]);
  *(float4*)(dst + 8)  = make_float4(s[8], s[9], s[10], s[11]);
  *(float4*)(dst + 12) = make_float4(s[12], s[13], s[14], s[15]);
}

// knn_merge: 1 thread per query; T = 16th smallest of the 8x16 partials
__global__ __launch_bounds__(256) void knn_merge(const float* __restrict__ pvals,
                                                 float* __restrict__ Tarr) {
  int q = blockIdx.x * 256 + threadIdx.x;   // over 32768 queries
  const float* src = pvals + (size_t)q * 128;
  float s[16];
  #pragma unroll
  for (int i = 0; i < 16; ++i) s[i] = 3.0e38f;
  for (int t = 0; t < 128; t += 4) {
    float4 v = *(const float4*)(src + t);
    float vv[4] = {v.x, v.y, v.z, v.w};
    #pragma unroll
    for (int u = 0; u < 4; ++u) {
      float d = vv[u];
      #pragma unroll
      for (int i = 0; i < 15; ++i) s[i] = fmaxf(s[i + 1], fminf(s[i], d));
      s[15] = fminf(s[15], d);
    }
  }
  Tarr[q] = s[0];
}

// knn_cand: chunk-split index recovery (d<=T, ascending within chunk, cap 16)
__global__ __launch_bounds__(64) void knn_cand(const float4* __restrict__ p1f4,
                                               const float4* __restrict__ p2f4,
                                               const float* __restrict__ Tarr,
                                               int* __restrict__ cidx,
                                               int* __restrict__ ccnt) {
  int lane = threadIdx.x;
  int blk = blockIdx.x;
  int chunk = blk & 7;
  int grp = (blk >> 3) & 63;
  int b = blk >> 9;
  int n1 = (grp << 6) + lane;
  int q = (b << 12) + n1;
  float4 qq = p1f4[q];
  float ax = qq.x, ay = qq.y, az = qq.z;
  const float4* pb = p2f4 + ((size_t)b << 12) + (chunk << 9);
  float T = Tarr[q];
  int cnt = 0;
  int base = ((size_t)q * 8 + chunk) * 16;
  #pragma unroll 4
  for (int t = 0; t < 512; ++t) {
    float4 c = pb[t];
    float dx = ax - c.x, dy = ay - c.y, dz = az - c.z;
    float d = __fadd_rn(__fadd_rn(__fmul_rn(dx, dx), __fmul_rn(dy, dy)), __fmul_rn(dz, dz));
    if (d <= T && cnt < 16) { cidx[base + cnt] = (chunk << 9) + t; ++cnt; }
  }
  ccnt[q * 8 + chunk] = cnt;
}

// knn_combine: ascending-chunk prefix fill to exactly 16 (== top_k tie-break)
__global__ __launch_bounds__(256) void knn_combine(const int* __restrict__ cidx,
                                                   const int* __restrict__ ccnt,
                                                   int* __restrict__ idxout) {
  int q = blockIdx.x * 256 + threadIdx.x;
  int tot = 0;
  int ob = q * 16;
  for (int c = 0; c < 8; ++c) {
    int m = ccnt[q * 8 + c];
    const int* src = cidx + ((size_t)q * 8 + c) * 16;
    for (int i = 0; i < m && tot < 16; ++i) idxout[ob + tot++] = src[i];
  }
}

// ---------------- P[bn][o] = sum_c W0[o][coff+c] * f[b][c][n] (+bias) ----------------
__global__ __launch_bounds__(256) void pkern(const float* __restrict__ f,
                                             const float* __restrict__ W0,
                                             const float* __restrict__ bias,
                                             float* __restrict__ P, int coff) {
  __shared__ float fx[32 * 65];                  // [n][c], pad 65
  __shared__ __align__(16) float Wl[64 * 132];   // [c][o], pad 132
  int tid = threadIdx.x;
  int bn0 = blockIdx.x * 32;
  int b = bn0 >> 12, nb0 = bn0 & (N_ - 1);

  for (int u = tid; u < 32 * 64; u += 256) {
    int c = u >> 5, nl = u & 31;                 // coalesced along n
    fx[nl * 65 + c] = f[((size_t)b * C_ + c) * N_ + nb0 + nl];
  }
  for (int u = tid; u < 128 * 64; u += 256) {
    int o = u >> 6, c = u & 63;
    Wl[c * 132 + o] = W0[o * 131 + coff + c];
  }
  __syncthreads();

  int og = tid & 15, np_ = tid >> 4;
  int o0 = og * 8;
  int na = np_ * 2, nb = na + 1;
  float acc0[8], acc1[8];
  #pragma unroll
  for (int j = 0; j < 8; ++j) {
    float bv = bias ? bias[o0 + j] : 0.f;
    acc0[j] = bv; acc1[j] = bv;
  }
  for (int c = 0; c < 64; ++c) {
    float x0 = fx[na * 65 + c], x1 = fx[nb * 65 + c];
    float4 wa = *(const float4*)&Wl[c * 132 + o0];
    float4 wb = *(const float4*)&Wl[c * 132 + o0 + 4];
    float w[8] = {wa.x, wa.y, wa.z, wa.w, wb.x, wb.y, wb.z, wb.w};
    #pragma unroll
    for (int j = 0; j < 8; ++j) {
      acc0[j] = fmaf(x0, w[j], acc0[j]);
      acc1[j] = fmaf(x1, w[j], acc1[j]);
    }
  }
  float* Pa = P + (size_t)(bn0 + na) * 128 + o0;
  float* Pb = P + (size_t)(bn0 + nb) * 128 + o0;
  *(float4*)Pa = make_float4(acc0[0], acc0[1], acc0[2], acc0[3]);
  *(float4*)(Pa + 4) = make_float4(acc0[4], acc0[5], acc0[6], acc0[7]);
  *(float4*)Pb = make_float4(acc1[0], acc1[1], acc1[2], acc1[3]);
  *(float4*)(Pb + 4) = make_float4(acc1[4], acc1[5], acc1[6], acc1[7]);
}

// ---------------- BN0 stats over x0 = P1 + P2[idx] + W0a*rel_xyz ----------------
__global__ __launch_bounds__(256) void stats0_kernel(
    const float* __restrict__ P1, const float* __restrict__ P2,
    const int* __restrict__ idx, const float4* __restrict__ p1f4,
    const float4* __restrict__ p2f4, const float* __restrict__ w0at,
    float* __restrict__ stats) {
  int tid = threadIdx.x;
  int c = tid & 127, h = tid >> 7;
  float w0 = w0at[c], w1 = w0at[128 + c], w2 = w0at[256 + c];
  float sum = 0.f, sq = 0.f;
  int rbase = blockIdx.x * 256 + h * 128;
  for (int i = 0; i < 128; ++i) {
    int r = rbase + i;
    int b = r >> 16;
    int nk = r & (NK_ - 1);
    int n = nk >> 4;
    int j = idx[r];
    float4 pq = p1f4[(b << 12) + n];
    float4 pj = p2f4[(b << 12) + j];
    float rx = pj.x - pq.x, ry = pj.y - pq.y, rz = pj.z - pq.z;
    float a0 = w0 * rx + w1 * ry + w2 * rz;
    float x = P1[(size_t)((b << 12) + n) * 128 + c] +
              P2[(size_t)((b << 12) + j) * 128 + c] + a0;
    sum += x;
    sq = fmaf(x, x, sq);
  }
  __shared__ float red[256 * 2];
  red[tid * 2] = sum;
  red[tid * 2 + 1] = sq;
  __syncthreads();
  if (h == 0) {
    atomicAdd(stats + c, sum + red[(tid + 128) * 2]);
    atomicAdd(stats + 128 + c, sq + red[(tid + 128) * 2 + 1]);
  }
}

// ---------------- BN finalize: s = gamma*rsqrt(var+eps), t = beta - mean*s ----------------
__global__ void bnfin_kernel(const float* __restrict__ stats, const float* __restrict__ gamma,
                             const float* __restrict__ beta, float* __restrict__ bnp) {
  int o = threadIdx.x;  // 128
  const float invM = 1.0f / (float)M_;
  float mean = stats[o] * invM;
  float var = stats[128 + o] * invM - mean * mean;
  float s = gamma[o] * rsqrtf(var + BN_EPS_);
  bnp[o] = s;
  bnp[128 + o] = beta[o] - mean * s;
}

// ---------------- layer1: assemble x0 -> BN0+relu -> GEMM W1 -> x1(bf16) + stats1 ----------------
__global__ __launch_bounds__(256) void layer1_kernel(
    const float* __restrict__ P1, const float* __restrict__ P2,
    const int* __restrict__ idx, const float4* __restrict__ p1f4,
    const float4* __restrict__ p2f4, const float* __restrict__ w0at,
    const float* __restrict__ bnp0, const float* __restrict__ W1t,
    const float* __restrict__ b1, unsigned short* __restrict__ x1out,
    float* __restrict__ stats1) {
  __shared__ __align__(16) float Xs[64 * 128];   // [c_local][row]
  __shared__ __align__(16) float Ws[16 * 128];   // [cc][o]
  __shared__ float sred[4 * 128 * 2];
  int tid = threadIdx.x;
  int R0 = blockIdx.x * 128;
  int b = R0 >> 16;
  int n0 = (R0 & (NK_ - 1)) >> 4;

  int rl = tid & 127;
  int r = R0 + rl;
  int n = n0 + (rl >> 4);
  int j = idx[r];
  float4 pq = p1f4[(b << 12) + n], pj = p2f4[(b << 12) + j];
  float rx = pj.x - pq.x, ry = pj.y - pq.y, rz = pj.z - pq.z;
  const float* P1r = P1 + (size_t)((b << 12) + n) * 128;
  const float* P2r = P2 + (size_t)((b << 12) + j) * 128;

  int tc = tid & 15, tr = tid >> 4;
  float acc[8][8];
  #pragma unroll
  for (int i = 0; i < 8; ++i)
    #pragma unroll
    for (int jj = 0; jj < 8; ++jj) acc[i][jj] = 0.f;

  for (int ch = 0; ch < 2; ++ch) {
    __syncthreads();  // previous half's Xs readers done
    int cbase = ch * 64 + (tid >> 7) * 32;
    #pragma unroll
    for (int u = 0; u < 32; u += 4) {
      int c = cbase + u;
      float4 p1v = *(const float4*)(P1r + c);
      float4 p2v = *(const float4*)(P2r + c);
      float4 wx = *(const float4*)(w0at + c);
      float4 wy = *(const float4*)(w0at + 128 + c);
      float4 wz = *(const float4*)(w0at + 256 + c);
      float4 sv = *(const float4*)(bnp0 + c);
      float4 tv = *(const float4*)(bnp0 + 128 + c);
      float x0 = p1v.x + p2v.x + wx.x * rx + wy.x * ry + wz.x * rz;
      float x1_ = p1v.y + p2v.y + wx.y * rx + wy.y * ry + wz.y * rz;
      float x2_ = p1v.z + p2v.z + wx.z * rx + wy.z * ry + wz.z * rz;
      float x3_ = p1v.w + p2v.w + wx.w * rx + wy.w * ry + wz.w * rz;
      int cl = c - ch * 64;
      Xs[(cl + 0) * 128 + rl] = fmaxf(fmaf(sv.x, x0, tv.x), 0.f);
      Xs[(cl + 1) * 128 + rl] = fmaxf(fmaf(sv.y, x1_, tv.y), 0.f);
      Xs[(cl + 2) * 128 + rl] = fmaxf(fmaf(sv.z, x2_, tv.z), 0.f);
      Xs[(cl + 3) * 128 + rl] = fmaxf(fmaf(sv.w, x3_, tv.w), 0.f);
    }
    for (int kc = 0; kc < 4; ++kc) {
      int f = tid * 8;
      int cc = f >> 7, oo = f & 127;
      int cglob = ch * 64 + kc * 16 + cc;
      float4 wv0 = *(const float4*)(W1t + cglob * 128 + oo);
      float4 wv1 = *(const float4*)(W1t + cglob * 128 + oo + 4);
      __syncthreads();
      *(float4*)(Ws + cc * 128 + oo) = wv0;
      *(float4*)(Ws + cc * 128 + oo + 4) = wv1;
      __syncthreads();
      #pragma unroll
      for (int cc2 = 0; cc2 < 16; ++cc2) {
        int cl = kc * 16 + cc2;
        float4 xa = *(const float4*)(Xs + cl * 128 + tr * 8);
        float4 xb = *(const float4*)(Xs + cl * 128 + tr * 8 + 4);
        float4 wa = *(const float4*)(Ws + cc2 * 128 + tc * 8);
        float4 wb = *(const float4*)(Ws + cc2 * 128 + tc * 8 + 4);
        float xv[8] = {xa.x, xa.y, xa.z, xa.w, xb.x, xb.y, xb.z, xb.w};
        float wv[8] = {wa.x, wa.y, wa.z, wa.w, wb.x, wb.y, wb.z, wb.w};
        #pragma unroll
        for (int i = 0; i < 8; ++i)
          #pragma unroll
          for (int jj = 0; jj < 8; ++jj) acc[i][jj] = fmaf(xv[i], wv[jj], acc[i][jj]);
      }
    }
  }
  // epilogue: y = acc + b1 ; store bf16 ; stats (fp32)
  float bv[8];
  *(float4*)&bv[0] = *(const float4*)(b1 + tc * 8);
  *(float4*)&bv[4] = *(const float4*)(b1 + tc * 8 + 4);
  float ssum[8], ssq[8];
  #pragma unroll
  for (int jj = 0; jj < 8; ++jj) { ssum[jj] = 0.f; ssq[jj] = 0.f; }
  #pragma unroll
  for (int i = 0; i < 8; ++i) {
    int g = R0 + tr * 8 + i;
    float y[8];
    #pragma unroll
    for (int jj = 0; jj < 8; ++jj) {
      y[jj] = acc[i][jj] + bv[jj];
      ssum[jj] += y[jj];
      ssq[jj] = fmaf(y[jj], y[jj], ssq[jj]);
    }
    uint4 pk;
    pk.x = (unsigned)f2bf(y[0]) | ((unsigned)f2bf(y[1]) << 16);
    pk.y = (unsigned)f2bf(y[2]) | ((unsigned)f2bf(y[3]) << 16);
    pk.z = (unsigned)f2bf(y[4]) | ((unsigned)f2bf(y[5]) << 16);
    pk.w = (unsigned)f2bf(y[6]) | ((unsigned)f2bf(y[7]) << 16);
    *(uint4*)(x1out + (size_t)g * 128 + tc * 8) = pk;
  }
  #pragma unroll
  for (int jj = 0; jj < 8; ++jj) {
    ssum[jj] += __shfl_xor(ssum[jj], 16);
    ssum[jj] += __shfl_xor(ssum[jj], 32);
    ssq[jj] += __shfl_xor(ssq[jj], 16);
    ssq[jj] += __shfl_xor(ssq[jj], 32);
  }
  int wv_ = tid >> 6;
  if ((tid & 63) < 16) {
    #pragma unroll
    for (int jj = 0; jj < 8; ++jj) {
      sred[(wv_ * 128 + tc * 8 + jj) * 2] = ssum[jj];
      sred[(wv_ * 128 + tc * 8 + jj) * 2 + 1] = ssq[jj];
    }
  }
  __syncthreads();
  if (tid < 128) {
    float a = 0.f, q2 = 0.f;
    #pragma unroll
    for (int w = 0; w < 4; ++w) {
      a += sred[(w * 128 + tid) * 2];
      q2 += sred[(w * 128 + tid) * 2 + 1];
    }
    atomicAdd(stats1 + tid, a);
    atomicAdd(stats1 + 128 + tid, q2);
  }
}

// ---------------- layer2: BN1+relu -> GEMM W2 -> max/min over k + stats2 ----------------
__global__ __launch_bounds__(256) void layer2_kernel(
    const unsigned short* __restrict__ x1, const float* __restrict__ bnp1,
    const float* __restrict__ W2t, const float* __restrict__ b2,
    float* __restrict__ ymaxo, float* __restrict__ ymino,
    float* __restrict__ stats2) {
  __shared__ __align__(16) float Xs[64 * 128];
  __shared__ __align__(16) float Ws[16 * 128];
  __shared__ float sred[4 * 128 * 2];
  int tid = threadIdx.x;
  int R0 = blockIdx.x * 128;
  int b = R0 >> 16;
  int n0 = (R0 & (NK_ - 1)) >> 4;

  int rl = tid & 127;
  int r = R0 + rl;
  const unsigned short* xr = x1 + (size_t)r * 128;

  int tc = tid & 15, tr = tid >> 4;
  float acc[8][8];
  #pragma unroll
  for (int i = 0; i < 8; ++i)
    #pragma unroll
    for (int jj = 0; jj < 8; ++jj) acc[i][jj] = 0.f;

  for (int ch = 0; ch < 2; ++ch) {
    __syncthreads();
    int cbase = ch * 64 + (tid >> 7) * 32;
    #pragma unroll
    for (int u = 0; u < 32; u += 4) {
      int c = cbase + u;
      uint2 pv = *(const uint2*)(xr + c);          // 4 bf16
      float xv0 = __uint_as_float(pv.x << 16);
      float xv1 = __uint_as_float(pv.x & 0xFFFF0000u);
      float xv2 = __uint_as_float(pv.y << 16);
      float xv3 = __uint_as_float(pv.y & 0xFFFF0000u);
      float4 sv = *(const float4*)(bnp1 + c);
      float4 tv = *(const float4*)(bnp1 + 128 + c);
      int cl = c - ch * 64;
      Xs[(cl + 0) * 128 + rl] = fmaxf(fmaf(sv.x, xv0, tv.x), 0.f);
      Xs[(cl + 1) * 128 + rl] = fmaxf(fmaf(sv.y, xv1, tv.y), 0.f);
      Xs[(cl + 2) * 128 + rl] = fmaxf(fmaf(sv.z, xv2, tv.z), 0.f);
      Xs[(cl + 3) * 128 + rl] = fmaxf(fmaf(sv.w, xv3, tv.w), 0.f);
    }
    for (int kc = 0; kc < 4; ++kc) {
      int f = tid * 8;
      int cc = f >> 7, oo = f & 127;
      int cglob = ch * 64 + kc * 16 + cc;
      float4 wv0 = *(const float4*)(W2t + cglob * 128 + oo);
      float4 wv1 = *(const float4*)(W2t + cglob * 128 + oo + 4);
      __syncthreads();
      *(float4*)(Ws + cc * 128 + oo) = wv0;
      *(float4*)(Ws + cc * 128 + oo + 4) = wv1;
      __syncthreads();
      #pragma unroll
      for (int cc2 = 0; cc2 < 16; ++cc2) {
        int cl = kc * 16 + cc2;
        float4 xa = *(const float4*)(Xs + cl * 128 + tr * 8);
        float4 xb = *(const float4*)(Xs + cl * 128 + tr * 8 + 4);
        float4 wa = *(const float4*)(Ws + cc2 * 128 + tc * 8);
        float4 wb = *(const float4*)(Ws + cc2 * 128 + tc * 8 + 4);
        float xv[8] = {xa.x, xa.y, xa.z, xa.w, xb.x, xb.y, xb.z, xb.w};
        float wv[8] = {wa.x, wa.y, wa.z, wa.w, wb.x, wb.y, wb.z, wb.w};
        #pragma unroll
        for (int i = 0; i < 8; ++i)
          #pragma unroll
          for (int jj = 0; jj < 8; ++jj) acc[i][jj] = fmaf(xv[i], wv[jj], acc[i][jj]);
      }
    }
  }
  // epilogue: y = acc + b2 ; stats2 ; per-(n,o) max/min over k=16
  float bv[8];
  *(float4*)&bv[0] = *(const float4*)(b2 + tc * 8);
  *(float4*)&bv[4] = *(const float4*)(b2 + tc * 8 + 4);
  #pragma unroll
  for (int i = 0; i < 8; ++i)
    #pragma unroll
    for (int jj = 0; jj < 8; ++jj) acc[i][jj] += bv[jj];

  float ssum[8], ssq[8], mx[8], mn[8];
  #pragma unroll
  for (int jj = 0; jj < 8; ++jj) {
    ssum[jj] = 0.f; ssq[jj] = 0.f;
    mx[jj] = acc[0][jj]; mn[jj] = acc[0][jj];
  }
  #pragma unroll
  for (int i = 0; i < 8; ++i)
    #pragma unroll
    for (int jj = 0; jj < 8; ++jj) {
      float y = acc[i][jj];
      ssum[jj] += y;
      ssq[jj] = fmaf(y, y, ssq[jj]);
      mx[jj] = fmaxf(mx[jj], y);
      mn[jj] = fminf(mn[jj], y);
    }
  #pragma unroll
  for (int jj = 0; jj < 8; ++jj) {
    mx[jj] = fmaxf(mx[jj], __shfl_xor(mx[jj], 16));
    mn[jj] = fminf(mn[jj], __shfl_xor(mn[jj], 16));
  }
  if ((tr & 1) == 0) {
    int n = n0 + (tr >> 1);
    size_t base = ((size_t)(b << 12) + n) * 128 + tc * 8;
    *(float4*)(ymaxo + base) = make_float4(mx[0], mx[1], mx[2], mx[3]);
    *(float4*)(ymaxo + base + 4) = make_float4(mx[4], mx[5], mx[6], mx[7]);
    *(float4*)(ymino + base) = make_float4(mn[0], mn[1], mn[2], mn[3]);
    *(float4*)(ymino + base + 4) = make_float4(mn[4], mn[5], mn[6], mn[7]);
  }
  #pragma unroll
  for (int jj = 0; jj < 8; ++jj) {
    ssum[jj] += __shfl_xor(ssum[jj], 16);
    ssum[jj] += __shfl_xor(ssum[jj], 32);
    ssq[jj] += __shfl_xor(ssq[jj], 16);
    ssq[jj] += __shfl_xor(ssq[jj], 32);
  }
  int wv_ = tid >> 6;
  if ((tid & 63) < 16) {
    #pragma unroll
    for (int jj = 0; jj < 8; ++jj) {
      sred[(wv_ * 128 + tc * 8 + jj) * 2] = ssum[jj];
      sred[(wv_ * 128 + tc * 8 + jj) * 2 + 1] = ssq[jj];
    }
  }
  __syncthreads();
  if (tid < 128) {
    float a = 0.f, q2 = 0.f;
    #pragma unroll
    for (int w = 0; w < 4; ++w) {
      a += sred[(w * 128 + tid) * 2];
      q2 += sred[(w * 128 + tid) * 2 + 1];
    }
    atomicAdd(stats2 + tid, a);
    atomicAdd(stats2 + 128 + tid, q2);
  }
}

// ---------------- final: BN2+relu on max/min, transpose to (B,128,N) ----------------
__global__ __launch_bounds__(256) void final_kernel(const float* __restrict__ ymaxo,
                                                    const float* __restrict__ ymino,
                                                    const float* __restrict__ bnp2,
                                                    float* __restrict__ out) {
  __shared__ float T[64 * 129];
  int tid = threadIdx.x;
  int b = blockIdx.x >> 6;
  int n0 = (blockIdx.x & 63) * 64;
  for (int u = tid; u < 64 * 128; u += 256) {
    int nl = u >> 7, o = u & 127;
    size_t base = ((size_t)(b << 12) + n0 + nl) * 128 + o;
    float s = bnp2[o], t = bnp2[128 + o];
    float v = fmaf(s, (s >= 0.f ? ymaxo[base] : ymino[base]), t);
    T[nl * 129 + o] = fmaxf(v, 0.f);
  }
  __syncthreads();
  for (int u = tid; u < 64 * 128; u += 256) {
    int o = u >> 6, nl = u & 63;
    out[((size_t)b * 128 + o) * N_ + n0 + nl] = T[nl * 129 + o];
  }
}

extern "C" void kernel_launch(void* const* d_in, const int* in_sizes, int n_in,
                              void* d_out, int out_size, void* d_ws, size_t ws_size,
                              hipStream_t stream) {
  (void)in_sizes; (void)n_in; (void)out_size; (void)ws_size;
  const float* points1 = (const float*)d_in[0];
  const float* points2 = (const float*)d_in[1];
  const float* features1 = (const float*)d_in[2];
  const float* features2 = (const float*)d_in[3];
  const float* W0 = (const float*)d_in[4];
  const float* b0 = (const float*)d_in[5];
  const float* g0 = (const float*)d_in[6];
  const float* be0 = (const float*)d_in[7];
  const float* W1 = (const float*)d_in[8];
  const float* b1 = (const float*)d_in[9];
  const float* g1 = (const float*)d_in[10];
  const float* be1 = (const float*)d_in[11];
  const float* W2 = (const float*)d_in[12];
  const float* b2 = (const float*)d_in[13];
  const float* g2 = (const float*)d_in[14];
  const float* be2 = (const float*)d_in[15];
  float* out = (float*)d_out;

  char* ws = (char*)d_ws;
  size_t off = 0;
  auto alloc = [&](size_t bytes) -> void* {
    void* p = ws + off;
    off += (bytes + 255) & ~(size_t)255;
    return p;
  };
  // total workspace: ~195 MB
  int* idx = (int*)alloc((size_t)M_ * 4);                          // 2 MB
  float4* p1f4 = (float4*)alloc((size_t)B_ * N_ * 16);             // 0.5 MB
  float4* p2f4 = (float4*)alloc((size_t)B_ * N_ * 16);             // 0.5 MB
  float* P1 = (float*)alloc((size_t)B_ * N_ * 128 * 4);            // 16 MB
  float* P2 = (float*)alloc((size_t)B_ * N_ * 128 * 4);            // 16 MB
  float* W1t = (float*)alloc(128 * 128 * 4);
  float* W2t = (float*)alloc(128 * 128 * 4);
  float* w0at = (float*)alloc(3 * 128 * 4);
  float* stats = (float*)alloc(3 * 256 * 4);
  float* bnp = (float*)alloc(3 * 256 * 4);
  unsigned short* x1 = (unsigned short*)alloc((size_t)M_ * 128 * 2);  // 128 MB (bf16)
  float* ymaxo = (float*)alloc((size_t)B_ * N_ * 128 * 4);         // 16 MB
  float* ymino = (float*)alloc((size_t)B_ * N_ * 128 * 4);         // 16 MB

  // KNN scratch aliased onto x1 (dead until layer1): 33.2 MB < 128 MB
  float* pvals = (float*)x1;                                        // 16 MB
  int* cidx = (int*)((char*)x1 + (size_t)16 * 1024 * 1024);         // 16 MB
  int* ccnt = (int*)((char*)x1 + (size_t)32 * 1024 * 1024);         // 1 MB
  float* Tarr = (float*)((char*)x1 + (size_t)33 * 1024 * 1024);     // 128 KB

  hipMemsetAsync(stats, 0, 3 * 256 * 4, stream);

  pack_pts<<<B_ * N_ / 256, 256, 0, stream>>>(points1, p1f4);
  pack_pts<<<B_ * N_ / 256, 256, 0, stream>>>(points2, p2f4);
  transpose_w<<<dim3(4, 4), dim3(32, 8), 0, stream>>>(W1, W1t);
  transpose_w<<<dim3(4, 4), dim3(32, 8), 0, stream>>>(W2, W2t);
  make_w0at<<<1, 128, 0, stream>>>(W0, w0at);

  // KNN: candidate-split 8x
  knn_part<<<B_ * 64 * 8, 64, 0, stream>>>(p1f4, p2f4, pvals);
  knn_merge<<<B_ * N_ / 256, 256, 0, stream>>>(pvals, Tarr);
  knn_cand<<<B_ * 64 * 8, 64, 0, stream>>>(p1f4, p2f4, Tarr, cidx, ccnt);
  knn_combine<<<B_ * N_ / 256, 256, 0, stream>>>(cidx, ccnt, idx);

  pkern<<<B_ * N_ / 32, 256, 0, stream>>>(features1, W0, b0, P1, 67);
  pkern<<<B_ * N_ / 32, 256, 0, stream>>>(features2, W0, nullptr, P2, 3);

  stats0_kernel<<<M_ / 256, 256, 0, stream>>>(P1, P2, idx, p1f4, p2f4, w0at, stats);
  bnfin_kernel<<<1, 128, 0, stream>>>(stats, g0, be0, bnp);

  layer1_kernel<<<M_ / 128, 256, 0, stream>>>(P1, P2, idx, p1f4, p2f4, w0at, bnp,
                                              W1t, b1, x1, stats + 256);
  bnfin_kernel<<<1, 128, 0, stream>>>(stats + 256, g1, be1, bnp + 256);

  layer2_kernel<<<M_ / 128, 256, 0, stream>>>(x1, bnp + 256, W2t, b2, ymaxo, ymino,
                                              stats + 512);
  bnfin_kernel<<<1, 128, 0, stream>>>(stats + 512, g2, be2, bnp + 512);

  final_kernel<<<B_ * N_ / 64, 256, 0, stream>>>(ymaxo, ymino, bnp + 512, out);
}

// Round 4
// 847.456 us; speedup vs baseline: 1.7533x; 1.3174x over previous
//
#include <hip/hip_runtime.h>

#define B_ 8
#define N_ 4096
#define K_ 16
#define C_ 64
#define NK_ (N_*K_)            // 65536
#define M_ (B_*N_*K_)          // 524288
#define BN_EPS_ 0.001f

typedef short bf16x8 __attribute__((ext_vector_type(8)));   // 8 bf16 = 4 VGPRs
typedef float f32x4 __attribute__((ext_vector_type(4)));

// bf16 round-to-nearest-even (no NaN inputs in this pipeline)
static __device__ __forceinline__ unsigned short f2bf(float x) {
  unsigned u = __float_as_uint(x);
  unsigned r = (u + 0x7FFFu + ((u >> 16) & 1u)) >> 16;
  return (unsigned short)r;
}
static __device__ __forceinline__ unsigned pk2bf(float a, float b) {
  return (unsigned)f2bf(a) | ((unsigned)f2bf(b) << 16);
}

// ---------------- pack points (B,3,N) -> float4 (B*N) ----------------
__global__ __launch_bounds__(256) void pack_pts(const float* __restrict__ p,
                                                float4* __restrict__ pf4) {
  int i = blockIdx.x * 256 + threadIdx.x;
  int b = i >> 12;
  int n = i & (N_ - 1);
  const float* base = p + (size_t)b * 3 * N_;
  pf4[i] = make_float4(base[n], base[N_ + n], base[2 * N_ + n], 0.f);
}

// ---------------- W (128x128 fp32) -> bf16 same layout ----------------
__global__ __launch_bounds__(256) void wcvt(const float* __restrict__ W,
                                            unsigned short* __restrict__ Wb) {
  int i = blockIdx.x * 256 + threadIdx.x;   // 16384
  Wb[i] = f2bf(W[i]);
}

// ---------------- w0at[d][o] = W0[o][d], d<3 ----------------
__global__ void make_w0at(const float* __restrict__ W0, float* __restrict__ w0at) {
  int o = threadIdx.x;  // 128
  for (int d = 0; d < 3; ++d) w0at[d * 128 + o] = W0[o * 131 + d];
}

// ================= KNN, candidate-split 8 ways =================
__global__ __launch_bounds__(64) void knn_part(const float4* __restrict__ p1f4,
                                               const float4* __restrict__ p2f4,
                                               float* __restrict__ pvals) {
  int lane = threadIdx.x;
  int blk = blockIdx.x;
  int chunk = blk & 7;
  int grp = (blk >> 3) & 63;
  int b = blk >> 9;
  int n1 = (grp << 6) + lane;
  float4 q = p1f4[(b << 12) + n1];
  float ax = q.x, ay = q.y, az = q.z;
  const float4* pb = p2f4 + ((size_t)b << 12) + (chunk << 9);

  float s[16];
  #pragma unroll
  for (int i = 0; i < 16; ++i) s[i] = 3.0e38f;

  #pragma unroll 4
  for (int t = 0; t < 512; ++t) {
    float4 c = pb[t];              // wave-uniform -> scalar load
    float dx = ax - c.x, dy = ay - c.y, dz = az - c.z;
    float d = __fadd_rn(__fadd_rn(__fmul_rn(dx, dx), __fmul_rn(dy, dy)), __fmul_rn(dz, dz));
    #pragma unroll
    for (int i = 0; i < 15; ++i) s[i] = fmaxf(s[i + 1], fminf(s[i], d));
    s[15] = fminf(s[15], d);
  }
  float* dst = pvals + ((size_t)((b << 12) + n1) * 8 + chunk) * 16;
  *(float4*)(dst + 0)  = make_float4(s[0], s[1], s[2], s[3]);
  *(float4*)(dst + 4)  = make_float4(s[4], s[5], s[6], s[7]);
  *(float4*)(dst + 8)  = make_float4(s[8], s[9], s[10], s[11]);
  *(float4*)(dst + 12) = make_float4(s[12], s[13], s[14], s[15]);
}

__global__ __launch_bounds__(256) void knn_merge(const float* __restrict__ pvals,
                                                 float* __restrict__ Tarr) {
  int q = blockIdx.x * 256 + threadIdx.x;
  const float* src = pvals + (size_t)q * 128;
  float s[16];
  #pragma unroll
  for (int i = 0; i < 16; ++i) s[i] = 3.0e38f;
  for (int t = 0; t < 128; t += 4) {
    float4 v = *(const float4*)(src + t);
    float vv[4] = {v.x, v.y, v.z, v.w};
    #pragma unroll
    for (int u = 0; u < 4; ++u) {
      float d = vv[u];
      #pragma unroll
      for (int i = 0; i < 15; ++i) s[i] = fmaxf(s[i + 1], fminf(s[i], d));
      s[15] = fminf(s[15], d);
    }
  }
  Tarr[q] = s[0];
}

__global__ __launch_bounds__(64) void knn_cand(const float4* __restrict__ p1f4,
                                               const float4* __restrict__ p2f4,
                                               const float* __restrict__ Tarr,
                                               int* __restrict__ cidx,
                                               int* __restrict__ ccnt) {
  int lane = threadIdx.x;
  int blk = blockIdx.x;
  int chunk = blk & 7;
  int grp = (blk >> 3) & 63;
  int b = blk >> 9;
  int n1 = (grp << 6) + lane;
  int q = (b << 12) + n1;
  float4 qq = p1f4[q];
  float ax = qq.x, ay = qq.y, az = qq.z;
  const float4* pb = p2f4 + ((size_t)b << 12) + (chunk << 9);
  float T = Tarr[q];
  int cnt = 0;
  int base = ((size_t)q * 8 + chunk) * 16;
  #pragma unroll 4
  for (int t = 0; t < 512; ++t) {
    float4 c = pb[t];
    float dx = ax - c.x, dy = ay - c.y, dz = az - c.z;
    float d = __fadd_rn(__fadd_rn(__fmul_rn(dx, dx), __fmul_rn(dy, dy)), __fmul_rn(dz, dz));
    if (d <= T && cnt < 16) { cidx[base + cnt] = (chunk << 9) + t; ++cnt; }
  }
  ccnt[q * 8 + chunk] = cnt;
}

__global__ __launch_bounds__(256) void knn_combine(const int* __restrict__ cidx,
                                                   const int* __restrict__ ccnt,
                                                   int* __restrict__ idxout) {
  int q = blockIdx.x * 256 + threadIdx.x;
  int tot = 0;
  int ob = q * 16;
  for (int c = 0; c < 8; ++c) {
    int m = ccnt[q * 8 + c];
    const int* src = cidx + ((size_t)q * 8 + c) * 16;
    for (int i = 0; i < m && tot < 16; ++i) idxout[ob + tot++] = src[i];
  }
}

// ---------------- P[bn][o] = sum_c W0[o][coff+c] * f[b][c][n] (+bias) ----------------
__global__ __launch_bounds__(256) void pkern(const float* __restrict__ f,
                                             const float* __restrict__ W0,
                                             const float* __restrict__ bias,
                                             float* __restrict__ P, int coff) {
  __shared__ float fx[32 * 65];
  __shared__ __align__(16) float Wl[64 * 132];
  int tid = threadIdx.x;
  int bn0 = blockIdx.x * 32;
  int b = bn0 >> 12, nb0 = bn0 & (N_ - 1);

  for (int u = tid; u < 32 * 64; u += 256) {
    int c = u >> 5, nl = u & 31;
    fx[nl * 65 + c] = f[((size_t)b * C_ + c) * N_ + nb0 + nl];
  }
  for (int u = tid; u < 128 * 64; u += 256) {
    int o = u >> 6, c = u & 63;
    Wl[c * 132 + o] = W0[o * 131 + coff + c];
  }
  __syncthreads();

  int og = tid & 15, np_ = tid >> 4;
  int o0 = og * 8;
  int na = np_ * 2, nb = na + 1;
  float acc0[8], acc1[8];
  #pragma unroll
  for (int j = 0; j < 8; ++j) {
    float bv = bias ? bias[o0 + j] : 0.f;
    acc0[j] = bv; acc1[j] = bv;
  }
  for (int c = 0; c < 64; ++c) {
    float x0 = fx[na * 65 + c], x1 = fx[nb * 65 + c];
    float4 wa = *(const float4*)&Wl[c * 132 + o0];
    float4 wb = *(const float4*)&Wl[c * 132 + o0 + 4];
    float w[8] = {wa.x, wa.y, wa.z, wa.w, wb.x, wb.y, wb.z, wb.w};
    #pragma unroll
    for (int j = 0; j < 8; ++j) {
      acc0[j] = fmaf(x0, w[j], acc0[j]);
      acc1[j] = fmaf(x1, w[j], acc1[j]);
    }
  }
  float* Pa = P + (size_t)(bn0 + na) * 128 + o0;
  float* Pb = P + (size_t)(bn0 + nb) * 128 + o0;
  *(float4*)Pa = make_float4(acc0[0], acc0[1], acc0[2], acc0[3]);
  *(float4*)(Pa + 4) = make_float4(acc0[4], acc0[5], acc0[6], acc0[7]);
  *(float4*)Pb = make_float4(acc1[0], acc1[1], acc1[2], acc1[3]);
  *(float4*)(Pb + 4) = make_float4(acc1[4], acc1[5], acc1[6], acc1[7]);
}

// ---------------- BN0 stats over x0 = P1 + P2[idx] + W0a*rel_xyz ----------------
__global__ __launch_bounds__(256) void stats0_kernel(
    const float* __restrict__ P1, const float* __restrict__ P2,
    const int* __restrict__ idx, const float4* __restrict__ p1f4,
    const float4* __restrict__ p2f4, const float* __restrict__ w0at,
    float* __restrict__ stats) {
  int tid = threadIdx.x;
  int c = tid & 127, h = tid >> 7;
  float w0 = w0at[c], w1 = w0at[128 + c], w2 = w0at[256 + c];
  float sum = 0.f, sq = 0.f;
  int rbase = blockIdx.x * 256 + h * 128;
  for (int i = 0; i < 128; ++i) {
    int r = rbase + i;
    int b = r >> 16;
    int nk = r & (NK_ - 1);
    int n = nk >> 4;
    int j = idx[r];
    float4 pq = p1f4[(b << 12) + n];
    float4 pj = p2f4[(b << 12) + j];
    float rx = pj.x - pq.x, ry = pj.y - pq.y, rz = pj.z - pq.z;
    float a0 = w0 * rx + w1 * ry + w2 * rz;
    float x = P1[(size_t)((b << 12) + n) * 128 + c] +
              P2[(size_t)((b << 12) + j) * 128 + c] + a0;
    sum += x;
    sq = fmaf(x, x, sq);
  }
  __shared__ float red[256 * 2];
  red[tid * 2] = sum;
  red[tid * 2 + 1] = sq;
  __syncthreads();
  if (h == 0) {
    atomicAdd(stats + c, sum + red[(tid + 128) * 2]);
    atomicAdd(stats + 128 + c, sq + red[(tid + 128) * 2 + 1]);
  }
}

// ---------------- BN finalize ----------------
__global__ void bnfin_kernel(const float* __restrict__ stats, const float* __restrict__ gamma,
                             const float* __restrict__ beta, float* __restrict__ bnp) {
  int o = threadIdx.x;
  const float invM = 1.0f / (float)M_;
  float mean = stats[o] * invM;
  float var = stats[128 + o] * invM - mean * mean;
  float s = gamma[o] * rsqrtf(var + BN_EPS_);
  bnp[o] = s;
  bnp[128 + o] = beta[o] - mean * s;
}

// ---------------- layer1 (MFMA): assemble x0 -> BN0+relu -> bf16 GEMM W1 -> x1(bf16) + stats1 ----------------
__global__ __launch_bounds__(256) void layer1_mfma(
    const float* __restrict__ P1, const float* __restrict__ P2,
    const int* __restrict__ idx, const float4* __restrict__ p1f4,
    const float4* __restrict__ p2f4, const float* __restrict__ w0at,
    const float* __restrict__ bnp0, const unsigned short* __restrict__ W1b,
    const float* __restrict__ b1, unsigned short* __restrict__ x1out,
    float* __restrict__ stats1) {
  __shared__ __align__(16) unsigned short Xs[128 * 136];   // [row][k], pad 8 bf16
  __shared__ float sred[4 * 128 * 2];
  int tid = threadIdx.x;
  int R0 = blockIdx.x * 128;
  int b = R0 >> 16;
  int n0 = (R0 & (NK_ - 1)) >> 4;

  // ---- stage X (bf16) ----
  {
    int rl = tid & 127;
    int r = R0 + rl;
    int n = n0 + (rl >> 4);
    int j = idx[r];
    float4 pq = p1f4[(b << 12) + n], pj = p2f4[(b << 12) + j];
    float rx = pj.x - pq.x, ry = pj.y - pq.y, rz = pj.z - pq.z;
    const float* P1r = P1 + (size_t)((b << 12) + n) * 128;
    const float* P2r = P2 + (size_t)((b << 12) + j) * 128;
    int kh = (tid >> 7) * 64;   // wave-pair uniform
    #pragma unroll
    for (int ci = 0; ci < 64; ci += 8) {
      int c = kh + ci;
      float p1v[8], p2v[8], wxv[8], wyv[8], wzv[8], svv[8], tvv[8];
      *(float4*)&p1v[0] = *(const float4*)(P1r + c);       *(float4*)&p1v[4] = *(const float4*)(P1r + c + 4);
      *(float4*)&p2v[0] = *(const float4*)(P2r + c);       *(float4*)&p2v[4] = *(const float4*)(P2r + c + 4);
      *(float4*)&wxv[0] = *(const float4*)(w0at + c);      *(float4*)&wxv[4] = *(const float4*)(w0at + c + 4);
      *(float4*)&wyv[0] = *(const float4*)(w0at + 128 + c);*(float4*)&wyv[4] = *(const float4*)(w0at + 132 + c);
      *(float4*)&wzv[0] = *(const float4*)(w0at + 256 + c);*(float4*)&wzv[4] = *(const float4*)(w0at + 260 + c);
      *(float4*)&svv[0] = *(const float4*)(bnp0 + c);      *(float4*)&svv[4] = *(const float4*)(bnp0 + c + 4);
      *(float4*)&tvv[0] = *(const float4*)(bnp0 + 128 + c);*(float4*)&tvv[4] = *(const float4*)(bnp0 + 132 + c);
      float y[8];
      #pragma unroll
      for (int u = 0; u < 8; ++u) {
        float x = p1v[u] + p2v[u] + wxv[u] * rx + wyv[u] * ry + wzv[u] * rz;
        y[u] = fmaxf(fmaf(svv[u], x, tvv[u]), 0.f);
      }
      uint4 pk;
      pk.x = pk2bf(y[0], y[1]); pk.y = pk2bf(y[2], y[3]);
      pk.z = pk2bf(y[4], y[5]); pk.w = pk2bf(y[6], y[7]);
      *(uint4*)&Xs[rl * 136 + c] = pk;
    }
  }
  __syncthreads();

  // ---- MFMA: wave w computes rows [w*32, w*32+32) x all 128 cols ----
  int w = tid >> 6, lane = tid & 63;
  int m16 = lane & 15, qd = lane >> 4;
  f32x4 acc[2][8];
  #pragma unroll
  for (int mt = 0; mt < 2; ++mt)
    #pragma unroll
    for (int nt = 0; nt < 8; ++nt) acc[mt][nt] = (f32x4){0.f, 0.f, 0.f, 0.f};

  const unsigned short* Ab = &Xs[(w * 32 + m16) * 136 + qd * 8];
  const unsigned short* Bb = W1b + m16 * 128 + qd * 8;
  #pragma unroll 1
  for (int q = 0; q < 4; ++q) {
    bf16x8 A0 = *(const bf16x8*)(Ab + q * 32);
    bf16x8 A1 = *(const bf16x8*)(Ab + 16 * 136 + q * 32);
    #pragma unroll
    for (int nt = 0; nt < 8; ++nt) {
      bf16x8 Bv = *(const bf16x8*)(Bb + nt * 16 * 128 + q * 32);
      acc[0][nt] = __builtin_amdgcn_mfma_f32_16x16x32_bf16(A0, Bv, acc[0][nt], 0, 0, 0);
      acc[1][nt] = __builtin_amdgcn_mfma_f32_16x16x32_bf16(A1, Bv, acc[1][nt], 0, 0, 0);
    }
  }

  // ---- epilogue: bias, stats, bf16 store (D: col=lane&15, row=qd*4+reg) ----
  float ssum[8], ssq[8];
  #pragma unroll
  for (int nt = 0; nt < 8; ++nt) { ssum[nt] = 0.f; ssq[nt] = 0.f; }
  #pragma unroll
  for (int nt = 0; nt < 8; ++nt) {
    int col = nt * 16 + m16;
    float bb = b1[col];
    #pragma unroll
    for (int mt = 0; mt < 2; ++mt) {
      #pragma unroll
      for (int rg = 0; rg < 4; ++rg) {
        float y = acc[mt][nt][rg] + bb;
        ssum[nt] += y;
        ssq[nt] = fmaf(y, y, ssq[nt]);
        int row = R0 + w * 32 + mt * 16 + qd * 4 + rg;
        x1out[(size_t)row * 128 + col] = f2bf(y);
      }
    }
  }
  #pragma unroll
  for (int nt = 0; nt < 8; ++nt) {
    ssum[nt] += __shfl_xor(ssum[nt], 16);
    ssum[nt] += __shfl_xor(ssum[nt], 32);
    ssq[nt] += __shfl_xor(ssq[nt], 16);
    ssq[nt] += __shfl_xor(ssq[nt], 32);
  }
  if (lane < 16) {
    #pragma unroll
    for (int nt = 0; nt < 8; ++nt) {
      sred[(w * 128 + nt * 16 + lane) * 2] = ssum[nt];
      sred[(w * 128 + nt * 16 + lane) * 2 + 1] = ssq[nt];
    }
  }
  __syncthreads();
  if (tid < 128) {
    float a = 0.f, q2 = 0.f;
    #pragma unroll
    for (int ww = 0; ww < 4; ++ww) {
      a += sred[(ww * 128 + tid) * 2];
      q2 += sred[(ww * 128 + tid) * 2 + 1];
    }
    atomicAdd(stats1 + tid, a);
    atomicAdd(stats1 + 128 + tid, q2);
  }
}

// ---------------- layer2 (MFMA): BN1+relu -> bf16 GEMM W2 -> k-max/min + stats2 ----------------
__global__ __launch_bounds__(256) void layer2_mfma(
    const unsigned short* __restrict__ x1, const float* __restrict__ bnp1,
    const unsigned short* __restrict__ W2b, const float* __restrict__ b2,
    float* __restrict__ ymaxo, float* __restrict__ ymino,
    float* __restrict__ stats2) {
  __shared__ __align__(16) unsigned short Xs[128 * 136];
  __shared__ float sred[4 * 128 * 2];
  int tid = threadIdx.x;
  int R0 = blockIdx.x * 128;
  int b = R0 >> 16;
  int n0 = (R0 & (NK_ - 1)) >> 4;

  // ---- stage X (bf16): BN1+relu on x1 ----
  {
    int rl = tid & 127;
    int r = R0 + rl;
    const unsigned short* xr = x1 + (size_t)r * 128;
    int kh = (tid >> 7) * 64;
    #pragma unroll
    for (int ci = 0; ci < 64; ci += 8) {
      int c = kh + ci;
      uint4 pv = *(const uint4*)(xr + c);
      float xv[8];
      xv[0] = __uint_as_float(pv.x << 16); xv[1] = __uint_as_float(pv.x & 0xFFFF0000u);
      xv[2] = __uint_as_float(pv.y << 16); xv[3] = __uint_as_float(pv.y & 0xFFFF0000u);
      xv[4] = __uint_as_float(pv.z << 16); xv[5] = __uint_as_float(pv.z & 0xFFFF0000u);
      xv[6] = __uint_as_float(pv.w << 16); xv[7] = __uint_as_float(pv.w & 0xFFFF0000u);
      float svv[8], tvv[8];
      *(float4*)&svv[0] = *(const float4*)(bnp1 + c);       *(float4*)&svv[4] = *(const float4*)(bnp1 + c + 4);
      *(float4*)&tvv[0] = *(const float4*)(bnp1 + 128 + c); *(float4*)&tvv[4] = *(const float4*)(bnp1 + 132 + c);
      float y[8];
      #pragma unroll
      for (int u = 0; u < 8; ++u) y[u] = fmaxf(fmaf(svv[u], xv[u], tvv[u]), 0.f);
      uint4 pk;
      pk.x = pk2bf(y[0], y[1]); pk.y = pk2bf(y[2], y[3]);
      pk.z = pk2bf(y[4], y[5]); pk.w = pk2bf(y[6], y[7]);
      *(uint4*)&Xs[rl * 136 + c] = pk;
    }
  }
  __syncthreads();

  int w = tid >> 6, lane = tid & 63;
  int m16 = lane & 15, qd = lane >> 4;
  f32x4 acc[2][8];
  #pragma unroll
  for (int mt = 0; mt < 2; ++mt)
    #pragma unroll
    for (int nt = 0; nt < 8; ++nt) acc[mt][nt] = (f32x4){0.f, 0.f, 0.f, 0.f};

  const unsigned short* Ab = &Xs[(w * 32 + m16) * 136 + qd * 8];
  const unsigned short* Bb = W2b + m16 * 128 + qd * 8;
  #pragma unroll 1
  for (int q = 0; q < 4; ++q) {
    bf16x8 A0 = *(const bf16x8*)(Ab + q * 32);
    bf16x8 A1 = *(const bf16x8*)(Ab + 16 * 136 + q * 32);
    #pragma unroll
    for (int nt = 0; nt < 8; ++nt) {
      bf16x8 Bv = *(const bf16x8*)(Bb + nt * 16 * 128 + q * 32);
      acc[0][nt] = __builtin_amdgcn_mfma_f32_16x16x32_bf16(A0, Bv, acc[0][nt], 0, 0, 0);
      acc[1][nt] = __builtin_amdgcn_mfma_f32_16x16x32_bf16(A1, Bv, acc[1][nt], 0, 0, 0);
    }
  }

  // ---- epilogue: bias, stats2, k-max/min over 16 rows ----
  float ssum[8], ssq[8], mxv[2][8], mnv[2][8];
  #pragma unroll
  for (int nt = 0; nt < 8; ++nt) { ssum[nt] = 0.f; ssq[nt] = 0.f; }
  #pragma unroll
  for (int nt = 0; nt < 8; ++nt) {
    float bb = b2[nt * 16 + m16];
    #pragma unroll
    for (int mt = 0; mt < 2; ++mt) {
      float y0 = acc[mt][nt][0] + bb;
      float mx = y0, mn = y0, su = y0, sq = y0 * y0;
      #pragma unroll
      for (int rg = 1; rg < 4; ++rg) {
        float y = acc[mt][nt][rg] + bb;
        mx = fmaxf(mx, y); mn = fminf(mn, y);
        su += y; sq = fmaf(y, y, sq);
      }
      mxv[mt][nt] = mx; mnv[mt][nt] = mn;
      ssum[nt] += su; ssq[nt] += sq;
    }
  }
  // k-reduction across qd (lanes xor 16, 32 share col & point)
  #pragma unroll
  for (int nt = 0; nt < 8; ++nt)
    #pragma unroll
    for (int mt = 0; mt < 2; ++mt) {
      mxv[mt][nt] = fmaxf(mxv[mt][nt], __shfl_xor(mxv[mt][nt], 16));
      mxv[mt][nt] = fmaxf(mxv[mt][nt], __shfl_xor(mxv[mt][nt], 32));
      mnv[mt][nt] = fminf(mnv[mt][nt], __shfl_xor(mnv[mt][nt], 16));
      mnv[mt][nt] = fminf(mnv[mt][nt], __shfl_xor(mnv[mt][nt], 32));
    }
  if (lane < 16) {
    #pragma unroll
    for (int mt = 0; mt < 2; ++mt) {
      int n = n0 + w * 2 + mt;
      size_t base = ((size_t)(b << 12) + n) * 128;
      #pragma unroll
      for (int nt = 0; nt < 8; ++nt) {
        ymaxo[base + nt * 16 + lane] = mxv[mt][nt];
        ymino[base + nt * 16 + lane] = mnv[mt][nt];
      }
    }
  }
  #pragma unroll
  for (int nt = 0; nt < 8; ++nt) {
    ssum[nt] += __shfl_xor(ssum[nt], 16);
    ssum[nt] += __shfl_xor(ssum[nt], 32);
    ssq[nt] += __shfl_xor(ssq[nt], 16);
    ssq[nt] += __shfl_xor(ssq[nt], 32);
  }
  if (lane < 16) {
    #pragma unroll
    for (int nt = 0; nt < 8; ++nt) {
      sred[(w * 128 + nt * 16 + lane) * 2] = ssum[nt];
      sred[(w * 128 + nt * 16 + lane) * 2 + 1] = ssq[nt];
    }
  }
  __syncthreads();
  if (tid < 128) {
    float a = 0.f, q2 = 0.f;
    #pragma unroll
    for (int ww = 0; ww < 4; ++ww) {
      a += sred[(ww * 128 + tid) * 2];
      q2 += sred[(ww * 128 + tid) * 2 + 1];
    }
    atomicAdd(stats2 + tid, a);
    atomicAdd(stats2 + 128 + tid, q2);
  }
}

// ---------------- final: BN2+relu on max/min, transpose to (B,128,N) ----------------
__global__ __launch_bounds__(256) void final_kernel(const float* __restrict__ ymaxo,
                                                    const float* __restrict__ ymino,
                                                    const float* __restrict__ bnp2,
                                                    float* __restrict__ out) {
  __shared__ float T[64 * 129];
  int tid = threadIdx.x;
  int b = blockIdx.x >> 6;
  int n0 = (blockIdx.x & 63) * 64;
  for (int u = tid; u < 64 * 128; u += 256) {
    int nl = u >> 7, o = u & 127;
    size_t base = ((size_t)(b << 12) + n0 + nl) * 128 + o;
    float s = bnp2[o], t = bnp2[128 + o];
    float v = fmaf(s, (s >= 0.f ? ymaxo[base] : ymino[base]), t);
    T[nl * 129 + o] = fmaxf(v, 0.f);
  }
  __syncthreads();
  for (int u = tid; u < 64 * 128; u += 256) {
    int o = u >> 6, nl = u & 63;
    out[((size_t)b * 128 + o) * N_ + n0 + nl] = T[nl * 129 + o];
  }
}

extern "C" void kernel_launch(void* const* d_in, const int* in_sizes, int n_in,
                              void* d_out, int out_size, void* d_ws, size_t ws_size,
                              hipStream_t stream) {
  (void)in_sizes; (void)n_in; (void)out_size; (void)ws_size;
  const float* points1 = (const float*)d_in[0];
  const float* points2 = (const float*)d_in[1];
  const float* features1 = (const float*)d_in[2];
  const float* features2 = (const float*)d_in[3];
  const float* W0 = (const float*)d_in[4];
  const float* b0 = (const float*)d_in[5];
  const float* g0 = (const float*)d_in[6];
  const float* be0 = (const float*)d_in[7];
  const float* W1 = (const float*)d_in[8];
  const float* b1 = (const float*)d_in[9];
  const float* g1 = (const float*)d_in[10];
  const float* be1 = (const float*)d_in[11];
  const float* W2 = (const float*)d_in[12];
  const float* b2 = (const float*)d_in[13];
  const float* g2 = (const float*)d_in[14];
  const float* be2 = (const float*)d_in[15];
  float* out = (float*)d_out;

  char* ws = (char*)d_ws;
  size_t off = 0;
  auto alloc = [&](size_t bytes) -> void* {
    void* p = ws + off;
    off += (bytes + 255) & ~(size_t)255;
    return p;
  };
  int* idx = (int*)alloc((size_t)M_ * 4);
  float4* p1f4 = (float4*)alloc((size_t)B_ * N_ * 16);
  float4* p2f4 = (float4*)alloc((size_t)B_ * N_ * 16);
  float* P1 = (float*)alloc((size_t)B_ * N_ * 128 * 4);
  float* P2 = (float*)alloc((size_t)B_ * N_ * 128 * 4);
  unsigned short* W1b = (unsigned short*)alloc(128 * 128 * 2);
  unsigned short* W2b = (unsigned short*)alloc(128 * 128 * 2);
  float* w0at = (float*)alloc(3 * 128 * 4);
  float* stats = (float*)alloc(3 * 256 * 4);
  float* bnp = (float*)alloc(3 * 256 * 4);
  unsigned short* x1 = (unsigned short*)alloc((size_t)M_ * 128 * 2);  // 128 MB (bf16)
  float* ymaxo = (float*)alloc((size_t)B_ * N_ * 128 * 4);
  float* ymino = (float*)alloc((size_t)B_ * N_ * 128 * 4);

  // KNN scratch aliased onto x1 (dead until layer1)
  float* pvals = (float*)x1;                                        // 16 MB
  int* cidx = (int*)((char*)x1 + (size_t)16 * 1024 * 1024);         // 16 MB
  int* ccnt = (int*)((char*)x1 + (size_t)32 * 1024 * 1024);         // 1 MB
  float* Tarr = (float*)((char*)x1 + (size_t)33 * 1024 * 1024);     // 128 KB

  hipMemsetAsync(stats, 0, 3 * 256 * 4, stream);

  pack_pts<<<B_ * N_ / 256, 256, 0, stream>>>(points1, p1f4);
  pack_pts<<<B_ * N_ / 256, 256, 0, stream>>>(points2, p2f4);
  wcvt<<<64, 256, 0, stream>>>(W1, W1b);
  wcvt<<<64, 256, 0, stream>>>(W2, W2b);
  make_w0at<<<1, 128, 0, stream>>>(W0, w0at);

  knn_part<<<B_ * 64 * 8, 64, 0, stream>>>(p1f4, p2f4, pvals);
  knn_merge<<<B_ * N_ / 256, 256, 0, stream>>>(pvals, Tarr);
  knn_cand<<<B_ * 64 * 8, 64, 0, stream>>>(p1f4, p2f4, Tarr, cidx, ccnt);
  knn_combine<<<B_ * N_ / 256, 256, 0, stream>>>(cidx, ccnt, idx);

  pkern<<<B_ * N_ / 32, 256, 0, stream>>>(features1, W0, b0, P1, 67);
  pkern<<<B_ * N_ / 32, 256, 0, stream>>>(features2, W0, nullptr, P2, 3);

  stats0_kernel<<<M_ / 256, 256, 0, stream>>>(P1, P2, idx, p1f4, p2f4, w0at, stats);
  bnfin_kernel<<<1, 128, 0, stream>>>(stats, g0, be0, bnp);

  layer1_mfma<<<M_ / 128, 256, 0, stream>>>(P1, P2, idx, p1f4, p2f4, w0at, bnp,
                                            W1b, b1, x1, stats + 256);
  bnfin_kernel<<<1, 128, 0, stream>>>(stats + 256, g1, be1, bnp + 256);

  layer2_mfma<<<M_ / 128, 256, 0, stream>>>(x1, bnp + 256, W2b, b2, ymaxo, ymino,
                                            stats + 512);
  bnfin_kernel<<<1, 128, 0, stream>>>(stats + 512, g2, be2, bnp + 512);

  final_kernel<<<B_ * N_ / 64, 256, 0, stream>>>(ymaxo, ymino, bnp + 512, out);
}

// Round 5
// 743.372 us; speedup vs baseline: 1.9988x; 1.1400x over previous
//
#include <hip/hip_runtime.h>

#define B_ 8
#define N_ 4096
#define K_ 16
#define C_ 64
#define NK_ (N_*K_)            // 65536
#define M_ (B_*N_*K_)          // 524288
#define BN_EPS_ 0.001f
#define CH_ 16                 // knn candidate chunks
#define CS_ (N_/CH_)           // 256 candidates per chunk
#define Q_ (B_*N_)             // 32768 queries

typedef short bf16x8 __attribute__((ext_vector_type(8)));   // 8 bf16 = 4 VGPRs
typedef float f32x4 __attribute__((ext_vector_type(4)));

// bf16 round-to-nearest-even (no NaN inputs in this pipeline)
static __device__ __forceinline__ unsigned short f2bf(float x) {
  unsigned u = __float_as_uint(x);
  unsigned r = (u + 0x7FFFu + ((u >> 16) & 1u)) >> 16;
  return (unsigned short)r;
}
static __device__ __forceinline__ unsigned pk2bf(float a, float b) {
  return (unsigned)f2bf(a) | ((unsigned)f2bf(b) << 16);
}

// ---------------- pack points (B,3,N) -> float4 (B*N) ----------------
__global__ __launch_bounds__(256) void pack_pts(const float* __restrict__ p,
                                                float4* __restrict__ pf4) {
  int i = blockIdx.x * 256 + threadIdx.x;
  int b = i >> 12;
  int n = i & (N_ - 1);
  const float* base = p + (size_t)b * 3 * N_;
  pf4[i] = make_float4(base[n], base[N_ + n], base[2 * N_ + n], 0.f);
}

// ---------------- W (128x128 fp32) -> bf16 same layout ----------------
__global__ __launch_bounds__(256) void wcvt(const float* __restrict__ W,
                                            unsigned short* __restrict__ Wb) {
  int i = blockIdx.x * 256 + threadIdx.x;   // 16384
  Wb[i] = f2bf(W[i]);
}

// ---------------- w0at[d][o] = W0[o][d], d<3 ----------------
__global__ void make_w0at(const float* __restrict__ W0, float* __restrict__ w0at) {
  int o = threadIdx.x;  // 128
  for (int d = 0; d < 3; ++d) w0at[d * 128 + o] = W0[o * 131 + d];
}

// ================= KNN, candidate-split 16 ways =================
// Sorted-16 insert via v_med3_f32: for desc-sorted s, max(s[i+1],min(s[i],d)) == median3.
__global__ __launch_bounds__(64) void knn_part(const float4* __restrict__ p1f4,
                                               const float4* __restrict__ p2f4,
                                               float* __restrict__ pvals) {
  int lane = threadIdx.x;
  int blk = blockIdx.x;            // chunk fastest: b(8) x grp(64) x chunk(16)
  int chunk = blk & (CH_ - 1);
  int grp = (blk >> 4) & 63;
  int b = blk >> 10;
  int n1 = (grp << 6) + lane;
  int q = (b << 12) + n1;
  float4 qv = p1f4[q];
  float ax = qv.x, ay = qv.y, az = qv.z;
  const float4* pb = p2f4 + ((size_t)b << 12) + chunk * CS_;

  float s[16];
  #pragma unroll
  for (int i = 0; i < 16; ++i) s[i] = 3.0e38f;   // desc sorted; s[0]=16th smallest

  #pragma unroll 8
  for (int t = 0; t < CS_; ++t) {
    float4 c = pb[t];              // wave-uniform -> scalar load
    float dx = ax - c.x, dy = ay - c.y, dz = az - c.z;
    float d = __fadd_rn(__fadd_rn(__fmul_rn(dx, dx), __fmul_rn(dy, dy)), __fmul_rn(dz, dz));
    #pragma unroll
    for (int i = 0; i < 15; ++i) s[i] = __builtin_amdgcn_fmed3f(s[i], s[i + 1], d);
    s[15] = fminf(s[15], d);
  }
  // transposed store: pvals[slot][q], coalesced along q
  #pragma unroll
  for (int i = 0; i < 16; ++i) pvals[(size_t)(chunk * 16 + i) * Q_ + q] = s[i];
}

// knn_merge: 1 thread/query; T = 16th smallest of CH_*16 partials (coalesced loads)
__global__ __launch_bounds__(256) void knn_merge(const float* __restrict__ pvals,
                                                 float* __restrict__ Tarr) {
  int q = blockIdx.x * 256 + threadIdx.x;
  float s[16];
  #pragma unroll
  for (int i = 0; i < 16; ++i) s[i] = 3.0e38f;
  #pragma unroll 8
  for (int t = 0; t < CH_ * 16; ++t) {
    float d = pvals[(size_t)t * Q_ + q];
    #pragma unroll
    for (int i = 0; i < 15; ++i) s[i] = __builtin_amdgcn_fmed3f(s[i], s[i + 1], d);
    s[15] = fminf(s[15], d);
  }
  Tarr[q] = s[0];
}

// knn_cand: chunk-split index recovery (d<=T, ascending within chunk, cap 16)
__global__ __launch_bounds__(64) void knn_cand(const float4* __restrict__ p1f4,
                                               const float4* __restrict__ p2f4,
                                               const float* __restrict__ Tarr,
                                               int* __restrict__ cidx,
                                               int* __restrict__ ccnt) {
  int lane = threadIdx.x;
  int blk = blockIdx.x;
  int chunk = blk & (CH_ - 1);
  int grp = (blk >> 4) & 63;
  int b = blk >> 10;
  int n1 = (grp << 6) + lane;
  int q = (b << 12) + n1;
  float4 qq = p1f4[q];
  float ax = qq.x, ay = qq.y, az = qq.z;
  const float4* pb = p2f4 + ((size_t)b << 12) + chunk * CS_;
  float T = Tarr[q];
  int cnt = 0;
  int base = (q * CH_ + chunk) * 16;
  #pragma unroll 4
  for (int t = 0; t < CS_; ++t) {
    float4 c = pb[t];
    float dx = ax - c.x, dy = ay - c.y, dz = az - c.z;
    float d = __fadd_rn(__fadd_rn(__fmul_rn(dx, dx), __fmul_rn(dy, dy)), __fmul_rn(dz, dz));
    if (d <= T && cnt < 16) { cidx[base + cnt] = chunk * CS_ + t; ++cnt; }
  }
  ccnt[q * CH_ + chunk] = cnt;
}

// knn_combine: ascending-chunk prefix fill to exactly 16 (== top_k tie-break)
__global__ __launch_bounds__(256) void knn_combine(const int* __restrict__ cidx,
                                                   const int* __restrict__ ccnt,
                                                   int* __restrict__ idxout) {
  int q = blockIdx.x * 256 + threadIdx.x;
  int tot = 0;
  int ob = q * 16;
  for (int c = 0; c < CH_; ++c) {
    int m = ccnt[q * CH_ + c];
    const int* src = cidx + (size_t)(q * CH_ + c) * 16;
    for (int i = 0; i < m && tot < 16; ++i) idxout[ob + tot++] = src[i];
  }
}

// ---------------- P[bn][o] = sum_c W0[o][coff+c] * f[b][c][n] (+bias) ----------------
__global__ __launch_bounds__(256) void pkern(const float* __restrict__ f,
                                             const float* __restrict__ W0,
                                             const float* __restrict__ bias,
                                             float* __restrict__ P, int coff) {
  __shared__ float fx[32 * 65];
  __shared__ __align__(16) float Wl[64 * 132];
  int tid = threadIdx.x;
  int bn0 = blockIdx.x * 32;
  int b = bn0 >> 12, nb0 = bn0 & (N_ - 1);

  for (int u = tid; u < 32 * 64; u += 256) {
    int c = u >> 5, nl = u & 31;
    fx[nl * 65 + c] = f[((size_t)b * C_ + c) * N_ + nb0 + nl];
  }
  for (int u = tid; u < 128 * 64; u += 256) {
    int o = u >> 6, c = u & 63;
    Wl[c * 132 + o] = W0[o * 131 + coff + c];
  }
  __syncthreads();

  int og = tid & 15, np_ = tid >> 4;
  int o0 = og * 8;
  int na = np_ * 2, nb = na + 1;
  float acc0[8], acc1[8];
  #pragma unroll
  for (int j = 0; j < 8; ++j) {
    float bv = bias ? bias[o0 + j] : 0.f;
    acc0[j] = bv; acc1[j] = bv;
  }
  for (int c = 0; c < 64; ++c) {
    float x0 = fx[na * 65 + c], x1 = fx[nb * 65 + c];
    float4 wa = *(const float4*)&Wl[c * 132 + o0];
    float4 wb = *(const float4*)&Wl[c * 132 + o0 + 4];
    float w[8] = {wa.x, wa.y, wa.z, wa.w, wb.x, wb.y, wb.z, wb.w};
    #pragma unroll
    for (int j = 0; j < 8; ++j) {
      acc0[j] = fmaf(x0, w[j], acc0[j]);
      acc1[j] = fmaf(x1, w[j], acc1[j]);
    }
  }
  float* Pa = P + (size_t)(bn0 + na) * 128 + o0;
  float* Pb = P + (size_t)(bn0 + nb) * 128 + o0;
  *(float4*)Pa = make_float4(acc0[0], acc0[1], acc0[2], acc0[3]);
  *(float4*)(Pa + 4) = make_float4(acc0[4], acc0[5], acc0[6], acc0[7]);
  *(float4*)Pb = make_float4(acc1[0], acc1[1], acc1[2], acc1[3]);
  *(float4*)(Pb + 4) = make_float4(acc1[4], acc1[5], acc1[6], acc1[7]);
}

// ---------------- BN0 stats over x0 = P1 + P2[idx] + W0a*rel_xyz ----------------
__global__ __launch_bounds__(256) void stats0_kernel(
    const float* __restrict__ P1, const float* __restrict__ P2,
    const int* __restrict__ idx, const float4* __restrict__ p1f4,
    const float4* __restrict__ p2f4, const float* __restrict__ w0at,
    float* __restrict__ stats) {
  int tid = threadIdx.x;
  int c = tid & 127, h = tid >> 7;
  float w0 = w0at[c], w1 = w0at[128 + c], w2 = w0at[256 + c];
  float sum = 0.f, sq = 0.f;
  int rbase = blockIdx.x * 256 + h * 128;
  for (int i = 0; i < 128; ++i) {
    int r = rbase + i;
    int b = r >> 16;
    int nk = r & (NK_ - 1);
    int n = nk >> 4;
    int j = idx[r];
    float4 pq = p1f4[(b << 12) + n];
    float4 pj = p2f4[(b << 12) + j];
    float rx = pj.x - pq.x, ry = pj.y - pq.y, rz = pj.z - pq.z;
    float a0 = w0 * rx + w1 * ry + w2 * rz;
    float x = P1[(size_t)((b << 12) + n) * 128 + c] +
              P2[(size_t)((b << 12) + j) * 128 + c] + a0;
    sum += x;
    sq = fmaf(x, x, sq);
  }
  __shared__ float red[256 * 2];
  red[tid * 2] = sum;
  red[tid * 2 + 1] = sq;
  __syncthreads();
  if (h == 0) {
    atomicAdd(stats + c, sum + red[(tid + 128) * 2]);
    atomicAdd(stats + 128 + c, sq + red[(tid + 128) * 2 + 1]);
  }
}

// ---------------- BN finalize ----------------
__global__ void bnfin_kernel(const float* __restrict__ stats, const float* __restrict__ gamma,
                             const float* __restrict__ beta, float* __restrict__ bnp) {
  int o = threadIdx.x;
  const float invM = 1.0f / (float)M_;
  float mean = stats[o] * invM;
  float var = stats[128 + o] * invM - mean * mean;
  float s = gamma[o] * rsqrtf(var + BN_EPS_);
  bnp[o] = s;
  bnp[128 + o] = beta[o] - mean * s;
}

// ---------------- layer1 (MFMA): assemble x0 -> BN0+relu -> bf16 GEMM W1 -> x1(bf16) + stats1 ----------------
__global__ __launch_bounds__(256) void layer1_mfma(
    const float* __restrict__ P1, const float* __restrict__ P2,
    const int* __restrict__ idx, const float4* __restrict__ p1f4,
    const float4* __restrict__ p2f4, const float* __restrict__ w0at,
    const float* __restrict__ bnp0, const unsigned short* __restrict__ W1b,
    const float* __restrict__ b1, unsigned short* __restrict__ x1out,
    float* __restrict__ stats1) {
  __shared__ __align__(16) unsigned short Xs[128 * 136];   // [row][k], pad 8 bf16
  __shared__ float sred[4 * 128 * 2];
  int tid = threadIdx.x;
  int R0 = blockIdx.x * 128;
  int b = R0 >> 16;
  int n0 = (R0 & (NK_ - 1)) >> 4;

  // ---- stage X (bf16) ----
  {
    int rl = tid & 127;
    int r = R0 + rl;
    int n = n0 + (rl >> 4);
    int j = idx[r];
    float4 pq = p1f4[(b << 12) + n], pj = p2f4[(b << 12) + j];
    float rx = pj.x - pq.x, ry = pj.y - pq.y, rz = pj.z - pq.z;
    const float* P1r = P1 + (size_t)((b << 12) + n) * 128;
    const float* P2r = P2 + (size_t)((b << 12) + j) * 128;
    int kh = (tid >> 7) * 64;   // wave-pair uniform
    #pragma unroll
    for (int ci = 0; ci < 64; ci += 8) {
      int c = kh + ci;
      float p1v[8], p2v[8], wxv[8], wyv[8], wzv[8], svv[8], tvv[8];
      *(float4*)&p1v[0] = *(const float4*)(P1r + c);       *(float4*)&p1v[4] = *(const float4*)(P1r + c + 4);
      *(float4*)&p2v[0] = *(const float4*)(P2r + c);       *(float4*)&p2v[4] = *(const float4*)(P2r + c + 4);
      *(float4*)&wxv[0] = *(const float4*)(w0at + c);      *(float4*)&wxv[4] = *(const float4*)(w0at + c + 4);
      *(float4*)&wyv[0] = *(const float4*)(w0at + 128 + c);*(float4*)&wyv[4] = *(const float4*)(w0at + 132 + c);
      *(float4*)&wzv[0] = *(const float4*)(w0at + 256 + c);*(float4*)&wzv[4] = *(const float4*)(w0at + 260 + c);
      *(float4*)&svv[0] = *(const float4*)(bnp0 + c);      *(float4*)&svv[4] = *(const float4*)(bnp0 + c + 4);
      *(float4*)&tvv[0] = *(const float4*)(bnp0 + 128 + c);*(float4*)&tvv[4] = *(const float4*)(bnp0 + 132 + c);
      float y[8];
      #pragma unroll
      for (int u = 0; u < 8; ++u) {
        float x = p1v[u] + p2v[u] + wxv[u] * rx + wyv[u] * ry + wzv[u] * rz;
        y[u] = fmaxf(fmaf(svv[u], x, tvv[u]), 0.f);
      }
      uint4 pk;
      pk.x = pk2bf(y[0], y[1]); pk.y = pk2bf(y[2], y[3]);
      pk.z = pk2bf(y[4], y[5]); pk.w = pk2bf(y[6], y[7]);
      *(uint4*)&Xs[rl * 136 + c] = pk;
    }
  }
  __syncthreads();

  // ---- MFMA: wave w computes rows [w*32, w*32+32) x all 128 cols ----
  int w = tid >> 6, lane = tid & 63;
  int m16 = lane & 15, qd = lane >> 4;
  f32x4 acc[2][8];
  #pragma unroll
  for (int mt = 0; mt < 2; ++mt)
    #pragma unroll
    for (int nt = 0; nt < 8; ++nt) acc[mt][nt] = (f32x4){0.f, 0.f, 0.f, 0.f};

  const unsigned short* Ab = &Xs[(w * 32 + m16) * 136 + qd * 8];
  const unsigned short* Bb = W1b + m16 * 128 + qd * 8;
  #pragma unroll 1
  for (int q = 0; q < 4; ++q) {
    bf16x8 A0 = *(const bf16x8*)(Ab + q * 32);
    bf16x8 A1 = *(const bf16x8*)(Ab + 16 * 136 + q * 32);
    #pragma unroll
    for (int nt = 0; nt < 8; ++nt) {
      bf16x8 Bv = *(const bf16x8*)(Bb + nt * 16 * 128 + q * 32);
      acc[0][nt] = __builtin_amdgcn_mfma_f32_16x16x32_bf16(A0, Bv, acc[0][nt], 0, 0, 0);
      acc[1][nt] = __builtin_amdgcn_mfma_f32_16x16x32_bf16(A1, Bv, acc[1][nt], 0, 0, 0);
    }
  }

  // ---- epilogue: bias, stats, bf16 store (D: col=lane&15, row=qd*4+reg) ----
  float ssum[8], ssq[8];
  #pragma unroll
  for (int nt = 0; nt < 8; ++nt) { ssum[nt] = 0.f; ssq[nt] = 0.f; }
  #pragma unroll
  for (int nt = 0; nt < 8; ++nt) {
    int col = nt * 16 + m16;
    float bb = b1[col];
    #pragma unroll
    for (int mt = 0; mt < 2; ++mt) {
      #pragma unroll
      for (int rg = 0; rg < 4; ++rg) {
        float y = acc[mt][nt][rg] + bb;
        ssum[nt] += y;
        ssq[nt] = fmaf(y, y, ssq[nt]);
        int row = R0 + w * 32 + mt * 16 + qd * 4 + rg;
        x1out[(size_t)row * 128 + col] = f2bf(y);
      }
    }
  }
  #pragma unroll
  for (int nt = 0; nt < 8; ++nt) {
    ssum[nt] += __shfl_xor(ssum[nt], 16);
    ssum[nt] += __shfl_xor(ssum[nt], 32);
    ssq[nt] += __shfl_xor(ssq[nt], 16);
    ssq[nt] += __shfl_xor(ssq[nt], 32);
  }
  if (lane < 16) {
    #pragma unroll
    for (int nt = 0; nt < 8; ++nt) {
      sred[(w * 128 + nt * 16 + lane) * 2] = ssum[nt];
      sred[(w * 128 + nt * 16 + lane) * 2 + 1] = ssq[nt];
    }
  }
  __syncthreads();
  if (tid < 128) {
    float a = 0.f, q2 = 0.f;
    #pragma unroll
    for (int ww = 0; ww < 4; ++ww) {
      a += sred[(ww * 128 + tid) * 2];
      q2 += sred[(ww * 128 + tid) * 2 + 1];
    }
    atomicAdd(stats1 + tid, a);
    atomicAdd(stats1 + 128 + tid, q2);
  }
}

// ---------------- layer2 (MFMA): BN1+relu -> bf16 GEMM W2 -> k-max/min + stats2 ----------------
__global__ __launch_bounds__(256) void layer2_mfma(
    const unsigned short* __restrict__ x1, const float* __restrict__ bnp1,
    const unsigned short* __restrict__ W2b, const float* __restrict__ b2,
    float* __restrict__ ymaxo, float* __restrict__ ymino,
    float* __restrict__ stats2) {
  __shared__ __align__(16) unsigned short Xs[128 * 136];
  __shared__ float sred[4 * 128 * 2];
  int tid = threadIdx.x;
  int R0 = blockIdx.x * 128;
  int b = R0 >> 16;
  int n0 = (R0 & (NK_ - 1)) >> 4;

  // ---- stage X (bf16): BN1+relu on x1 ----
  {
    int rl = tid & 127;
    int r = R0 + rl;
    const unsigned short* xr = x1 + (size_t)r * 128;
    int kh = (tid >> 7) * 64;
    #pragma unroll
    for (int ci = 0; ci < 64; ci += 8) {
      int c = kh + ci;
      uint4 pv = *(const uint4*)(xr + c);
      float xv[8];
      xv[0] = __uint_as_float(pv.x << 16); xv[1] = __uint_as_float(pv.x & 0xFFFF0000u);
      xv[2] = __uint_as_float(pv.y << 16); xv[3] = __uint_as_float(pv.y & 0xFFFF0000u);
      xv[4] = __uint_as_float(pv.z << 16); xv[5] = __uint_as_float(pv.z & 0xFFFF0000u);
      xv[6] = __uint_as_float(pv.w << 16); xv[7] = __uint_as_float(pv.w & 0xFFFF0000u);
      float svv[8], tvv[8];
      *(float4*)&svv[0] = *(const float4*)(bnp1 + c);       *(float4*)&svv[4] = *(const float4*)(bnp1 + c + 4);
      *(float4*)&tvv[0] = *(const float4*)(bnp1 + 128 + c); *(float4*)&tvv[4] = *(const float4*)(bnp1 + 132 + c);
      float y[8];
      #pragma unroll
      for (int u = 0; u < 8; ++u) y[u] = fmaxf(fmaf(svv[u], xv[u], tvv[u]), 0.f);
      uint4 pk;
      pk.x = pk2bf(y[0], y[1]); pk.y = pk2bf(y[2], y[3]);
      pk.z = pk2bf(y[4], y[5]); pk.w = pk2bf(y[6], y[7]);
      *(uint4*)&Xs[rl * 136 + c] = pk;
    }
  }
  __syncthreads();

  int w = tid >> 6, lane = tid & 63;
  int m16 = lane & 15, qd = lane >> 4;
  f32x4 acc[2][8];
  #pragma unroll
  for (int mt = 0; mt < 2; ++mt)
    #pragma unroll
    for (int nt = 0; nt < 8; ++nt) acc[mt][nt] = (f32x4){0.f, 0.f, 0.f, 0.f};

  const unsigned short* Ab = &Xs[(w * 32 + m16) * 136 + qd * 8];
  const unsigned short* Bb = W2b + m16 * 128 + qd * 8;
  #pragma unroll 1
  for (int q = 0; q < 4; ++q) {
    bf16x8 A0 = *(const bf16x8*)(Ab + q * 32);
    bf16x8 A1 = *(const bf16x8*)(Ab + 16 * 136 + q * 32);
    #pragma unroll
    for (int nt = 0; nt < 8; ++nt) {
      bf16x8 Bv = *(const bf16x8*)(Bb + nt * 16 * 128 + q * 32);
      acc[0][nt] = __builtin_amdgcn_mfma_f32_16x16x32_bf16(A0, Bv, acc[0][nt], 0, 0, 0);
      acc[1][nt] = __builtin_amdgcn_mfma_f32_16x16x32_bf16(A1, Bv, acc[1][nt], 0, 0, 0);
    }
  }

  // ---- epilogue: bias, stats2, k-max/min over 16 rows ----
  float ssum[8], ssq[8], mxv[2][8], mnv[2][8];
  #pragma unroll
  for (int nt = 0; nt < 8; ++nt) { ssum[nt] = 0.f; ssq[nt] = 0.f; }
  #pragma unroll
  for (int nt = 0; nt < 8; ++nt) {
    float bb = b2[nt * 16 + m16];
    #pragma unroll
    for (int mt = 0; mt < 2; ++mt) {
      float y0 = acc[mt][nt][0] + bb;
      float mx = y0, mn = y0, su = y0, sq = y0 * y0;
      #pragma unroll
      for (int rg = 1; rg < 4; ++rg) {
        float y = acc[mt][nt][rg] + bb;
        mx = fmaxf(mx, y); mn = fminf(mn, y);
        su += y; sq = fmaf(y, y, sq);
      }
      mxv[mt][nt] = mx; mnv[mt][nt] = mn;
      ssum[nt] += su; ssq[nt] += sq;
    }
  }
  // k-reduction across qd (lanes xor 16, 32 share col & point)
  #pragma unroll
  for (int nt = 0; nt < 8; ++nt)
    #pragma unroll
    for (int mt = 0; mt < 2; ++mt) {
      mxv[mt][nt] = fmaxf(mxv[mt][nt], __shfl_xor(mxv[mt][nt], 16));
      mxv[mt][nt] = fmaxf(mxv[mt][nt], __shfl_xor(mxv[mt][nt], 32));
      mnv[mt][nt] = fminf(mnv[mt][nt], __shfl_xor(mnv[mt][nt], 16));
      mnv[mt][nt] = fminf(mnv[mt][nt], __shfl_xor(mnv[mt][nt], 32));
    }
  if (lane < 16) {
    #pragma unroll
    for (int mt = 0; mt < 2; ++mt) {
      int n = n0 + w * 2 + mt;
      size_t base = ((size_t)(b << 12) + n) * 128;
      #pragma unroll
      for (int nt = 0; nt < 8; ++nt) {
        ymaxo[base + nt * 16 + lane] = mxv[mt][nt];
        ymino[base + nt * 16 + lane] = mnv[mt][nt];
      }
    }
  }
  #pragma unroll
  for (int nt = 0; nt < 8; ++nt) {
    ssum[nt] += __shfl_xor(ssum[nt], 16);
    ssum[nt] += __shfl_xor(ssum[nt], 32);
    ssq[nt] += __shfl_xor(ssq[nt], 16);
    ssq[nt] += __shfl_xor(ssq[nt], 32);
  }
  if (lane < 16) {
    #pragma unroll
    for (int nt = 0; nt < 8; ++nt) {
      sred[(w * 128 + nt * 16 + lane) * 2] = ssum[nt];
      sred[(w * 128 + nt * 16 + lane) * 2 + 1] = ssq[nt];
    }
  }
  __syncthreads();
  if (tid < 128) {
    float a = 0.f, q2 = 0.f;
    #pragma unroll
    for (int ww = 0; ww < 4; ++ww) {
      a += sred[(ww * 128 + tid) * 2];
      q2 += sred[(ww * 128 + tid) * 2 + 1];
    }
    atomicAdd(stats2 + tid, a);
    atomicAdd(stats2 + 128 + tid, q2);
  }
}

// ---------------- final: BN2+relu on max/min, transpose to (B,128,N) ----------------
__global__ __launch_bounds__(256) void final_kernel(const float* __restrict__ ymaxo,
                                                    const float* __restrict__ ymino,
                                                    const float* __restrict__ bnp2,
                                                    float* __restrict__ out) {
  __shared__ float T[64 * 129];
  int tid = threadIdx.x;
  int b = blockIdx.x >> 6;
  int n0 = (blockIdx.x & 63) * 64;
  for (int u = tid; u < 64 * 128; u += 256) {
    int nl = u >> 7, o = u & 127;
    size_t base = ((size_t)(b << 12) + n0 + nl) * 128 + o;
    float s = bnp2[o], t = bnp2[128 + o];
    float v = fmaf(s, (s >= 0.f ? ymaxo[base] : ymino[base]), t);
    T[nl * 129 + o] = fmaxf(v, 0.f);
  }
  __syncthreads();
  for (int u = tid; u < 64 * 128; u += 256) {
    int o = u >> 6, nl = u & 63;
    out[((size_t)b * 128 + o) * N_ + n0 + nl] = T[nl * 129 + o];
  }
}

extern "C" void kernel_launch(void* const* d_in, const int* in_sizes, int n_in,
                              void* d_out, int out_size, void* d_ws, size_t ws_size,
                              hipStream_t stream) {
  (void)in_sizes; (void)n_in; (void)out_size; (void)ws_size;
  const float* points1 = (const float*)d_in[0];
  const float* points2 = (const float*)d_in[1];
  const float* features1 = (const float*)d_in[2];
  const float* features2 = (const float*)d_in[3];
  const float* W0 = (const float*)d_in[4];
  const float* b0 = (const float*)d_in[5];
  const float* g0 = (const float*)d_in[6];
  const float* be0 = (const float*)d_in[7];
  const float* W1 = (const float*)d_in[8];
  const float* b1 = (const float*)d_in[9];
  const float* g1 = (const float*)d_in[10];
  const float* be1 = (const float*)d_in[11];
  const float* W2 = (const float*)d_in[12];
  const float* b2 = (const float*)d_in[13];
  const float* g2 = (const float*)d_in[14];
  const float* be2 = (const float*)d_in[15];
  float* out = (float*)d_out;

  char* ws = (char*)d_ws;
  size_t off = 0;
  auto alloc = [&](size_t bytes) -> void* {
    void* p = ws + off;
    off += (bytes + 255) & ~(size_t)255;
    return p;
  };
  int* idx = (int*)alloc((size_t)M_ * 4);
  float4* p1f4 = (float4*)alloc((size_t)B_ * N_ * 16);
  float4* p2f4 = (float4*)alloc((size_t)B_ * N_ * 16);
  float* P1 = (float*)alloc((size_t)B_ * N_ * 128 * 4);
  float* P2 = (float*)alloc((size_t)B_ * N_ * 128 * 4);
  unsigned short* W1b = (unsigned short*)alloc(128 * 128 * 2);
  unsigned short* W2b = (unsigned short*)alloc(128 * 128 * 2);
  float* w0at = (float*)alloc(3 * 128 * 4);
  float* stats = (float*)alloc(3 * 256 * 4);
  float* bnp = (float*)alloc(3 * 256 * 4);
  unsigned short* x1 = (unsigned short*)alloc((size_t)M_ * 128 * 2);  // 128 MB (bf16)
  float* ymaxo = (float*)alloc((size_t)B_ * N_ * 128 * 4);
  float* ymino = (float*)alloc((size_t)B_ * N_ * 128 * 4);

  // KNN scratch aliased onto x1 (dead until layer1): 32+32+2+0.13 = ~66.2 MB < 128 MB
  float* pvals = (float*)x1;                                         // CH*16 x Q floats = 32 MB
  int* cidx = (int*)((char*)x1 + (size_t)32 * 1024 * 1024);          // Q*CH*16 ints = 32 MB
  int* ccnt = (int*)((char*)x1 + (size_t)64 * 1024 * 1024);          // Q*CH ints = 2 MB
  float* Tarr = (float*)((char*)x1 + (size_t)66 * 1024 * 1024);      // Q floats = 128 KB

  hipMemsetAsync(stats, 0, 3 * 256 * 4, stream);

  pack_pts<<<B_ * N_ / 256, 256, 0, stream>>>(points1, p1f4);
  pack_pts<<<B_ * N_ / 256, 256, 0, stream>>>(points2, p2f4);
  wcvt<<<64, 256, 0, stream>>>(W1, W1b);
  wcvt<<<64, 256, 0, stream>>>(W2, W2b);
  make_w0at<<<1, 128, 0, stream>>>(W0, w0at);

  knn_part<<<B_ * 64 * CH_, 64, 0, stream>>>(p1f4, p2f4, pvals);
  knn_merge<<<Q_ / 256, 256, 0, stream>>>(pvals, Tarr);
  knn_cand<<<B_ * 64 * CH_, 64, 0, stream>>>(p1f4, p2f4, Tarr, cidx, ccnt);
  knn_combine<<<Q_ / 256, 256, 0, stream>>>(cidx, ccnt, idx);

  pkern<<<B_ * N_ / 32, 256, 0, stream>>>(features1, W0, b0, P1, 67);
  pkern<<<B_ * N_ / 32, 256, 0, stream>>>(features2, W0, nullptr, P2, 3);

  stats0_kernel<<<M_ / 256, 256, 0, stream>>>(P1, P2, idx, p1f4, p2f4, w0at, stats);
  bnfin_kernel<<<1, 128, 0, stream>>>(stats, g0, be0, bnp);

  layer1_mfma<<<M_ / 128, 256, 0, stream>>>(P1, P2, idx, p1f4, p2f4, w0at, bnp,
                                            W1b, b1, x1, stats + 256);
  bnfin_kernel<<<1, 128, 0, stream>>>(stats + 256, g1, be1, bnp + 256);

  layer2_mfma<<<M_ / 128, 256, 0, stream>>>(x1, bnp + 256, W2b, b2, ymaxo, ymino,
                                            stats + 512);
  bnfin_kernel<<<1, 128, 0, stream>>>(stats + 512, g2, be2, bnp + 512);

  final_kernel<<<B_ * N_ / 64, 256, 0, stream>>>(ymaxo, ymino, bnp + 512, out);
}

// Round 6
// 720.247 us; speedup vs baseline: 2.0629x; 1.0321x over previous
//
#include <hip/hip_runtime.h>

#define B_ 8
#define N_ 4096
#define K_ 16
#define C_ 64
#define NK_ (N_*K_)            // 65536
#define M_ (B_*N_*K_)          // 524288
#define BN_EPS_ 0.001f
#define CH_ 16                 // knn candidate chunks
#define CS_ (N_/CH_)           // 256 candidates per chunk
#define Q_ (B_*N_)             // 32768 queries

typedef short bf16x8 __attribute__((ext_vector_type(8)));   // 8 bf16 = 4 VGPRs
typedef float f32x4 __attribute__((ext_vector_type(4)));

// bf16 round-to-nearest-even (no NaN inputs in this pipeline)
static __device__ __forceinline__ unsigned short f2bf(float x) {
  unsigned u = __float_as_uint(x);
  unsigned r = (u + 0x7FFFu + ((u >> 16) & 1u)) >> 16;
  return (unsigned short)r;
}
static __device__ __forceinline__ unsigned pk2bf(float a, float b) {
  return (unsigned)f2bf(a) | ((unsigned)f2bf(b) << 16);
}

// ---------------- pack points (B,3,N) -> float4 (B*N) ----------------
__global__ __launch_bounds__(256) void pack_pts(const float* __restrict__ p,
                                                float4* __restrict__ pf4) {
  int i = blockIdx.x * 256 + threadIdx.x;
  int b = i >> 12;
  int n = i & (N_ - 1);
  const float* base = p + (size_t)b * 3 * N_;
  pf4[i] = make_float4(base[n], base[N_ + n], base[2 * N_ + n], 0.f);
}

// ---------------- W (128x128 fp32) -> bf16 same layout ----------------
__global__ __launch_bounds__(256) void wcvt(const float* __restrict__ W,
                                            unsigned short* __restrict__ Wb) {
  int i = blockIdx.x * 256 + threadIdx.x;   // 16384
  Wb[i] = f2bf(W[i]);
}

// ---------------- w0at[d][o] = W0[o][d], d<3 ----------------
__global__ void make_w0at(const float* __restrict__ W0, float* __restrict__ w0at) {
  int o = threadIdx.x;  // 128
  for (int d = 0; d < 3; ++d) w0at[d * 128 + o] = W0[o * 131 + d];
}

// ================= KNN, candidate-split 16 ways =================
// Sorted-16 insert via v_med3_f32: for desc-sorted s, max(s[i+1],min(s[i],d)) == median3.
__global__ __launch_bounds__(64) void knn_part(const float4* __restrict__ p1f4,
                                               const float4* __restrict__ p2f4,
                                               float* __restrict__ pvals) {
  int lane = threadIdx.x;
  int blk = blockIdx.x;            // chunk fastest: b(8) x grp(64) x chunk(16)
  int chunk = blk & (CH_ - 1);
  int grp = (blk >> 4) & 63;
  int b = blk >> 10;
  int n1 = (grp << 6) + lane;
  int q = (b << 12) + n1;
  float4 qv = p1f4[q];
  float ax = qv.x, ay = qv.y, az = qv.z;
  const float4* pb = p2f4 + ((size_t)b << 12) + chunk * CS_;

  float s[16];
  #pragma unroll
  for (int i = 0; i < 16; ++i) s[i] = 3.0e38f;   // desc sorted; s[0]=16th smallest

  #pragma unroll 8
  for (int t = 0; t < CS_; ++t) {
    float4 c = pb[t];              // wave-uniform -> scalar load
    float dx = ax - c.x, dy = ay - c.y, dz = az - c.z;
    float d = __fadd_rn(__fadd_rn(__fmul_rn(dx, dx), __fmul_rn(dy, dy)), __fmul_rn(dz, dz));
    #pragma unroll
    for (int i = 0; i < 15; ++i) s[i] = __builtin_amdgcn_fmed3f(s[i], s[i + 1], d);
    s[15] = fminf(s[15], d);
  }
  // transposed store: pvals[slot][q], coalesced along q
  #pragma unroll
  for (int i = 0; i < 16; ++i) pvals[(size_t)(chunk * 16 + i) * Q_ + q] = s[i];
}

// knn_merge: 1 thread/query; T = 16th smallest of CH_*16 partials (coalesced loads)
__global__ __launch_bounds__(256) void knn_merge(const float* __restrict__ pvals,
                                                 float* __restrict__ Tarr) {
  int q = blockIdx.x * 256 + threadIdx.x;
  float s[16];
  #pragma unroll
  for (int i = 0; i < 16; ++i) s[i] = 3.0e38f;
  #pragma unroll 8
  for (int t = 0; t < CH_ * 16; ++t) {
    float d = pvals[(size_t)t * Q_ + q];
    #pragma unroll
    for (int i = 0; i < 15; ++i) s[i] = __builtin_amdgcn_fmed3f(s[i], s[i + 1], d);
    s[15] = fminf(s[15], d);
  }
  Tarr[q] = s[0];
}

// knn_cand: chunk-split index recovery (d<=T, ascending within chunk, cap 16)
__global__ __launch_bounds__(64) void knn_cand(const float4* __restrict__ p1f4,
                                               const float4* __restrict__ p2f4,
                                               const float* __restrict__ Tarr,
                                               int* __restrict__ cidx,
                                               int* __restrict__ ccnt) {
  int lane = threadIdx.x;
  int blk = blockIdx.x;
  int chunk = blk & (CH_ - 1);
  int grp = (blk >> 4) & 63;
  int b = blk >> 10;
  int n1 = (grp << 6) + lane;
  int q = (b << 12) + n1;
  float4 qq = p1f4[q];
  float ax = qq.x, ay = qq.y, az = qq.z;
  const float4* pb = p2f4 + ((size_t)b << 12) + chunk * CS_;
  float T = Tarr[q];
  int cnt = 0;
  int base = (q * CH_ + chunk) * 16;
  #pragma unroll 4
  for (int t = 0; t < CS_; ++t) {
    float4 c = pb[t];
    float dx = ax - c.x, dy = ay - c.y, dz = az - c.z;
    float d = __fadd_rn(__fadd_rn(__fmul_rn(dx, dx), __fmul_rn(dy, dy)), __fmul_rn(dz, dz));
    if (d <= T && cnt < 16) { cidx[base + cnt] = chunk * CS_ + t; ++cnt; }
  }
  ccnt[q * CH_ + chunk] = cnt;
}

// knn_combine: ascending-chunk prefix fill to exactly 16 (== top_k tie-break)
__global__ __launch_bounds__(256) void knn_combine(const int* __restrict__ cidx,
                                                   const int* __restrict__ ccnt,
                                                   int* __restrict__ idxout) {
  int q = blockIdx.x * 256 + threadIdx.x;
  int tot = 0;
  int ob = q * 16;
  for (int c = 0; c < CH_; ++c) {
    int m = ccnt[q * CH_ + c];
    const int* src = cidx + (size_t)(q * CH_ + c) * 16;
    for (int i = 0; i < m && tot < 16; ++i) idxout[ob + tot++] = src[i];
  }
}

// ---------------- P[bn][o] = sum_c W0[o][coff+c] * f[b][c][n] (+bias) ----------------
__global__ __launch_bounds__(256) void pkern(const float* __restrict__ f,
                                             const float* __restrict__ W0,
                                             const float* __restrict__ bias,
                                             float* __restrict__ P, int coff) {
  __shared__ float fx[32 * 65];
  __shared__ __align__(16) float Wl[64 * 132];
  int tid = threadIdx.x;
  int bn0 = blockIdx.x * 32;
  int b = bn0 >> 12, nb0 = bn0 & (N_ - 1);

  for (int u = tid; u < 32 * 64; u += 256) {
    int c = u >> 5, nl = u & 31;
    fx[nl * 65 + c] = f[((size_t)b * C_ + c) * N_ + nb0 + nl];
  }
  for (int u = tid; u < 128 * 64; u += 256) {
    int o = u >> 6, c = u & 63;
    Wl[c * 132 + o] = W0[o * 131 + coff + c];
  }
  __syncthreads();

  int og = tid & 15, np_ = tid >> 4;
  int o0 = og * 8;
  int na = np_ * 2, nb = na + 1;
  float acc0[8], acc1[8];
  #pragma unroll
  for (int j = 0; j < 8; ++j) {
    float bv = bias ? bias[o0 + j] : 0.f;
    acc0[j] = bv; acc1[j] = bv;
  }
  for (int c = 0; c < 64; ++c) {
    float x0 = fx[na * 65 + c], x1 = fx[nb * 65 + c];
    float4 wa = *(const float4*)&Wl[c * 132 + o0];
    float4 wb = *(const float4*)&Wl[c * 132 + o0 + 4];
    float w[8] = {wa.x, wa.y, wa.z, wa.w, wb.x, wb.y, wb.z, wb.w};
    #pragma unroll
    for (int j = 0; j < 8; ++j) {
      acc0[j] = fmaf(x0, w[j], acc0[j]);
      acc1[j] = fmaf(x1, w[j], acc1[j]);
    }
  }
  float* Pa = P + (size_t)(bn0 + na) * 128 + o0;
  float* Pb = P + (size_t)(bn0 + nb) * 128 + o0;
  *(float4*)Pa = make_float4(acc0[0], acc0[1], acc0[2], acc0[3]);
  *(float4*)(Pa + 4) = make_float4(acc0[4], acc0[5], acc0[6], acc0[7]);
  *(float4*)Pb = make_float4(acc1[0], acc1[1], acc1[2], acc1[3]);
  *(float4*)(Pb + 4) = make_float4(acc1[4], acc1[5], acc1[6], acc1[7]);
}

// ---------------- BN0 stats over x0 = P1 + P2[idx] + W0a*rel_xyz ----------------
__global__ __launch_bounds__(256) void stats0_kernel(
    const float* __restrict__ P1, const float* __restrict__ P2,
    const int* __restrict__ idx, const float4* __restrict__ p1f4,
    const float4* __restrict__ p2f4, const float* __restrict__ w0at,
    float* __restrict__ stats) {
  int tid = threadIdx.x;
  int c = tid & 127, h = tid >> 7;
  float w0 = w0at[c], w1 = w0at[128 + c], w2 = w0at[256 + c];
  float sum = 0.f, sq = 0.f;
  int rbase = blockIdx.x * 256 + h * 128;
  for (int i = 0; i < 128; ++i) {
    int r = rbase + i;
    int b = r >> 16;
    int nk = r & (NK_ - 1);
    int n = nk >> 4;
    int j = idx[r];
    float4 pq = p1f4[(b << 12) + n];
    float4 pj = p2f4[(b << 12) + j];
    float rx = pj.x - pq.x, ry = pj.y - pq.y, rz = pj.z - pq.z;
    float a0 = w0 * rx + w1 * ry + w2 * rz;
    float x = P1[(size_t)((b << 12) + n) * 128 + c] +
              P2[(size_t)((b << 12) + j) * 128 + c] + a0;
    sum += x;
    sq = fmaf(x, x, sq);
  }
  __shared__ float red[256 * 2];
  red[tid * 2] = sum;
  red[tid * 2 + 1] = sq;
  __syncthreads();
  if (h == 0) {
    atomicAdd(stats + c, sum + red[(tid + 128) * 2]);
    atomicAdd(stats + 128 + c, sq + red[(tid + 128) * 2 + 1]);
  }
}

// ---------------- BN finalize ----------------
__global__ void bnfin_kernel(const float* __restrict__ stats, const float* __restrict__ gamma,
                             const float* __restrict__ beta, float* __restrict__ bnp) {
  int o = threadIdx.x;
  const float invM = 1.0f / (float)M_;
  float mean = stats[o] * invM;
  float var = stats[128 + o] * invM - mean * mean;
  float s = gamma[o] * rsqrtf(var + BN_EPS_);
  bnp[o] = s;
  bnp[128 + o] = beta[o] - mean * s;
}

// ---------------- layer1 (MFMA): assemble x0 -> BN0+relu -> bf16 GEMM W1 -> x1(bf16) + stats1 ----------------
// Coalesced staging: lane (row = tid>>4 (+16/pass), colchunk = tid&15) -> 1KB/wave bursts.
__global__ __launch_bounds__(256) void layer1_mfma(
    const float* __restrict__ P1, const float* __restrict__ P2,
    const int* __restrict__ idx, const float4* __restrict__ p1f4,
    const float4* __restrict__ p2f4, const float* __restrict__ w0at,
    const float* __restrict__ bnp0, const unsigned short* __restrict__ W1b,
    const float* __restrict__ b1, unsigned short* __restrict__ x1out,
    float* __restrict__ stats1) {
  __shared__ __align__(16) unsigned short Xs[128 * 136];   // [row][k], pad 8 bf16
  __shared__ float sred[4 * 128 * 2];
  int tid = threadIdx.x;
  int R0 = blockIdx.x * 128;
  int b = R0 >> 16;
  int n0 = (R0 & (NK_ - 1)) >> 4;

  int cc = (tid & 15) * 8;     // column base (fixed across passes)
  int r0l = tid >> 4;          // row within pass group [0,16)

  // ---- stage X (bf16), coalesced ----
  {
    float wxv[8], wyv[8], wzv[8], svv[8], tvv[8];
    *(float4*)&wxv[0] = *(const float4*)(w0at + cc);       *(float4*)&wxv[4] = *(const float4*)(w0at + cc + 4);
    *(float4*)&wyv[0] = *(const float4*)(w0at + 128 + cc); *(float4*)&wyv[4] = *(const float4*)(w0at + 132 + cc);
    *(float4*)&wzv[0] = *(const float4*)(w0at + 256 + cc); *(float4*)&wzv[4] = *(const float4*)(w0at + 260 + cc);
    *(float4*)&svv[0] = *(const float4*)(bnp0 + cc);       *(float4*)&svv[4] = *(const float4*)(bnp0 + cc + 4);
    *(float4*)&tvv[0] = *(const float4*)(bnp0 + 128 + cc); *(float4*)&tvv[4] = *(const float4*)(bnp0 + 132 + cc);
    #pragma unroll 2
    for (int p = 0; p < 8; ++p) {
      int rl = r0l + p * 16;
      int r = R0 + rl;
      int n = n0 + (rl >> 4);
      int j = idx[r];                          // quarter-wave uniform -> broadcast
      float4 pq = p1f4[(b << 12) + n], pj = p2f4[(b << 12) + j];
      float rx = pj.x - pq.x, ry = pj.y - pq.y, rz = pj.z - pq.z;
      const float* P1r = P1 + (size_t)((b << 12) + n) * 128 + cc;
      const float* P2r = P2 + (size_t)((b << 12) + j) * 128 + cc;
      float p1v[8], p2v[8];
      *(float4*)&p1v[0] = *(const float4*)(P1r);     *(float4*)&p1v[4] = *(const float4*)(P1r + 4);
      *(float4*)&p2v[0] = *(const float4*)(P2r);     *(float4*)&p2v[4] = *(const float4*)(P2r + 4);
      float y[8];
      #pragma unroll
      for (int u = 0; u < 8; ++u) {
        float x = p1v[u] + p2v[u] + wxv[u] * rx + wyv[u] * ry + wzv[u] * rz;
        y[u] = fmaxf(fmaf(svv[u], x, tvv[u]), 0.f);
      }
      uint4 pk;
      pk.x = pk2bf(y[0], y[1]); pk.y = pk2bf(y[2], y[3]);
      pk.z = pk2bf(y[4], y[5]); pk.w = pk2bf(y[6], y[7]);
      *(uint4*)&Xs[rl * 136 + cc] = pk;
    }
  }
  __syncthreads();

  // ---- MFMA: wave w computes rows [w*32, w*32+32) x all 128 cols ----
  int w = tid >> 6, lane = tid & 63;
  int m16 = lane & 15, qd = lane >> 4;
  f32x4 acc[2][8];
  #pragma unroll
  for (int mt = 0; mt < 2; ++mt)
    #pragma unroll
    for (int nt = 0; nt < 8; ++nt) acc[mt][nt] = (f32x4){0.f, 0.f, 0.f, 0.f};

  const unsigned short* Ab = &Xs[(w * 32 + m16) * 136 + qd * 8];
  const unsigned short* Bb = W1b + m16 * 128 + qd * 8;
  #pragma unroll 1
  for (int q = 0; q < 4; ++q) {
    bf16x8 A0 = *(const bf16x8*)(Ab + q * 32);
    bf16x8 A1 = *(const bf16x8*)(Ab + 16 * 136 + q * 32);
    #pragma unroll
    for (int nt = 0; nt < 8; ++nt) {
      bf16x8 Bv = *(const bf16x8*)(Bb + nt * 16 * 128 + q * 32);
      acc[0][nt] = __builtin_amdgcn_mfma_f32_16x16x32_bf16(A0, Bv, acc[0][nt], 0, 0, 0);
      acc[1][nt] = __builtin_amdgcn_mfma_f32_16x16x32_bf16(A1, Bv, acc[1][nt], 0, 0, 0);
    }
  }
  __syncthreads();   // all Xs reads done; Xs is now reused for the D-transpose

  // ---- epilogue: bias + stats (registers), D -> Xs (bf16) ----
  float ssum[8], ssq[8];
  #pragma unroll
  for (int nt = 0; nt < 8; ++nt) { ssum[nt] = 0.f; ssq[nt] = 0.f; }
  #pragma unroll
  for (int nt = 0; nt < 8; ++nt) {
    int col = nt * 16 + m16;
    float bb = b1[col];
    #pragma unroll
    for (int mt = 0; mt < 2; ++mt) {
      #pragma unroll
      for (int rg = 0; rg < 4; ++rg) {
        float y = acc[mt][nt][rg] + bb;
        ssum[nt] += y;
        ssq[nt] = fmaf(y, y, ssq[nt]);
        Xs[(w * 32 + mt * 16 + qd * 4 + rg) * 136 + col] = f2bf(y);
      }
    }
  }
  #pragma unroll
  for (int nt = 0; nt < 8; ++nt) {
    ssum[nt] += __shfl_xor(ssum[nt], 16);
    ssum[nt] += __shfl_xor(ssum[nt], 32);
    ssq[nt] += __shfl_xor(ssq[nt], 16);
    ssq[nt] += __shfl_xor(ssq[nt], 32);
  }
  if (lane < 16) {
    #pragma unroll
    for (int nt = 0; nt < 8; ++nt) {
      sred[(w * 128 + nt * 16 + lane) * 2] = ssum[nt];
      sred[(w * 128 + nt * 16 + lane) * 2 + 1] = ssq[nt];
    }
  }
  __syncthreads();
  if (tid < 128) {
    float a = 0.f, q2 = 0.f;
    #pragma unroll
    for (int ww = 0; ww < 4; ++ww) {
      a += sred[(ww * 128 + tid) * 2];
      q2 += sred[(ww * 128 + tid) * 2 + 1];
    }
    atomicAdd(stats1 + tid, a);
    atomicAdd(stats1 + 128 + tid, q2);
  }
  // ---- coalesced x1 store from Xs: 1KB/wave bursts ----
  #pragma unroll
  for (int p = 0; p < 8; ++p) {
    int rl = r0l + p * 16;
    uint4 v = *(const uint4*)&Xs[rl * 136 + cc];
    *(uint4*)(x1out + (size_t)(R0 + rl) * 128 + cc) = v;
  }
}

// ---------------- layer2 (MFMA): BN1+relu -> bf16 GEMM W2 -> k-max/min + stats2 ----------------
__global__ __launch_bounds__(256) void layer2_mfma(
    const unsigned short* __restrict__ x1, const float* __restrict__ bnp1,
    const unsigned short* __restrict__ W2b, const float* __restrict__ b2,
    float* __restrict__ ymaxo, float* __restrict__ ymino,
    float* __restrict__ stats2) {
  __shared__ __align__(16) unsigned short Xs[128 * 136];
  __shared__ float sred[4 * 128 * 2];
  int tid = threadIdx.x;
  int R0 = blockIdx.x * 128;
  int b = R0 >> 16;
  int n0 = (R0 & (NK_ - 1)) >> 4;

  int cc = (tid & 15) * 8;
  int r0l = tid >> 4;

  // ---- stage X (bf16): BN1+relu on x1, coalesced 1KB/wave ----
  {
    float svv[8], tvv[8];
    *(float4*)&svv[0] = *(const float4*)(bnp1 + cc);       *(float4*)&svv[4] = *(const float4*)(bnp1 + cc + 4);
    *(float4*)&tvv[0] = *(const float4*)(bnp1 + 128 + cc); *(float4*)&tvv[4] = *(const float4*)(bnp1 + 132 + cc);
    #pragma unroll 2
    for (int p = 0; p < 8; ++p) {
      int rl = r0l + p * 16;
      uint4 pv = *(const uint4*)(x1 + (size_t)(R0 + rl) * 128 + cc);
      float xv[8];
      xv[0] = __uint_as_float(pv.x << 16); xv[1] = __uint_as_float(pv.x & 0xFFFF0000u);
      xv[2] = __uint_as_float(pv.y << 16); xv[3] = __uint_as_float(pv.y & 0xFFFF0000u);
      xv[4] = __uint_as_float(pv.z << 16); xv[5] = __uint_as_float(pv.z & 0xFFFF0000u);
      xv[6] = __uint_as_float(pv.w << 16); xv[7] = __uint_as_float(pv.w & 0xFFFF0000u);
      float y[8];
      #pragma unroll
      for (int u = 0; u < 8; ++u) y[u] = fmaxf(fmaf(svv[u], xv[u], tvv[u]), 0.f);
      uint4 pk;
      pk.x = pk2bf(y[0], y[1]); pk.y = pk2bf(y[2], y[3]);
      pk.z = pk2bf(y[4], y[5]); pk.w = pk2bf(y[6], y[7]);
      *(uint4*)&Xs[rl * 136 + cc] = pk;
    }
  }
  __syncthreads();

  int w = tid >> 6, lane = tid & 63;
  int m16 = lane & 15, qd = lane >> 4;
  f32x4 acc[2][8];
  #pragma unroll
  for (int mt = 0; mt < 2; ++mt)
    #pragma unroll
    for (int nt = 0; nt < 8; ++nt) acc[mt][nt] = (f32x4){0.f, 0.f, 0.f, 0.f};

  const unsigned short* Ab = &Xs[(w * 32 + m16) * 136 + qd * 8];
  const unsigned short* Bb = W2b + m16 * 128 + qd * 8;
  #pragma unroll 1
  for (int q = 0; q < 4; ++q) {
    bf16x8 A0 = *(const bf16x8*)(Ab + q * 32);
    bf16x8 A1 = *(const bf16x8*)(Ab + 16 * 136 + q * 32);
    #pragma unroll
    for (int nt = 0; nt < 8; ++nt) {
      bf16x8 Bv = *(const bf16x8*)(Bb + nt * 16 * 128 + q * 32);
      acc[0][nt] = __builtin_amdgcn_mfma_f32_16x16x32_bf16(A0, Bv, acc[0][nt], 0, 0, 0);
      acc[1][nt] = __builtin_amdgcn_mfma_f32_16x16x32_bf16(A1, Bv, acc[1][nt], 0, 0, 0);
    }
  }

  // ---- epilogue: bias, stats2, k-max/min over 16 rows ----
  float ssum[8], ssq[8], mxv[2][8], mnv[2][8];
  #pragma unroll
  for (int nt = 0; nt < 8; ++nt) { ssum[nt] = 0.f; ssq[nt] = 0.f; }
  #pragma unroll
  for (int nt = 0; nt < 8; ++nt) {
    float bb = b2[nt * 16 + m16];
    #pragma unroll
    for (int mt = 0; mt < 2; ++mt) {
      float y0 = acc[mt][nt][0] + bb;
      float mx = y0, mn = y0, su = y0, sq = y0 * y0;
      #pragma unroll
      for (int rg = 1; rg < 4; ++rg) {
        float y = acc[mt][nt][rg] + bb;
        mx = fmaxf(mx, y); mn = fminf(mn, y);
        su += y; sq = fmaf(y, y, sq);
      }
      mxv[mt][nt] = mx; mnv[mt][nt] = mn;
      ssum[nt] += su; ssq[nt] += sq;
    }
  }
  // k-reduction across qd (lanes xor 16, 32 share col & point)
  #pragma unroll
  for (int nt = 0; nt < 8; ++nt)
    #pragma unroll
    for (int mt = 0; mt < 2; ++mt) {
      mxv[mt][nt] = fmaxf(mxv[mt][nt], __shfl_xor(mxv[mt][nt], 16));
      mxv[mt][nt] = fmaxf(mxv[mt][nt], __shfl_xor(mxv[mt][nt], 32));
      mnv[mt][nt] = fminf(mnv[mt][nt], __shfl_xor(mnv[mt][nt], 16));
      mnv[mt][nt] = fminf(mnv[mt][nt], __shfl_xor(mnv[mt][nt], 32));
    }
  if (lane < 16) {
    #pragma unroll
    for (int mt = 0; mt < 2; ++mt) {
      int n = n0 + w * 2 + mt;
      size_t base = ((size_t)(b << 12) + n) * 128;
      #pragma unroll
      for (int nt = 0; nt < 8; ++nt) {
        ymaxo[base + nt * 16 + lane] = mxv[mt][nt];
        ymino[base + nt * 16 + lane] = mnv[mt][nt];
      }
    }
  }
  #pragma unroll
  for (int nt = 0; nt < 8; ++nt) {
    ssum[nt] += __shfl_xor(ssum[nt], 16);
    ssum[nt] += __shfl_xor(ssum[nt], 32);
    ssq[nt] += __shfl_xor(ssq[nt], 16);
    ssq[nt] += __shfl_xor(ssq[nt], 32);
  }
  if (lane < 16) {
    #pragma unroll
    for (int nt = 0; nt < 8; ++nt) {
      sred[(w * 128 + nt * 16 + lane) * 2] = ssum[nt];
      sred[(w * 128 + nt * 16 + lane) * 2 + 1] = ssq[nt];
    }
  }
  __syncthreads();
  if (tid < 128) {
    float a = 0.f, q2 = 0.f;
    #pragma unroll
    for (int ww = 0; ww < 4; ++ww) {
      a += sred[(ww * 128 + tid) * 2];
      q2 += sred[(ww * 128 + tid) * 2 + 1];
    }
    atomicAdd(stats2 + tid, a);
    atomicAdd(stats2 + 128 + tid, q2);
  }
}

// ---------------- final: BN2+relu on max/min, transpose to (B,128,N) ----------------
__global__ __launch_bounds__(256) void final_kernel(const float* __restrict__ ymaxo,
                                                    const float* __restrict__ ymino,
                                                    const float* __restrict__ bnp2,
                                                    float* __restrict__ out) {
  __shared__ float T[64 * 129];
  int tid = threadIdx.x;
  int b = blockIdx.x >> 6;
  int n0 = (blockIdx.x & 63) * 64;
  for (int u = tid; u < 64 * 128; u += 256) {
    int nl = u >> 7, o = u & 127;
    size_t base = ((size_t)(b << 12) + n0 + nl) * 128 + o;
    float s = bnp2[o], t = bnp2[128 + o];
    float v = fmaf(s, (s >= 0.f ? ymaxo[base] : ymino[base]), t);
    T[nl * 129 + o] = fmaxf(v, 0.f);
  }
  __syncthreads();
  for (int u = tid; u < 64 * 128; u += 256) {
    int o = u >> 6, nl = u & 63;
    out[((size_t)b * 128 + o) * N_ + n0 + nl] = T[nl * 129 + o];
  }
}

extern "C" void kernel_launch(void* const* d_in, const int* in_sizes, int n_in,
                              void* d_out, int out_size, void* d_ws, size_t ws_size,
                              hipStream_t stream) {
  (void)in_sizes; (void)n_in; (void)out_size; (void)ws_size;
  const float* points1 = (const float*)d_in[0];
  const float* points2 = (const float*)d_in[1];
  const float* features1 = (const float*)d_in[2];
  const float* features2 = (const float*)d_in[3];
  const float* W0 = (const float*)d_in[4];
  const float* b0 = (const float*)d_in[5];
  const float* g0 = (const float*)d_in[6];
  const float* be0 = (const float*)d_in[7];
  const float* W1 = (const float*)d_in[8];
  const float* b1 = (const float*)d_in[9];
  const float* g1 = (const float*)d_in[10];
  const float* be1 = (const float*)d_in[11];
  const float* W2 = (const float*)d_in[12];
  const float* b2 = (const float*)d_in[13];
  const float* g2 = (const float*)d_in[14];
  const float* be2 = (const float*)d_in[15];
  float* out = (float*)d_out;

  char* ws = (char*)d_ws;
  size_t off = 0;
  auto alloc = [&](size_t bytes) -> void* {
    void* p = ws + off;
    off += (bytes + 255) & ~(size_t)255;
    return p;
  };
  int* idx = (int*)alloc((size_t)M_ * 4);
  float4* p1f4 = (float4*)alloc((size_t)B_ * N_ * 16);
  float4* p2f4 = (float4*)alloc((size_t)B_ * N_ * 16);
  float* P1 = (float*)alloc((size_t)B_ * N_ * 128 * 4);
  float* P2 = (float*)alloc((size_t)B_ * N_ * 128 * 4);
  unsigned short* W1b = (unsigned short*)alloc(128 * 128 * 2);
  unsigned short* W2b = (unsigned short*)alloc(128 * 128 * 2);
  float* w0at = (float*)alloc(3 * 128 * 4);
  float* stats = (float*)alloc(3 * 256 * 4);
  float* bnp = (float*)alloc(3 * 256 * 4);
  unsigned short* x1 = (unsigned short*)alloc((size_t)M_ * 128 * 2);  // 128 MB (bf16)
  float* ymaxo = (float*)alloc((size_t)B_ * N_ * 128 * 4);
  float* ymino = (float*)alloc((size_t)B_ * N_ * 128 * 4);

  // KNN scratch aliased onto x1 (dead until layer1): ~66.2 MB < 128 MB
  float* pvals = (float*)x1;                                         // 32 MB
  int* cidx = (int*)((char*)x1 + (size_t)32 * 1024 * 1024);          // 32 MB
  int* ccnt = (int*)((char*)x1 + (size_t)64 * 1024 * 1024);          // 2 MB
  float* Tarr = (float*)((char*)x1 + (size_t)66 * 1024 * 1024);      // 128 KB

  hipMemsetAsync(stats, 0, 3 * 256 * 4, stream);

  pack_pts<<<B_ * N_ / 256, 256, 0, stream>>>(points1, p1f4);
  pack_pts<<<B_ * N_ / 256, 256, 0, stream>>>(points2, p2f4);
  wcvt<<<64, 256, 0, stream>>>(W1, W1b);
  wcvt<<<64, 256, 0, stream>>>(W2, W2b);
  make_w0at<<<1, 128, 0, stream>>>(W0, w0at);

  knn_part<<<B_ * 64 * CH_, 64, 0, stream>>>(p1f4, p2f4, pvals);
  knn_merge<<<Q_ / 256, 256, 0, stream>>>(pvals, Tarr);
  knn_cand<<<B_ * 64 * CH_, 64, 0, stream>>>(p1f4, p2f4, Tarr, cidx, ccnt);
  knn_combine<<<Q_ / 256, 256, 0, stream>>>(cidx, ccnt, idx);

  pkern<<<B_ * N_ / 32, 256, 0, stream>>>(features1, W0, b0, P1, 67);
  pkern<<<B_ * N_ / 32, 256, 0, stream>>>(features2, W0, nullptr, P2, 3);

  stats0_kernel<<<M_ / 256, 256, 0, stream>>>(P1, P2, idx, p1f4, p2f4, w0at, stats);
  bnfin_kernel<<<1, 128, 0, stream>>>(stats, g0, be0, bnp);

  layer1_mfma<<<M_ / 128, 256, 0, stream>>>(P1, P2, idx, p1f4, p2f4, w0at, bnp,
                                            W1b, b1, x1, stats + 256);
  bnfin_kernel<<<1, 128, 0, stream>>>(stats + 256, g1, be1, bnp + 256);

  layer2_mfma<<<M_ / 128, 256, 0, stream>>>(x1, bnp + 256, W2b, b2, ymaxo, ymino,
                                            stats + 512);
  bnfin_kernel<<<1, 128, 0, stream>>>(stats + 512, g2, be2, bnp + 512);

  final_kernel<<<B_ * N_ / 64, 256, 0, stream>>>(ymaxo, ymino, bnp + 512, out);
}

// Round 7
// 700.747 us; speedup vs baseline: 2.1203x; 1.0278x over previous
//
#include <hip/hip_runtime.h>

#define B_ 8
#define N_ 4096
#define K_ 16
#define C_ 64
#define NK_ (N_*K_)            // 65536
#define M_ (B_*N_*K_)          // 524288
#define BN_EPS_ 0.001f
#define CH_ 16                 // knn candidate chunks
#define CS_ (N_/CH_)           // 256 candidates per chunk
#define Q_ (B_*N_)             // 32768 queries

typedef short bf16x8 __attribute__((ext_vector_type(8)));   // 8 bf16 = 4 VGPRs
typedef float f32x4 __attribute__((ext_vector_type(4)));

// bf16 round-to-nearest-even (no NaN inputs in this pipeline)
static __device__ __forceinline__ unsigned short f2bf(float x) {
  unsigned u = __float_as_uint(x);
  unsigned r = (u + 0x7FFFu + ((u >> 16) & 1u)) >> 16;
  return (unsigned short)r;
}
static __device__ __forceinline__ unsigned pk2bf(float a, float b) {
  return (unsigned)f2bf(a) | ((unsigned)f2bf(b) << 16);
}

// ---------------- pack points (B,3,N) -> float4 (B*N) ----------------
__global__ __launch_bounds__(256) void pack_pts(const float* __restrict__ p,
                                                float4* __restrict__ pf4) {
  int i = blockIdx.x * 256 + threadIdx.x;
  int b = i >> 12;
  int n = i & (N_ - 1);
  const float* base = p + (size_t)b * 3 * N_;
  pf4[i] = make_float4(base[n], base[N_ + n], base[2 * N_ + n], 0.f);
}

// ---------------- W (128x128 fp32) -> bf16 same layout ----------------
__global__ __launch_bounds__(256) void wcvt(const float* __restrict__ W,
                                            unsigned short* __restrict__ Wb) {
  int i = blockIdx.x * 256 + threadIdx.x;   // 16384
  Wb[i] = f2bf(W[i]);
}

// ---------------- w0at[d][o] = W0[o][d], d<3 ----------------
__global__ void make_w0at(const float* __restrict__ W0, float* __restrict__ w0at) {
  int o = threadIdx.x;  // 128
  for (int d = 0; d < 3; ++d) w0at[d * 128 + o] = W0[o * 131 + d];
}

// ================= KNN, candidate-split 16 ways =================
// Sorted-16 insert via v_med3_f32: for desc-sorted s, max(s[i+1],min(s[i],d)) == median3.
__global__ __launch_bounds__(64) void knn_part(const float4* __restrict__ p1f4,
                                               const float4* __restrict__ p2f4,
                                               float* __restrict__ pvals) {
  int lane = threadIdx.x;
  int blk = blockIdx.x;            // chunk fastest: b(8) x grp(64) x chunk(16)
  int chunk = blk & (CH_ - 1);
  int grp = (blk >> 4) & 63;
  int b = blk >> 10;
  int n1 = (grp << 6) + lane;
  int q = (b << 12) + n1;
  float4 qv = p1f4[q];
  float ax = qv.x, ay = qv.y, az = qv.z;
  const float4* pb = p2f4 + ((size_t)b << 12) + chunk * CS_;

  float s[16];
  #pragma unroll
  for (int i = 0; i < 16; ++i) s[i] = 3.0e38f;   // desc sorted; s[0]=16th smallest

  #pragma unroll 8
  for (int t = 0; t < CS_; ++t) {
    float4 c = pb[t];              // wave-uniform -> scalar load
    float dx = ax - c.x, dy = ay - c.y, dz = az - c.z;
    float d = __fadd_rn(__fadd_rn(__fmul_rn(dx, dx), __fmul_rn(dy, dy)), __fmul_rn(dz, dz));
    #pragma unroll
    for (int i = 0; i < 15; ++i) s[i] = __builtin_amdgcn_fmed3f(s[i], s[i + 1], d);
    s[15] = fminf(s[15], d);
  }
  // transposed store: pvals[slot][q], coalesced along q
  #pragma unroll
  for (int i = 0; i < 16; ++i) pvals[(size_t)(chunk * 16 + i) * Q_ + q] = s[i];
}

// knn_merge: 1 thread/query; T = 16th smallest of CH_*16 partials (coalesced loads)
__global__ __launch_bounds__(256) void knn_merge(const float* __restrict__ pvals,
                                                 float* __restrict__ Tarr) {
  int q = blockIdx.x * 256 + threadIdx.x;
  float s[16];
  #pragma unroll
  for (int i = 0; i < 16; ++i) s[i] = 3.0e38f;
  #pragma unroll 8
  for (int t = 0; t < CH_ * 16; ++t) {
    float d = pvals[(size_t)t * Q_ + q];
    #pragma unroll
    for (int i = 0; i < 15; ++i) s[i] = __builtin_amdgcn_fmed3f(s[i], s[i + 1], d);
    s[15] = fminf(s[15], d);
  }
  Tarr[q] = s[0];
}

// knn_cand: chunk-split index recovery (d<=T, ascending within chunk, cap 16)
__global__ __launch_bounds__(64) void knn_cand(const float4* __restrict__ p1f4,
                                               const float4* __restrict__ p2f4,
                                               const float* __restrict__ Tarr,
                                               int* __restrict__ cidx,
                                               int* __restrict__ ccnt) {
  int lane = threadIdx.x;
  int blk = blockIdx.x;
  int chunk = blk & (CH_ - 1);
  int grp = (blk >> 4) & 63;
  int b = blk >> 10;
  int n1 = (grp << 6) + lane;
  int q = (b << 12) + n1;
  float4 qq = p1f4[q];
  float ax = qq.x, ay = qq.y, az = qq.z;
  const float4* pb = p2f4 + ((size_t)b << 12) + chunk * CS_;
  float T = Tarr[q];
  int cnt = 0;
  int base = (q * CH_ + chunk) * 16;
  #pragma unroll 4
  for (int t = 0; t < CS_; ++t) {
    float4 c = pb[t];
    float dx = ax - c.x, dy = ay - c.y, dz = az - c.z;
    float d = __fadd_rn(__fadd_rn(__fmul_rn(dx, dx), __fmul_rn(dy, dy)), __fmul_rn(dz, dz));
    if (d <= T && cnt < 16) { cidx[base + cnt] = chunk * CS_ + t; ++cnt; }
  }
  ccnt[q * CH_ + chunk] = cnt;
}

// knn_combine: ascending-chunk prefix fill to exactly 16 (== top_k tie-break)
__global__ __launch_bounds__(256) void knn_combine(const int* __restrict__ cidx,
                                                   const int* __restrict__ ccnt,
                                                   int* __restrict__ idxout) {
  int q = blockIdx.x * 256 + threadIdx.x;
  int tot = 0;
  int ob = q * 16;
  for (int c = 0; c < CH_; ++c) {
    int m = ccnt[q * CH_ + c];
    const int* src = cidx + (size_t)(q * CH_ + c) * 16;
    for (int i = 0; i < m && tot < 16; ++i) idxout[ob + tot++] = src[i];
  }
}

// ---------------- P[bn][o] = sum_c W0[o][coff+c] * f[b][c][n] (+bias) ----------------
__global__ __launch_bounds__(256) void pkern(const float* __restrict__ f,
                                             const float* __restrict__ W0,
                                             const float* __restrict__ bias,
                                             float* __restrict__ P, int coff) {
  __shared__ float fx[32 * 65];
  __shared__ __align__(16) float Wl[64 * 132];
  int tid = threadIdx.x;
  int bn0 = blockIdx.x * 32;
  int b = bn0 >> 12, nb0 = bn0 & (N_ - 1);

  for (int u = tid; u < 32 * 64; u += 256) {
    int c = u >> 5, nl = u & 31;
    fx[nl * 65 + c] = f[((size_t)b * C_ + c) * N_ + nb0 + nl];
  }
  for (int u = tid; u < 128 * 64; u += 256) {
    int o = u >> 6, c = u & 63;
    Wl[c * 132 + o] = W0[o * 131 + coff + c];
  }
  __syncthreads();

  int og = tid & 15, np_ = tid >> 4;
  int o0 = og * 8;
  int na = np_ * 2, nb = na + 1;
  float acc0[8], acc1[8];
  #pragma unroll
  for (int j = 0; j < 8; ++j) {
    float bv = bias ? bias[o0 + j] : 0.f;
    acc0[j] = bv; acc1[j] = bv;
  }
  for (int c = 0; c < 64; ++c) {
    float x0 = fx[na * 65 + c], x1 = fx[nb * 65 + c];
    float4 wa = *(const float4*)&Wl[c * 132 + o0];
    float4 wb = *(const float4*)&Wl[c * 132 + o0 + 4];
    float w[8] = {wa.x, wa.y, wa.z, wa.w, wb.x, wb.y, wb.z, wb.w};
    #pragma unroll
    for (int j = 0; j < 8; ++j) {
      acc0[j] = fmaf(x0, w[j], acc0[j]);
      acc1[j] = fmaf(x1, w[j], acc1[j]);
    }
  }
  float* Pa = P + (size_t)(bn0 + na) * 128 + o0;
  float* Pb = P + (size_t)(bn0 + nb) * 128 + o0;
  *(float4*)Pa = make_float4(acc0[0], acc0[1], acc0[2], acc0[3]);
  *(float4*)(Pa + 4) = make_float4(acc0[4], acc0[5], acc0[6], acc0[7]);
  *(float4*)Pb = make_float4(acc1[0], acc1[1], acc1[2], acc1[3]);
  *(float4*)(Pb + 4) = make_float4(acc1[4], acc1[5], acc1[6], acc1[7]);
}

// ---------------- BN0 stats over x0 = P1 + P2[idx] + W0a*rel_xyz ----------------
__global__ __launch_bounds__(256) void stats0_kernel(
    const float* __restrict__ P1, const float* __restrict__ P2,
    const int* __restrict__ idx, const float4* __restrict__ p1f4,
    const float4* __restrict__ p2f4, const float* __restrict__ w0at,
    float* __restrict__ stats) {
  int tid = threadIdx.x;
  int c = tid & 127, h = tid >> 7;
  float w0 = w0at[c], w1 = w0at[128 + c], w2 = w0at[256 + c];
  float sum = 0.f, sq = 0.f;
  int rbase = blockIdx.x * 256 + h * 128;
  for (int i = 0; i < 128; ++i) {
    int r = rbase + i;
    int b = r >> 16;
    int nk = r & (NK_ - 1);
    int n = nk >> 4;
    int j = idx[r];
    float4 pq = p1f4[(b << 12) + n];
    float4 pj = p2f4[(b << 12) + j];
    float rx = pj.x - pq.x, ry = pj.y - pq.y, rz = pj.z - pq.z;
    float a0 = w0 * rx + w1 * ry + w2 * rz;
    float x = P1[(size_t)((b << 12) + n) * 128 + c] +
              P2[(size_t)((b << 12) + j) * 128 + c] + a0;
    sum += x;
    sq = fmaf(x, x, sq);
  }
  __shared__ float red[256 * 2];
  red[tid * 2] = sum;
  red[tid * 2 + 1] = sq;
  __syncthreads();
  if (h == 0) {
    atomicAdd(stats + c, sum + red[(tid + 128) * 2]);
    atomicAdd(stats + 128 + c, sq + red[(tid + 128) * 2 + 1]);
  }
}

// ---------------- BN finalize ----------------
__global__ void bnfin_kernel(const float* __restrict__ stats, const float* __restrict__ gamma,
                             const float* __restrict__ beta, float* __restrict__ bnp) {
  int o = threadIdx.x;
  const float invM = 1.0f / (float)M_;
  float mean = stats[o] * invM;
  float var = stats[128 + o] * invM - mean * mean;
  float s = gamma[o] * rsqrtf(var + BN_EPS_);
  bnp[o] = s;
  bnp[128 + o] = beta[o] - mean * s;
}

// ---------------- layer1 (MFMA): assemble x0 -> BN0+relu -> bf16 GEMM W1 -> x1(bf16) + stats1 ----------------
// Staging with hoisted load groups for MLP (Little's-law fix).
__global__ __launch_bounds__(256) void layer1_mfma(
    const float* __restrict__ P1, const float* __restrict__ P2,
    const int* __restrict__ idx, const float4* __restrict__ p1f4,
    const float4* __restrict__ p2f4, const float* __restrict__ w0at,
    const float* __restrict__ bnp0, const unsigned short* __restrict__ W1b,
    const float* __restrict__ b1, unsigned short* __restrict__ x1out,
    float* __restrict__ stats1) {
  __shared__ __align__(16) unsigned short Xs[128 * 136];   // [row][k], pad 8 bf16
  __shared__ float sred[4 * 128 * 2];
  int tid = threadIdx.x;
  int R0 = blockIdx.x * 128;
  int b = R0 >> 16;
  int n0 = (R0 & (NK_ - 1)) >> 4;

  int cc = (tid & 15) * 8;     // column base (fixed across passes)
  int r0l = tid >> 4;          // row within pass group [0,16)

  // ---- stage X (bf16), coalesced, MLP-hoisted ----
  {
    float wxv[8], wyv[8], wzv[8], svv[8], tvv[8];
    *(float4*)&wxv[0] = *(const float4*)(w0at + cc);       *(float4*)&wxv[4] = *(const float4*)(w0at + cc + 4);
    *(float4*)&wyv[0] = *(const float4*)(w0at + 128 + cc); *(float4*)&wyv[4] = *(const float4*)(w0at + 132 + cc);
    *(float4*)&wzv[0] = *(const float4*)(w0at + 256 + cc); *(float4*)&wzv[4] = *(const float4*)(w0at + 260 + cc);
    *(float4*)&svv[0] = *(const float4*)(bnp0 + cc);       *(float4*)&svv[4] = *(const float4*)(bnp0 + cc + 4);
    *(float4*)&tvv[0] = *(const float4*)(bnp0 + 128 + cc); *(float4*)&tvv[4] = *(const float4*)(bnp0 + 132 + cc);
    // hoist idx (8 dwords) and wave-uniform query points (s_loads)
    int jj[8];
    #pragma unroll
    for (int p = 0; p < 8; ++p) jj[p] = idx[R0 + r0l + p * 16];   // n = n0+p, k = r0l
    float4 pq8[8];
    #pragma unroll
    for (int p = 0; p < 8; ++p) pq8[p] = p1f4[(b << 12) + n0 + p];
    #pragma unroll
    for (int g = 0; g < 4; ++g) {
      float4 pjv[2], p1a[2], p1b[2], p2a[2], p2b[2];
      #pragma unroll
      for (int t = 0; t < 2; ++t) {
        int p = g * 2 + t;
        pjv[t] = p2f4[(b << 12) + jj[p]];
        const float* P1r = P1 + (size_t)((b << 12) + n0 + p) * 128 + cc;
        const float* P2r = P2 + (size_t)((b << 12) + jj[p]) * 128 + cc;
        p1a[t] = *(const float4*)P1r; p1b[t] = *(const float4*)(P1r + 4);
        p2a[t] = *(const float4*)P2r; p2b[t] = *(const float4*)(P2r + 4);
      }
      #pragma unroll
      for (int t = 0; t < 2; ++t) {
        int p = g * 2 + t;
        float rx = pjv[t].x - pq8[p].x, ry = pjv[t].y - pq8[p].y, rz = pjv[t].z - pq8[p].z;
        float p1v[8], p2v[8];
        *(float4*)&p1v[0] = p1a[t]; *(float4*)&p1v[4] = p1b[t];
        *(float4*)&p2v[0] = p2a[t]; *(float4*)&p2v[4] = p2b[t];
        float y[8];
        #pragma unroll
        for (int u = 0; u < 8; ++u) {
          float x = p1v[u] + p2v[u] + wxv[u] * rx + wyv[u] * ry + wzv[u] * rz;
          y[u] = fmaxf(fmaf(svv[u], x, tvv[u]), 0.f);
        }
        uint4 pk;
        pk.x = pk2bf(y[0], y[1]); pk.y = pk2bf(y[2], y[3]);
        pk.z = pk2bf(y[4], y[5]); pk.w = pk2bf(y[6], y[7]);
        *(uint4*)&Xs[(r0l + p * 16) * 136 + cc] = pk;
      }
    }
  }
  __syncthreads();

  // ---- MFMA: wave w computes rows [w*32, w*32+32) x all 128 cols ----
  int w = tid >> 6, lane = tid & 63;
  int m16 = lane & 15, qd = lane >> 4;
  f32x4 acc[2][8];
  #pragma unroll
  for (int mt = 0; mt < 2; ++mt)
    #pragma unroll
    for (int nt = 0; nt < 8; ++nt) acc[mt][nt] = (f32x4){0.f, 0.f, 0.f, 0.f};

  const unsigned short* Ab = &Xs[(w * 32 + m16) * 136 + qd * 8];
  const unsigned short* Bb = W1b + m16 * 128 + qd * 8;
  #pragma unroll 1
  for (int q = 0; q < 4; ++q) {
    bf16x8 A0 = *(const bf16x8*)(Ab + q * 32);
    bf16x8 A1 = *(const bf16x8*)(Ab + 16 * 136 + q * 32);
    #pragma unroll
    for (int nt = 0; nt < 8; ++nt) {
      bf16x8 Bv = *(const bf16x8*)(Bb + nt * 16 * 128 + q * 32);
      acc[0][nt] = __builtin_amdgcn_mfma_f32_16x16x32_bf16(A0, Bv, acc[0][nt], 0, 0, 0);
      acc[1][nt] = __builtin_amdgcn_mfma_f32_16x16x32_bf16(A1, Bv, acc[1][nt], 0, 0, 0);
    }
  }
  __syncthreads();   // all Xs reads done; Xs is now reused for the D-transpose

  // ---- epilogue: bias + stats (registers), D -> Xs (bf16) ----
  float ssum[8], ssq[8];
  #pragma unroll
  for (int nt = 0; nt < 8; ++nt) { ssum[nt] = 0.f; ssq[nt] = 0.f; }
  #pragma unroll
  for (int nt = 0; nt < 8; ++nt) {
    int col = nt * 16 + m16;
    float bb = b1[col];
    #pragma unroll
    for (int mt = 0; mt < 2; ++mt) {
      #pragma unroll
      for (int rg = 0; rg < 4; ++rg) {
        float y = acc[mt][nt][rg] + bb;
        ssum[nt] += y;
        ssq[nt] = fmaf(y, y, ssq[nt]);
        Xs[(w * 32 + mt * 16 + qd * 4 + rg) * 136 + col] = f2bf(y);
      }
    }
  }
  #pragma unroll
  for (int nt = 0; nt < 8; ++nt) {
    ssum[nt] += __shfl_xor(ssum[nt], 16);
    ssum[nt] += __shfl_xor(ssum[nt], 32);
    ssq[nt] += __shfl_xor(ssq[nt], 16);
    ssq[nt] += __shfl_xor(ssq[nt], 32);
  }
  if (lane < 16) {
    #pragma unroll
    for (int nt = 0; nt < 8; ++nt) {
      sred[(w * 128 + nt * 16 + lane) * 2] = ssum[nt];
      sred[(w * 128 + nt * 16 + lane) * 2 + 1] = ssq[nt];
    }
  }
  __syncthreads();
  if (tid < 128) {
    float a = 0.f, q2 = 0.f;
    #pragma unroll
    for (int ww = 0; ww < 4; ++ww) {
      a += sred[(ww * 128 + tid) * 2];
      q2 += sred[(ww * 128 + tid) * 2 + 1];
    }
    atomicAdd(stats1 + tid, a);
    atomicAdd(stats1 + 128 + tid, q2);
  }
  // ---- coalesced x1 store from Xs: 1KB/wave bursts ----
  #pragma unroll
  for (int p = 0; p < 8; ++p) {
    int rl = r0l + p * 16;
    uint4 v = *(const uint4*)&Xs[rl * 136 + cc];
    *(uint4*)(x1out + (size_t)(R0 + rl) * 128 + cc) = v;
  }
}

// ---------------- layer2 (MFMA): BN1+relu -> bf16 GEMM W2 -> k-max/min + stats2 ----------------
__global__ __launch_bounds__(256) void layer2_mfma(
    const unsigned short* __restrict__ x1, const float* __restrict__ bnp1,
    const unsigned short* __restrict__ W2b, const float* __restrict__ b2,
    float* __restrict__ ymaxo, float* __restrict__ ymino,
    float* __restrict__ stats2) {
  __shared__ __align__(16) unsigned short Xs[128 * 136];
  __shared__ float sred[4 * 128 * 2];
  int tid = threadIdx.x;
  int R0 = blockIdx.x * 128;
  int b = R0 >> 16;
  int n0 = (R0 & (NK_ - 1)) >> 4;

  int cc = (tid & 15) * 8;
  int r0l = tid >> 4;

  // ---- stage X (bf16): BN1+relu on x1; hoisted 4-load groups for MLP ----
  {
    float svv[8], tvv[8];
    *(float4*)&svv[0] = *(const float4*)(bnp1 + cc);       *(float4*)&svv[4] = *(const float4*)(bnp1 + cc + 4);
    *(float4*)&tvv[0] = *(const float4*)(bnp1 + 128 + cc); *(float4*)&tvv[4] = *(const float4*)(bnp1 + 132 + cc);
    #pragma unroll
    for (int g = 0; g < 2; ++g) {
      uint4 pv[4];
      #pragma unroll
      for (int t = 0; t < 4; ++t)
        pv[t] = *(const uint4*)(x1 + (size_t)(R0 + r0l + (g * 4 + t) * 16) * 128 + cc);
      #pragma unroll
      for (int t = 0; t < 4; ++t) {
        int rl = r0l + (g * 4 + t) * 16;
        float xv[8];
        xv[0] = __uint_as_float(pv[t].x << 16); xv[1] = __uint_as_float(pv[t].x & 0xFFFF0000u);
        xv[2] = __uint_as_float(pv[t].y << 16); xv[3] = __uint_as_float(pv[t].y & 0xFFFF0000u);
        xv[4] = __uint_as_float(pv[t].z << 16); xv[5] = __uint_as_float(pv[t].z & 0xFFFF0000u);
        xv[6] = __uint_as_float(pv[t].w << 16); xv[7] = __uint_as_float(pv[t].w & 0xFFFF0000u);
        float y[8];
        #pragma unroll
        for (int u = 0; u < 8; ++u) y[u] = fmaxf(fmaf(svv[u], xv[u], tvv[u]), 0.f);
        uint4 pk;
        pk.x = pk2bf(y[0], y[1]); pk.y = pk2bf(y[2], y[3]);
        pk.z = pk2bf(y[4], y[5]); pk.w = pk2bf(y[6], y[7]);
        *(uint4*)&Xs[rl * 136 + cc] = pk;
      }
    }
  }
  __syncthreads();

  int w = tid >> 6, lane = tid & 63;
  int m16 = lane & 15, qd = lane >> 4;
  f32x4 acc[2][8];
  #pragma unroll
  for (int mt = 0; mt < 2; ++mt)
    #pragma unroll
    for (int nt = 0; nt < 8; ++nt) acc[mt][nt] = (f32x4){0.f, 0.f, 0.f, 0.f};

  const unsigned short* Ab = &Xs[(w * 32 + m16) * 136 + qd * 8];
  const unsigned short* Bb = W2b + m16 * 128 + qd * 8;
  #pragma unroll 1
  for (int q = 0; q < 4; ++q) {
    bf16x8 A0 = *(const bf16x8*)(Ab + q * 32);
    bf16x8 A1 = *(const bf16x8*)(Ab + 16 * 136 + q * 32);
    #pragma unroll
    for (int nt = 0; nt < 8; ++nt) {
      bf16x8 Bv = *(const bf16x8*)(Bb + nt * 16 * 128 + q * 32);
      acc[0][nt] = __builtin_amdgcn_mfma_f32_16x16x32_bf16(A0, Bv, acc[0][nt], 0, 0, 0);
      acc[1][nt] = __builtin_amdgcn_mfma_f32_16x16x32_bf16(A1, Bv, acc[1][nt], 0, 0, 0);
    }
  }

  // ---- epilogue: bias, stats2, k-max/min over 16 rows ----
  float ssum[8], ssq[8], mxv[2][8], mnv[2][8];
  #pragma unroll
  for (int nt = 0; nt < 8; ++nt) { ssum[nt] = 0.f; ssq[nt] = 0.f; }
  #pragma unroll
  for (int nt = 0; nt < 8; ++nt) {
    float bb = b2[nt * 16 + m16];
    #pragma unroll
    for (int mt = 0; mt < 2; ++mt) {
      float y0 = acc[mt][nt][0] + bb;
      float mx = y0, mn = y0, su = y0, sq = y0 * y0;
      #pragma unroll
      for (int rg = 1; rg < 4; ++rg) {
        float y = acc[mt][nt][rg] + bb;
        mx = fmaxf(mx, y); mn = fminf(mn, y);
        su += y; sq = fmaf(y, y, sq);
      }
      mxv[mt][nt] = mx; mnv[mt][nt] = mn;
      ssum[nt] += su; ssq[nt] += sq;
    }
  }
  // k-reduction across qd (lanes xor 16, 32 share col & point)
  #pragma unroll
  for (int nt = 0; nt < 8; ++nt)
    #pragma unroll
    for (int mt = 0; mt < 2; ++mt) {
      mxv[mt][nt] = fmaxf(mxv[mt][nt], __shfl_xor(mxv[mt][nt], 16));
      mxv[mt][nt] = fmaxf(mxv[mt][nt], __shfl_xor(mxv[mt][nt], 32));
      mnv[mt][nt] = fminf(mnv[mt][nt], __shfl_xor(mnv[mt][nt], 16));
      mnv[mt][nt] = fminf(mnv[mt][nt], __shfl_xor(mnv[mt][nt], 32));
    }
  if (lane < 16) {
    #pragma unroll
    for (int mt = 0; mt < 2; ++mt) {
      int n = n0 + w * 2 + mt;
      size_t base = ((size_t)(b << 12) + n) * 128;
      #pragma unroll
      for (int nt = 0; nt < 8; ++nt) {
        ymaxo[base + nt * 16 + lane] = mxv[mt][nt];
        ymino[base + nt * 16 + lane] = mnv[mt][nt];
      }
    }
  }
  #pragma unroll
  for (int nt = 0; nt < 8; ++nt) {
    ssum[nt] += __shfl_xor(ssum[nt], 16);
    ssum[nt] += __shfl_xor(ssum[nt], 32);
    ssq[nt] += __shfl_xor(ssq[nt], 16);
    ssq[nt] += __shfl_xor(ssq[nt], 32);
  }
  if (lane < 16) {
    #pragma unroll
    for (int nt = 0; nt < 8; ++nt) {
      sred[(w * 128 + nt * 16 + lane) * 2] = ssum[nt];
      sred[(w * 128 + nt * 16 + lane) * 2 + 1] = ssq[nt];
    }
  }
  __syncthreads();
  if (tid < 128) {
    float a = 0.f, q2 = 0.f;
    #pragma unroll
    for (int ww = 0; ww < 4; ++ww) {
      a += sred[(ww * 128 + tid) * 2];
      q2 += sred[(ww * 128 + tid) * 2 + 1];
    }
    atomicAdd(stats2 + tid, a);
    atomicAdd(stats2 + 128 + tid, q2);
  }
}

// ---------------- final: BN2+relu on max/min, transpose to (B,128,N) ----------------
__global__ __launch_bounds__(256) void final_kernel(const float* __restrict__ ymaxo,
                                                    const float* __restrict__ ymino,
                                                    const float* __restrict__ bnp2,
                                                    float* __restrict__ out) {
  __shared__ float T[64 * 129];
  int tid = threadIdx.x;
  int b = blockIdx.x >> 6;
  int n0 = (blockIdx.x & 63) * 64;
  for (int u = tid; u < 64 * 128; u += 256) {
    int nl = u >> 7, o = u & 127;
    size_t base = ((size_t)(b << 12) + n0 + nl) * 128 + o;
    float s = bnp2[o], t = bnp2[128 + o];
    float v = fmaf(s, (s >= 0.f ? ymaxo[base] : ymino[base]), t);
    T[nl * 129 + o] = fmaxf(v, 0.f);
  }
  __syncthreads();
  for (int u = tid; u < 64 * 128; u += 256) {
    int o = u >> 6, nl = u & 63;
    out[((size_t)b * 128 + o) * N_ + n0 + nl] = T[nl * 129 + o];
  }
}

extern "C" void kernel_launch(void* const* d_in, const int* in_sizes, int n_in,
                              void* d_out, int out_size, void* d_ws, size_t ws_size,
                              hipStream_t stream) {
  (void)in_sizes; (void)n_in; (void)out_size; (void)ws_size;
  const float* points1 = (const float*)d_in[0];
  const float* points2 = (const float*)d_in[1];
  const float* features1 = (const float*)d_in[2];
  const float* features2 = (const float*)d_in[3];
  const float* W0 = (const float*)d_in[4];
  const float* b0 = (const float*)d_in[5];
  const float* g0 = (const float*)d_in[6];
  const float* be0 = (const float*)d_in[7];
  const float* W1 = (const float*)d_in[8];
  const float* b1 = (const float*)d_in[9];
  const float* g1 = (const float*)d_in[10];
  const float* be1 = (const float*)d_in[11];
  const float* W2 = (const float*)d_in[12];
  const float* b2 = (const float*)d_in[13];
  const float* g2 = (const float*)d_in[14];
  const float* be2 = (const float*)d_in[15];
  float* out = (float*)d_out;

  char* ws = (char*)d_ws;
  size_t off = 0;
  auto alloc = [&](size_t bytes) -> void* {
    void* p = ws + off;
    off += (bytes + 255) & ~(size_t)255;
    return p;
  };
  int* idx = (int*)alloc((size_t)M_ * 4);
  float4* p1f4 = (float4*)alloc((size_t)B_ * N_ * 16);
  float4* p2f4 = (float4*)alloc((size_t)B_ * N_ * 16);
  float* P1 = (float*)alloc((size_t)B_ * N_ * 128 * 4);
  float* P2 = (float*)alloc((size_t)B_ * N_ * 128 * 4);
  unsigned short* W1b = (unsigned short*)alloc(128 * 128 * 2);
  unsigned short* W2b = (unsigned short*)alloc(128 * 128 * 2);
  float* w0at = (float*)alloc(3 * 128 * 4);
  float* stats = (float*)alloc(3 * 256 * 4);
  float* bnp = (float*)alloc(3 * 256 * 4);
  unsigned short* x1 = (unsigned short*)alloc((size_t)M_ * 128 * 2);  // 128 MB (bf16)
  float* ymaxo = (float*)alloc((size_t)B_ * N_ * 128 * 4);
  float* ymino = (float*)alloc((size_t)B_ * N_ * 128 * 4);

  // KNN scratch aliased onto x1 (dead until layer1): ~66.2 MB < 128 MB
  float* pvals = (float*)x1;                                         // 32 MB
  int* cidx = (int*)((char*)x1 + (size_t)32 * 1024 * 1024);          // 32 MB
  int* ccnt = (int*)((char*)x1 + (size_t)64 * 1024 * 1024);          // 2 MB
  float* Tarr = (float*)((char*)x1 + (size_t)66 * 1024 * 1024);      // 128 KB

  hipMemsetAsync(stats, 0, 3 * 256 * 4, stream);

  pack_pts<<<B_ * N_ / 256, 256, 0, stream>>>(points1, p1f4);
  pack_pts<<<B_ * N_ / 256, 256, 0, stream>>>(points2, p2f4);
  wcvt<<<64, 256, 0, stream>>>(W1, W1b);
  wcvt<<<64, 256, 0, stream>>>(W2, W2b);
  make_w0at<<<1, 128, 0, stream>>>(W0, w0at);

  knn_part<<<B_ * 64 * CH_, 64, 0, stream>>>(p1f4, p2f4, pvals);
  knn_merge<<<Q_ / 256, 256, 0, stream>>>(pvals, Tarr);
  knn_cand<<<B_ * 64 * CH_, 64, 0, stream>>>(p1f4, p2f4, Tarr, cidx, ccnt);
  knn_combine<<<Q_ / 256, 256, 0, stream>>>(cidx, ccnt, idx);

  pkern<<<B_ * N_ / 32, 256, 0, stream>>>(features1, W0, b0, P1, 67);
  pkern<<<B_ * N_ / 32, 256, 0, stream>>>(features2, W0, nullptr, P2, 3);

  stats0_kernel<<<M_ / 256, 256, 0, stream>>>(P1, P2, idx, p1f4, p2f4, w0at, stats);
  bnfin_kernel<<<1, 128, 0, stream>>>(stats, g0, be0, bnp);

  layer1_mfma<<<M_ / 128, 256, 0, stream>>>(P1, P2, idx, p1f4, p2f4, w0at, bnp,
                                            W1b, b1, x1, stats + 256);
  bnfin_kernel<<<1, 128, 0, stream>>>(stats + 256, g1, be1, bnp + 256);

  layer2_mfma<<<M_ / 128, 256, 0, stream>>>(x1, bnp + 256, W2b, b2, ymaxo, ymino,
                                            stats + 512);
  bnfin_kernel<<<1, 128, 0, stream>>>(stats + 512, g2, be2, bnp + 512);

  final_kernel<<<B_ * N_ / 64, 256, 0, stream>>>(ymaxo, ymino, bnp + 512, out);
}

// Round 8
// 599.843 us; speedup vs baseline: 2.4770x; 1.1682x over previous
//
#include <hip/hip_runtime.h>

#define B_ 8
#define N_ 4096
#define K_ 16
#define C_ 64
#define NK_ (N_*K_)            // 65536
#define M_ (B_*N_*K_)          // 524288
#define BN_EPS_ 0.001f
#define CH_ 16                 // knn candidate chunks
#define CS_ (N_/CH_)           // 256 candidates per chunk
#define Q_ (B_*N_)             // 32768 queries
#define NB1_ (M_/128)          // 4096 blocks in layer kernels
#define NB0_ (M_/256)          // 2048 blocks in stats0

typedef short bf16x8 __attribute__((ext_vector_type(8)));   // 8 bf16 = 4 VGPRs
typedef float f32x4 __attribute__((ext_vector_type(4)));

// bf16 round-to-nearest-even (no NaN inputs in this pipeline)
static __device__ __forceinline__ unsigned short f2bf(float x) {
  unsigned u = __float_as_uint(x);
  unsigned r = (u + 0x7FFFu + ((u >> 16) & 1u)) >> 16;
  return (unsigned short)r;
}
static __device__ __forceinline__ unsigned pk2bf(float a, float b) {
  return (unsigned)f2bf(a) | ((unsigned)f2bf(b) << 16);
}

// ---------------- pack points (B,3,N) -> float4 (B*N) ----------------
__global__ __launch_bounds__(256) void pack_pts(const float* __restrict__ p,
                                                float4* __restrict__ pf4) {
  int i = blockIdx.x * 256 + threadIdx.x;
  int b = i >> 12;
  int n = i & (N_ - 1);
  const float* base = p + (size_t)b * 3 * N_;
  pf4[i] = make_float4(base[n], base[N_ + n], base[2 * N_ + n], 0.f);
}

// ---------------- W (128x128 fp32) -> bf16 same layout ----------------
__global__ __launch_bounds__(256) void wcvt(const float* __restrict__ W,
                                            unsigned short* __restrict__ Wb) {
  int i = blockIdx.x * 256 + threadIdx.x;   // 16384
  Wb[i] = f2bf(W[i]);
}

// ---------------- w0at[d][o] = W0[o][d], d<3 ----------------
__global__ void make_w0at(const float* __restrict__ W0, float* __restrict__ w0at) {
  int o = threadIdx.x;  // 128
  for (int d = 0; d < 3; ++d) w0at[d * 128 + o] = W0[o * 131 + d];
}

// ================= KNN, candidate-split 16 ways =================
__global__ __launch_bounds__(64) void knn_part(const float4* __restrict__ p1f4,
                                               const float4* __restrict__ p2f4,
                                               float* __restrict__ pvals) {
  int lane = threadIdx.x;
  int blk = blockIdx.x;            // chunk fastest: b(8) x grp(64) x chunk(16)
  int chunk = blk & (CH_ - 1);
  int grp = (blk >> 4) & 63;
  int b = blk >> 10;
  int n1 = (grp << 6) + lane;
  int q = (b << 12) + n1;
  float4 qv = p1f4[q];
  float ax = qv.x, ay = qv.y, az = qv.z;
  const float4* pb = p2f4 + ((size_t)b << 12) + chunk * CS_;

  float s[16];
  #pragma unroll
  for (int i = 0; i < 16; ++i) s[i] = 3.0e38f;   // desc sorted; s[0]=16th smallest

  #pragma unroll 8
  for (int t = 0; t < CS_; ++t) {
    float4 c = pb[t];              // wave-uniform -> scalar load
    float dx = ax - c.x, dy = ay - c.y, dz = az - c.z;
    float d = __fadd_rn(__fadd_rn(__fmul_rn(dx, dx), __fmul_rn(dy, dy)), __fmul_rn(dz, dz));
    #pragma unroll
    for (int i = 0; i < 15; ++i) s[i] = __builtin_amdgcn_fmed3f(s[i], s[i + 1], d);
    s[15] = fminf(s[15], d);
  }
  #pragma unroll
  for (int i = 0; i < 16; ++i) pvals[(size_t)(chunk * 16 + i) * Q_ + q] = s[i];
}

__global__ __launch_bounds__(256) void knn_merge(const float* __restrict__ pvals,
                                                 float* __restrict__ Tarr) {
  int q = blockIdx.x * 256 + threadIdx.x;
  float s[16];
  #pragma unroll
  for (int i = 0; i < 16; ++i) s[i] = 3.0e38f;
  #pragma unroll 8
  for (int t = 0; t < CH_ * 16; ++t) {
    float d = pvals[(size_t)t * Q_ + q];
    #pragma unroll
    for (int i = 0; i < 15; ++i) s[i] = __builtin_amdgcn_fmed3f(s[i], s[i + 1], d);
    s[15] = fminf(s[15], d);
  }
  Tarr[q] = s[0];
}

__global__ __launch_bounds__(64) void knn_cand(const float4* __restrict__ p1f4,
                                               const float4* __restrict__ p2f4,
                                               const float* __restrict__ Tarr,
                                               int* __restrict__ cidx,
                                               int* __restrict__ ccnt) {
  int lane = threadIdx.x;
  int blk = blockIdx.x;
  int chunk = blk & (CH_ - 1);
  int grp = (blk >> 4) & 63;
  int b = blk >> 10;
  int n1 = (grp << 6) + lane;
  int q = (b << 12) + n1;
  float4 qq = p1f4[q];
  float ax = qq.x, ay = qq.y, az = qq.z;
  const float4* pb = p2f4 + ((size_t)b << 12) + chunk * CS_;
  float T = Tarr[q];
  int cnt = 0;
  int base = (q * CH_ + chunk) * 16;
  #pragma unroll 4
  for (int t = 0; t < CS_; ++t) {
    float4 c = pb[t];
    float dx = ax - c.x, dy = ay - c.y, dz = az - c.z;
    float d = __fadd_rn(__fadd_rn(__fmul_rn(dx, dx), __fmul_rn(dy, dy)), __fmul_rn(dz, dz));
    if (d <= T && cnt < 16) { cidx[base + cnt] = chunk * CS_ + t; ++cnt; }
  }
  ccnt[q * CH_ + chunk] = cnt;
}

__global__ __launch_bounds__(256) void knn_combine(const int* __restrict__ cidx,
                                                   const int* __restrict__ ccnt,
                                                   int* __restrict__ idxout) {
  int q = blockIdx.x * 256 + threadIdx.x;
  int tot = 0;
  int ob = q * 16;
  for (int c = 0; c < CH_; ++c) {
    int m = ccnt[q * CH_ + c];
    const int* src = cidx + (size_t)(q * CH_ + c) * 16;
    for (int i = 0; i < m && tot < 16; ++i) idxout[ob + tot++] = src[i];
  }
}

// ---------------- P[bn][o] = sum_c W0[o][coff+c] * f[b][c][n] (+bias) ----------------
__global__ __launch_bounds__(256) void pkern(const float* __restrict__ f,
                                             const float* __restrict__ W0,
                                             const float* __restrict__ bias,
                                             float* __restrict__ P, int coff) {
  __shared__ float fx[32 * 65];
  __shared__ __align__(16) float Wl[64 * 132];
  int tid = threadIdx.x;
  int bn0 = blockIdx.x * 32;
  int b = bn0 >> 12, nb0 = bn0 & (N_ - 1);

  for (int u = tid; u < 32 * 64; u += 256) {
    int c = u >> 5, nl = u & 31;
    fx[nl * 65 + c] = f[((size_t)b * C_ + c) * N_ + nb0 + nl];
  }
  for (int u = tid; u < 128 * 64; u += 256) {
    int o = u >> 6, c = u & 63;
    Wl[c * 132 + o] = W0[o * 131 + coff + c];
  }
  __syncthreads();

  int og = tid & 15, np_ = tid >> 4;
  int o0 = og * 8;
  int na = np_ * 2, nb = na + 1;
  float acc0[8], acc1[8];
  #pragma unroll
  for (int j = 0; j < 8; ++j) {
    float bv = bias ? bias[o0 + j] : 0.f;
    acc0[j] = bv; acc1[j] = bv;
  }
  for (int c = 0; c < 64; ++c) {
    float x0 = fx[na * 65 + c], x1 = fx[nb * 65 + c];
    float4 wa = *(const float4*)&Wl[c * 132 + o0];
    float4 wb = *(const float4*)&Wl[c * 132 + o0 + 4];
    float w[8] = {wa.x, wa.y, wa.z, wa.w, wb.x, wb.y, wb.z, wb.w};
    #pragma unroll
    for (int j = 0; j < 8; ++j) {
      acc0[j] = fmaf(x0, w[j], acc0[j]);
      acc1[j] = fmaf(x1, w[j], acc1[j]);
    }
  }
  float* Pa = P + (size_t)(bn0 + na) * 128 + o0;
  float* Pb = P + (size_t)(bn0 + nb) * 128 + o0;
  *(float4*)Pa = make_float4(acc0[0], acc0[1], acc0[2], acc0[3]);
  *(float4*)(Pa + 4) = make_float4(acc0[4], acc0[5], acc0[6], acc0[7]);
  *(float4*)Pb = make_float4(acc1[0], acc1[1], acc1[2], acc1[3]);
  *(float4*)(Pb + 4) = make_float4(acc1[4], acc1[5], acc1[6], acc1[7]);
}

// ---------------- BN0 stats over x0 = P1 + P2[idx] + W0a*rel_xyz ----------------
// Partials to part[s][blockIdx] (contention-free stores; no atomics).
__global__ __launch_bounds__(256) void stats0_kernel(
    const float* __restrict__ P1, const float* __restrict__ P2,
    const int* __restrict__ idx, const float4* __restrict__ p1f4,
    const float4* __restrict__ p2f4, const float* __restrict__ w0at,
    float* __restrict__ part) {
  int tid = threadIdx.x;
  int c = tid & 127, h = tid >> 7;
  float w0 = w0at[c], w1 = w0at[128 + c], w2 = w0at[256 + c];
  float sum = 0.f, sq = 0.f;
  int rbase = blockIdx.x * 256 + h * 128;
  for (int i = 0; i < 128; ++i) {
    int r = rbase + i;
    int b = r >> 16;
    int nk = r & (NK_ - 1);
    int n = nk >> 4;
    int j = idx[r];
    float4 pq = p1f4[(b << 12) + n];
    float4 pj = p2f4[(b << 12) + j];
    float rx = pj.x - pq.x, ry = pj.y - pq.y, rz = pj.z - pq.z;
    float a0 = w0 * rx + w1 * ry + w2 * rz;
    float x = P1[(size_t)((b << 12) + n) * 128 + c] +
              P2[(size_t)((b << 12) + j) * 128 + c] + a0;
    sum += x;
    sq = fmaf(x, x, sq);
  }
  __shared__ float red[256 * 2];
  red[tid * 2] = sum;
  red[tid * 2 + 1] = sq;
  __syncthreads();
  if (h == 0) {
    float a = sum + red[(tid + 128) * 2];
    float q2 = sq + red[(tid + 128) * 2 + 1];
    part[(size_t)c * NB0_ + blockIdx.x] = a;
    part[(size_t)(128 + c) * NB0_ + blockIdx.x] = q2;
  }
}

// ---------------- reduce partials: stats[s] = sum_i part[s][i] ----------------
__global__ __launch_bounds__(256) void reduce_stats(const float* __restrict__ part,
                                                    int nb, float* __restrict__ statso) {
  int s = blockIdx.x;     // 0..255
  int tid = threadIdx.x;
  const float* src = part + (size_t)s * nb;
  float a = 0.f;
  for (int i = tid; i < nb; i += 256) a += src[i];
  a += __shfl_xor(a, 1);  a += __shfl_xor(a, 2);  a += __shfl_xor(a, 4);
  a += __shfl_xor(a, 8);  a += __shfl_xor(a, 16); a += __shfl_xor(a, 32);
  __shared__ float red[4];
  if ((tid & 63) == 0) red[tid >> 6] = a;
  __syncthreads();
  if (tid == 0) statso[s] = red[0] + red[1] + red[2] + red[3];
}

// ---------------- BN finalize ----------------
__global__ void bnfin_kernel(const float* __restrict__ stats, const float* __restrict__ gamma,
                             const float* __restrict__ beta, float* __restrict__ bnp) {
  int o = threadIdx.x;
  const float invM = 1.0f / (float)M_;
  float mean = stats[o] * invM;
  float var = stats[128 + o] * invM - mean * mean;
  float s = gamma[o] * rsqrtf(var + BN_EPS_);
  bnp[o] = s;
  bnp[128 + o] = beta[o] - mean * s;
}

// ---------------- layer1 (MFMA): assemble x0 -> BN0+relu -> bf16 GEMM W1 -> x1(bf16) + partials ----------------
__global__ __launch_bounds__(256) void layer1_mfma(
    const float* __restrict__ P1, const float* __restrict__ P2,
    const int* __restrict__ idx, const float4* __restrict__ p1f4,
    const float4* __restrict__ p2f4, const float* __restrict__ w0at,
    const float* __restrict__ bnp0, const unsigned short* __restrict__ W1b,
    const float* __restrict__ b1, unsigned short* __restrict__ x1out,
    float* __restrict__ part) {
  __shared__ __align__(16) unsigned short Xs[128 * 136];   // [row][k], pad 8 bf16
  __shared__ float sred[4 * 128 * 2];
  int tid = threadIdx.x;
  int R0 = blockIdx.x * 128;
  int b = R0 >> 16;
  int n0 = (R0 & (NK_ - 1)) >> 4;

  int cc = (tid & 15) * 8;     // column base (fixed across passes)
  int r0l = tid >> 4;          // row within pass group [0,16)

  // ---- stage X (bf16), coalesced, MLP-hoisted ----
  {
    float wxv[8], wyv[8], wzv[8], svv[8], tvv[8];
    *(float4*)&wxv[0] = *(const float4*)(w0at + cc);       *(float4*)&wxv[4] = *(const float4*)(w0at + cc + 4);
    *(float4*)&wyv[0] = *(const float4*)(w0at + 128 + cc); *(float4*)&wyv[4] = *(const float4*)(w0at + 132 + cc);
    *(float4*)&wzv[0] = *(const float4*)(w0at + 256 + cc); *(float4*)&wzv[4] = *(const float4*)(w0at + 260 + cc);
    *(float4*)&svv[0] = *(const float4*)(bnp0 + cc);       *(float4*)&svv[4] = *(const float4*)(bnp0 + cc + 4);
    *(float4*)&tvv[0] = *(const float4*)(bnp0 + 128 + cc); *(float4*)&tvv[4] = *(const float4*)(bnp0 + 132 + cc);
    int jj[8];
    #pragma unroll
    for (int p = 0; p < 8; ++p) jj[p] = idx[R0 + r0l + p * 16];
    float4 pq8[8];
    #pragma unroll
    for (int p = 0; p < 8; ++p) pq8[p] = p1f4[(b << 12) + n0 + p];
    #pragma unroll
    for (int g = 0; g < 4; ++g) {
      float4 pjv[2], p1a[2], p1b[2], p2a[2], p2b[2];
      #pragma unroll
      for (int t = 0; t < 2; ++t) {
        int p = g * 2 + t;
        pjv[t] = p2f4[(b << 12) + jj[p]];
        const float* P1r = P1 + (size_t)((b << 12) + n0 + p) * 128 + cc;
        const float* P2r = P2 + (size_t)((b << 12) + jj[p]) * 128 + cc;
        p1a[t] = *(const float4*)P1r; p1b[t] = *(const float4*)(P1r + 4);
        p2a[t] = *(const float4*)P2r; p2b[t] = *(const float4*)(P2r + 4);
      }
      #pragma unroll
      for (int t = 0; t < 2; ++t) {
        int p = g * 2 + t;
        float rx = pjv[t].x - pq8[p].x, ry = pjv[t].y - pq8[p].y, rz = pjv[t].z - pq8[p].z;
        float p1v[8], p2v[8];
        *(float4*)&p1v[0] = p1a[t]; *(float4*)&p1v[4] = p1b[t];
        *(float4*)&p2v[0] = p2a[t]; *(float4*)&p2v[4] = p2b[t];
        float y[8];
        #pragma unroll
        for (int u = 0; u < 8; ++u) {
          float x = p1v[u] + p2v[u] + wxv[u] * rx + wyv[u] * ry + wzv[u] * rz;
          y[u] = fmaxf(fmaf(svv[u], x, tvv[u]), 0.f);
        }
        uint4 pk;
        pk.x = pk2bf(y[0], y[1]); pk.y = pk2bf(y[2], y[3]);
        pk.z = pk2bf(y[4], y[5]); pk.w = pk2bf(y[6], y[7]);
        *(uint4*)&Xs[(r0l + p * 16) * 136 + cc] = pk;
      }
    }
  }
  __syncthreads();

  // ---- MFMA ----
  int w = tid >> 6, lane = tid & 63;
  int m16 = lane & 15, qd = lane >> 4;
  f32x4 acc[2][8];
  #pragma unroll
  for (int mt = 0; mt < 2; ++mt)
    #pragma unroll
    for (int nt = 0; nt < 8; ++nt) acc[mt][nt] = (f32x4){0.f, 0.f, 0.f, 0.f};

  const unsigned short* Ab = &Xs[(w * 32 + m16) * 136 + qd * 8];
  const unsigned short* Bb = W1b + m16 * 128 + qd * 8;
  #pragma unroll 1
  for (int q = 0; q < 4; ++q) {
    bf16x8 A0 = *(const bf16x8*)(Ab + q * 32);
    bf16x8 A1 = *(const bf16x8*)(Ab + 16 * 136 + q * 32);
    #pragma unroll
    for (int nt = 0; nt < 8; ++nt) {
      bf16x8 Bv = *(const bf16x8*)(Bb + nt * 16 * 128 + q * 32);
      acc[0][nt] = __builtin_amdgcn_mfma_f32_16x16x32_bf16(A0, Bv, acc[0][nt], 0, 0, 0);
      acc[1][nt] = __builtin_amdgcn_mfma_f32_16x16x32_bf16(A1, Bv, acc[1][nt], 0, 0, 0);
    }
  }
  __syncthreads();   // Xs reads done; reuse for D-transpose

  // ---- epilogue: bias + stats (registers), D -> Xs (bf16) ----
  float ssum[8], ssq[8];
  #pragma unroll
  for (int nt = 0; nt < 8; ++nt) { ssum[nt] = 0.f; ssq[nt] = 0.f; }
  #pragma unroll
  for (int nt = 0; nt < 8; ++nt) {
    int col = nt * 16 + m16;
    float bb = b1[col];
    #pragma unroll
    for (int mt = 0; mt < 2; ++mt) {
      #pragma unroll
      for (int rg = 0; rg < 4; ++rg) {
        float y = acc[mt][nt][rg] + bb;
        ssum[nt] += y;
        ssq[nt] = fmaf(y, y, ssq[nt]);
        Xs[(w * 32 + mt * 16 + qd * 4 + rg) * 136 + col] = f2bf(y);
      }
    }
  }
  #pragma unroll
  for (int nt = 0; nt < 8; ++nt) {
    ssum[nt] += __shfl_xor(ssum[nt], 16);
    ssum[nt] += __shfl_xor(ssum[nt], 32);
    ssq[nt] += __shfl_xor(ssq[nt], 16);
    ssq[nt] += __shfl_xor(ssq[nt], 32);
  }
  if (lane < 16) {
    #pragma unroll
    for (int nt = 0; nt < 8; ++nt) {
      sred[(w * 128 + nt * 16 + lane) * 2] = ssum[nt];
      sred[(w * 128 + nt * 16 + lane) * 2 + 1] = ssq[nt];
    }
  }
  __syncthreads();
  if (tid < 128) {
    float a = 0.f, q2 = 0.f;
    #pragma unroll
    for (int ww = 0; ww < 4; ++ww) {
      a += sred[(ww * 128 + tid) * 2];
      q2 += sred[(ww * 128 + tid) * 2 + 1];
    }
    part[(size_t)tid * NB1_ + blockIdx.x] = a;
    part[(size_t)(128 + tid) * NB1_ + blockIdx.x] = q2;
  }
  // ---- coalesced x1 store from Xs ----
  #pragma unroll
  for (int p = 0; p < 8; ++p) {
    int rl = r0l + p * 16;
    uint4 v = *(const uint4*)&Xs[rl * 136 + cc];
    *(uint4*)(x1out + (size_t)(R0 + rl) * 128 + cc) = v;
  }
}

// ---------------- layer2 (MFMA): BN1+relu -> bf16 GEMM W2 -> k-max/min + partials ----------------
__global__ __launch_bounds__(256) void layer2_mfma(
    const unsigned short* __restrict__ x1, const float* __restrict__ bnp1,
    const unsigned short* __restrict__ W2b, const float* __restrict__ b2,
    float* __restrict__ ymaxo, float* __restrict__ ymino,
    float* __restrict__ part) {
  __shared__ __align__(16) unsigned short Xs[128 * 136];
  __shared__ float sred[4 * 128 * 2];
  int tid = threadIdx.x;
  int R0 = blockIdx.x * 128;
  int b = R0 >> 16;
  int n0 = (R0 & (NK_ - 1)) >> 4;

  int cc = (tid & 15) * 8;
  int r0l = tid >> 4;

  // ---- stage X (bf16): BN1+relu on x1 ----
  {
    float svv[8], tvv[8];
    *(float4*)&svv[0] = *(const float4*)(bnp1 + cc);       *(float4*)&svv[4] = *(const float4*)(bnp1 + cc + 4);
    *(float4*)&tvv[0] = *(const float4*)(bnp1 + 128 + cc); *(float4*)&tvv[4] = *(const float4*)(bnp1 + 132 + cc);
    #pragma unroll
    for (int g = 0; g < 2; ++g) {
      uint4 pv[4];
      #pragma unroll
      for (int t = 0; t < 4; ++t)
        pv[t] = *(const uint4*)(x1 + (size_t)(R0 + r0l + (g * 4 + t) * 16) * 128 + cc);
      #pragma unroll
      for (int t = 0; t < 4; ++t) {
        int rl = r0l + (g * 4 + t) * 16;
        float xv[8];
        xv[0] = __uint_as_float(pv[t].x << 16); xv[1] = __uint_as_float(pv[t].x & 0xFFFF0000u);
        xv[2] = __uint_as_float(pv[t].y << 16); xv[3] = __uint_as_float(pv[t].y & 0xFFFF0000u);
        xv[4] = __uint_as_float(pv[t].z << 16); xv[5] = __uint_as_float(pv[t].z & 0xFFFF0000u);
        xv[6] = __uint_as_float(pv[t].w << 16); xv[7] = __uint_as_float(pv[t].w & 0xFFFF0000u);
        float y[8];
        #pragma unroll
        for (int u = 0; u < 8; ++u) y[u] = fmaxf(fmaf(svv[u], xv[u], tvv[u]), 0.f);
        uint4 pk;
        pk.x = pk2bf(y[0], y[1]); pk.y = pk2bf(y[2], y[3]);
        pk.z = pk2bf(y[4], y[5]); pk.w = pk2bf(y[6], y[7]);
        *(uint4*)&Xs[rl * 136 + cc] = pk;
      }
    }
  }
  __syncthreads();

  int w = tid >> 6, lane = tid & 63;
  int m16 = lane & 15, qd = lane >> 4;
  f32x4 acc[2][8];
  #pragma unroll
  for (int mt = 0; mt < 2; ++mt)
    #pragma unroll
    for (int nt = 0; nt < 8; ++nt) acc[mt][nt] = (f32x4){0.f, 0.f, 0.f, 0.f};

  const unsigned short* Ab = &Xs[(w * 32 + m16) * 136 + qd * 8];
  const unsigned short* Bb = W2b + m16 * 128 + qd * 8;
  #pragma unroll 1
  for (int q = 0; q < 4; ++q) {
    bf16x8 A0 = *(const bf16x8*)(Ab + q * 32);
    bf16x8 A1 = *(const bf16x8*)(Ab + 16 * 136 + q * 32);
    #pragma unroll
    for (int nt = 0; nt < 8; ++nt) {
      bf16x8 Bv = *(const bf16x8*)(Bb + nt * 16 * 128 + q * 32);
      acc[0][nt] = __builtin_amdgcn_mfma_f32_16x16x32_bf16(A0, Bv, acc[0][nt], 0, 0, 0);
      acc[1][nt] = __builtin_amdgcn_mfma_f32_16x16x32_bf16(A1, Bv, acc[1][nt], 0, 0, 0);
    }
  }

  // ---- epilogue: bias, stats, k-max/min over 16 rows ----
  float ssum[8], ssq[8], mxv[2][8], mnv[2][8];
  #pragma unroll
  for (int nt = 0; nt < 8; ++nt) { ssum[nt] = 0.f; ssq[nt] = 0.f; }
  #pragma unroll
  for (int nt = 0; nt < 8; ++nt) {
    float bb = b2[nt * 16 + m16];
    #pragma unroll
    for (int mt = 0; mt < 2; ++mt) {
      float y0 = acc[mt][nt][0] + bb;
      float mx = y0, mn = y0, su = y0, sq = y0 * y0;
      #pragma unroll
      for (int rg = 1; rg < 4; ++rg) {
        float y = acc[mt][nt][rg] + bb;
        mx = fmaxf(mx, y); mn = fminf(mn, y);
        su += y; sq = fmaf(y, y, sq);
      }
      mxv[mt][nt] = mx; mnv[mt][nt] = mn;
      ssum[nt] += su; ssq[nt] += sq;
    }
  }
  #pragma unroll
  for (int nt = 0; nt < 8; ++nt)
    #pragma unroll
    for (int mt = 0; mt < 2; ++mt) {
      mxv[mt][nt] = fmaxf(mxv[mt][nt], __shfl_xor(mxv[mt][nt], 16));
      mxv[mt][nt] = fmaxf(mxv[mt][nt], __shfl_xor(mxv[mt][nt], 32));
      mnv[mt][nt] = fminf(mnv[mt][nt], __shfl_xor(mnv[mt][nt], 16));
      mnv[mt][nt] = fminf(mnv[mt][nt], __shfl_xor(mnv[mt][nt], 32));
    }
  if (lane < 16) {
    #pragma unroll
    for (int mt = 0; mt < 2; ++mt) {
      int n = n0 + w * 2 + mt;
      size_t base = ((size_t)(b << 12) + n) * 128;
      #pragma unroll
      for (int nt = 0; nt < 8; ++nt) {
        ymaxo[base + nt * 16 + lane] = mxv[mt][nt];
        ymino[base + nt * 16 + lane] = mnv[mt][nt];
      }
    }
  }
  #pragma unroll
  for (int nt = 0; nt < 8; ++nt) {
    ssum[nt] += __shfl_xor(ssum[nt], 16);
    ssum[nt] += __shfl_xor(ssum[nt], 32);
    ssq[nt] += __shfl_xor(ssq[nt], 16);
    ssq[nt] += __shfl_xor(ssq[nt], 32);
  }
  if (lane < 16) {
    #pragma unroll
    for (int nt = 0; nt < 8; ++nt) {
      sred[(w * 128 + nt * 16 + lane) * 2] = ssum[nt];
      sred[(w * 128 + nt * 16 + lane) * 2 + 1] = ssq[nt];
    }
  }
  __syncthreads();
  if (tid < 128) {
    float a = 0.f, q2 = 0.f;
    #pragma unroll
    for (int ww = 0; ww < 4; ++ww) {
      a += sred[(ww * 128 + tid) * 2];
      q2 += sred[(ww * 128 + tid) * 2 + 1];
    }
    part[(size_t)tid * NB1_ + blockIdx.x] = a;
    part[(size_t)(128 + tid) * NB1_ + blockIdx.x] = q2;
  }
}

// ---------------- final: BN2+relu on max/min, transpose to (B,128,N) ----------------
__global__ __launch_bounds__(256) void final_kernel(const float* __restrict__ ymaxo,
                                                    const float* __restrict__ ymino,
                                                    const float* __restrict__ bnp2,
                                                    float* __restrict__ out) {
  __shared__ float T[64 * 129];
  int tid = threadIdx.x;
  int b = blockIdx.x >> 6;
  int n0 = (blockIdx.x & 63) * 64;
  for (int u = tid; u < 64 * 128; u += 256) {
    int nl = u >> 7, o = u & 127;
    size_t base = ((size_t)(b << 12) + n0 + nl) * 128 + o;
    float s = bnp2[o], t = bnp2[128 + o];
    float v = fmaf(s, (s >= 0.f ? ymaxo[base] : ymino[base]), t);
    T[nl * 129 + o] = fmaxf(v, 0.f);
  }
  __syncthreads();
  for (int u = tid; u < 64 * 128; u += 256) {
    int o = u >> 6, nl = u & 63;
    out[((size_t)b * 128 + o) * N_ + n0 + nl] = T[nl * 129 + o];
  }
}

extern "C" void kernel_launch(void* const* d_in, const int* in_sizes, int n_in,
                              void* d_out, int out_size, void* d_ws, size_t ws_size,
                              hipStream_t stream) {
  (void)in_sizes; (void)n_in; (void)out_size; (void)ws_size;
  const float* points1 = (const float*)d_in[0];
  const float* points2 = (const float*)d_in[1];
  const float* features1 = (const float*)d_in[2];
  const float* features2 = (const float*)d_in[3];
  const float* W0 = (const float*)d_in[4];
  const float* b0 = (const float*)d_in[5];
  const float* g0 = (const float*)d_in[6];
  const float* be0 = (const float*)d_in[7];
  const float* W1 = (const float*)d_in[8];
  const float* b1 = (const float*)d_in[9];
  const float* g1 = (const float*)d_in[10];
  const float* be1 = (const float*)d_in[11];
  const float* W2 = (const float*)d_in[12];
  const float* b2 = (const float*)d_in[13];
  const float* g2 = (const float*)d_in[14];
  const float* be2 = (const float*)d_in[15];
  float* out = (float*)d_out;

  char* ws = (char*)d_ws;
  size_t off = 0;
  auto alloc = [&](size_t bytes) -> void* {
    void* p = ws + off;
    off += (bytes + 255) & ~(size_t)255;
    return p;
  };
  int* idx = (int*)alloc((size_t)M_ * 4);
  float4* p1f4 = (float4*)alloc((size_t)B_ * N_ * 16);
  float4* p2f4 = (float4*)alloc((size_t)B_ * N_ * 16);
  float* P1 = (float*)alloc((size_t)B_ * N_ * 128 * 4);
  float* P2 = (float*)alloc((size_t)B_ * N_ * 128 * 4);
  unsigned short* W1b = (unsigned short*)alloc(128 * 128 * 2);
  unsigned short* W2b = (unsigned short*)alloc(128 * 128 * 2);
  float* w0at = (float*)alloc(3 * 128 * 4);
  float* stats = (float*)alloc(3 * 256 * 4);
  float* bnp = (float*)alloc(3 * 256 * 4);
  unsigned short* x1 = (unsigned short*)alloc((size_t)M_ * 128 * 2);  // 128 MB (bf16)
  float* ymaxo = (float*)alloc((size_t)B_ * N_ * 128 * 4);
  float* ymino = (float*)alloc((size_t)B_ * N_ * 128 * 4);

  // KNN scratch aliased onto x1 (dead until layer1): ~66.2 MB < 128 MB
  float* pvals = (float*)x1;                                         // 32 MB
  int* cidx = (int*)((char*)x1 + (size_t)32 * 1024 * 1024);          // 32 MB
  int* ccnt = (int*)((char*)x1 + (size_t)64 * 1024 * 1024);          // 2 MB
  float* Tarr = (float*)((char*)x1 + (size_t)66 * 1024 * 1024);      // 128 KB

  // stats partials aliased onto dead buffers (liveness-checked):
  //  part0 (2 MB, stats0→reduce0) on ymaxo   [ymaxo first written in layer2]
  //  part1 (4 MB, layer1→reduce1) on ymino   [ymino first written in layer2]
  //  part2 (4 MB, layer2→reduce2) on P1      [P1 dead after layer1]
  float* part0 = ymaxo;
  float* part1 = ymino;
  float* part2 = P1;

  pack_pts<<<B_ * N_ / 256, 256, 0, stream>>>(points1, p1f4);
  pack_pts<<<B_ * N_ / 256, 256, 0, stream>>>(points2, p2f4);
  wcvt<<<64, 256, 0, stream>>>(W1, W1b);
  wcvt<<<64, 256, 0, stream>>>(W2, W2b);
  make_w0at<<<1, 128, 0, stream>>>(W0, w0at);

  knn_part<<<B_ * 64 * CH_, 64, 0, stream>>>(p1f4, p2f4, pvals);
  knn_merge<<<Q_ / 256, 256, 0, stream>>>(pvals, Tarr);
  knn_cand<<<B_ * 64 * CH_, 64, 0, stream>>>(p1f4, p2f4, Tarr, cidx, ccnt);
  knn_combine<<<Q_ / 256, 256, 0, stream>>>(cidx, ccnt, idx);

  pkern<<<B_ * N_ / 32, 256, 0, stream>>>(features1, W0, b0, P1, 67);
  pkern<<<B_ * N_ / 32, 256, 0, stream>>>(features2, W0, nullptr, P2, 3);

  stats0_kernel<<<NB0_, 256, 0, stream>>>(P1, P2, idx, p1f4, p2f4, w0at, part0);
  reduce_stats<<<256, 256, 0, stream>>>(part0, NB0_, stats);
  bnfin_kernel<<<1, 128, 0, stream>>>(stats, g0, be0, bnp);

  layer1_mfma<<<NB1_, 256, 0, stream>>>(P1, P2, idx, p1f4, p2f4, w0at, bnp,
                                        W1b, b1, x1, part1);
  reduce_stats<<<256, 256, 0, stream>>>(part1, NB1_, stats + 256);
  bnfin_kernel<<<1, 128, 0, stream>>>(stats + 256, g1, be1, bnp + 256);

  layer2_mfma<<<NB1_, 256, 0, stream>>>(x1, bnp + 256, W2b, b2, ymaxo, ymino, part2);
  reduce_stats<<<256, 256, 0, stream>>>(part2, NB1_, stats + 512);
  bnfin_kernel<<<1, 128, 0, stream>>>(stats + 512, g2, be2, bnp + 512);

  final_kernel<<<B_ * N_ / 64, 256, 0, stream>>>(ymaxo, ymino, bnp + 512, out);
}